// Round 4
// baseline (1025.075 us; speedup 1.0000x reference)
//
#include <hip/hip_runtime.h>
#include <hip/hip_bf16.h>

#define DEV __device__ __forceinline__

typedef __attribute__((ext_vector_type(8))) short bf16x8_t;
typedef __attribute__((ext_vector_type(4))) float f32x4_t;

constexpr int cB = 4, cC = 256, cH = 256, cW = 128, cHN = 8, cHS = 32;
constexpr int cM = cB * cH * cW;  // 131072 rows

DEV float bfu(unsigned int b16) { union { unsigned int u; float f; } v; v.u = b16 << 16; return v.f; }
DEV unsigned short f2bb(float f) { union { __hip_bfloat16 h; unsigned short u; } v; v.h = __float2bfloat16(f); return v.u; }
DEV unsigned int pk2(float a, float b) { return (unsigned)f2bb(a) | ((unsigned)f2bb(b) << 16); }

// ---------------- weight transpose + fp32->bf16 ----------------
__global__ __launch_bounds__(256) void transpose_bf16(const float* __restrict__ src,
                                                      __hip_bfloat16* __restrict__ dst,
                                                      int R, int Ccol) {
  int idx = blockIdx.x * 256 + threadIdx.x;
  if (idx < R * Ccol) {
    int r = idx / Ccol, c = idx - r * Ccol;
    dst[c * R + r] = __float2bfloat16(src[idx]);
  }
}

// ---------------- MFMA attention: grouped proj + RoPE + softpick + PV ----------------
// one block per (b, h, g); 256 threads = 4 waves, each wave owns 32 q-rows.
constexpr int XL_OFF = 0, XR_OFF = 10240, WQ_OFF = 20480, WK_OFF = 23040, WV_OFF = 25600;
constexpr int QS_OFF = 28160, KS_OFF = 38400, VT_OFF = 0, P_OFF = 10240;
constexpr int SMEM_BYTES = 48640;

__global__ __launch_bounds__(256) void attn_mfma(
    const float* __restrict__ left, const float* __restrict__ right,
    const float* __restrict__ qw, const float* __restrict__ kw, const float* __restrict__ vw,
    __hip_bfloat16* __restrict__ att_out)
{
  __shared__ __align__(16) char smem[SMEM_BYTES];

  const int t = threadIdx.x;
  const int g = blockIdx.x & 7;
  const int h = (blockIdx.x >> 3) & 255;
  const int b = blockIdx.x >> 11;
  const size_t HW = (size_t)cH * cW;

  // ---- stage X (transposed, bf16) and weights ----
  {
    const float* lb = left  + ((size_t)(b * cC + g * cHS) * cH + h) * cW;
    const float* rb = right + ((size_t)(b * cC + g * cHS) * cH + h) * cW;
    int w = t & 127, ih = (t >> 7) * 16;
    unsigned short* xlrow = (unsigned short*)(smem + XL_OFF) + w * 40 + ih;
    unsigned short* xrrow = (unsigned short*)(smem + XR_OFF) + w * 40 + ih;
#pragma unroll
    for (int i = 0; i < 16; i += 2) {
      float a0 = lb[(size_t)(ih + i) * HW + w], a1 = lb[(size_t)(ih + i + 1) * HW + w];
      *(unsigned int*)(xlrow + i) = pk2(a0, a1);
      float c0 = rb[(size_t)(ih + i) * HW + w], c1 = rb[(size_t)(ih + i + 1) * HW + w];
      *(unsigned int*)(xrrow + i) = pk2(c0, c1);
    }
    int o = t >> 3, i0 = (t & 7) * 4;
    {
      float4 v4 = *(const float4*)(qw + g * 1024 + t * 4);
      unsigned short* dst = (unsigned short*)(smem + WQ_OFF) + o * 40 + i0;
      *(unsigned int*)(dst) = pk2(v4.x, v4.y); *(unsigned int*)(dst + 2) = pk2(v4.z, v4.w);
    }
    {
      float4 v4 = *(const float4*)(kw + g * 1024 + t * 4);
      unsigned short* dst = (unsigned short*)(smem + WK_OFF) + o * 40 + i0;
      *(unsigned int*)(dst) = pk2(v4.x, v4.y); *(unsigned int*)(dst + 2) = pk2(v4.z, v4.w);
    }
    {
      float4 v4 = *(const float4*)(vw + g * 1024 + t * 4);
      unsigned short* dst = (unsigned short*)(smem + WV_OFF) + o * 40 + i0;
      *(unsigned int*)(dst) = pk2(v4.x, v4.y); *(unsigned int*)(dst + 2) = pk2(v4.z, v4.w);
    }
  }
  __syncthreads();  // B1

  const int lane = t & 63, wid = t >> 6;
  const int c = lane & 15, q4 = lane >> 4;
  const int wbase = wid * 32;
  const f32x4_t zero = {0.f, 0.f, 0.f, 0.f};

  // ---- QK projection (MFMA) + RoPE; write qs/ks ----
  bf16x8_t a_xl[2], a_xr[2];
#pragma unroll
  for (int sub = 0; sub < 2; ++sub) {
    a_xl[sub] = *(const bf16x8_t*)(smem + XL_OFF + (wbase + sub * 16 + c) * 80 + q4 * 16);
    a_xr[sub] = *(const bf16x8_t*)(smem + XR_OFF + (wbase + sub * 16 + c) * 80 + q4 * 16);
  }
  f32x4_t qacc[2][2], kacc[2][2];
#pragma unroll
  for (int ot = 0; ot < 2; ++ot) {
    bf16x8_t bq = *(const bf16x8_t*)(smem + WQ_OFF + (ot * 16 + c) * 80 + q4 * 16);
    bf16x8_t bk = *(const bf16x8_t*)(smem + WK_OFF + (ot * 16 + c) * 80 + q4 * 16);
#pragma unroll
    for (int sub = 0; sub < 2; ++sub) {
      qacc[sub][ot] = __builtin_amdgcn_mfma_f32_16x16x32_bf16(a_xl[sub], bq, zero, 0, 0, 0);
      kacc[sub][ot] = __builtin_amdgcn_mfma_f32_16x16x32_bf16(a_xr[sub], bk, zero, 0, 0, 0);
    }
  }
  {
    const float scale = 0.17677669529663687f;  // 1/sqrt(32)
    float inv = expf((float)c * -0.28782313662425572f);  // 100^(-c/16)
    unsigned short* qsp = (unsigned short*)(smem + QS_OFF);
    unsigned short* ksp = (unsigned short*)(smem + KS_OFF);
#pragma unroll
    for (int sub = 0; sub < 2; ++sub)
#pragma unroll
      for (int r = 0; r < 4; ++r) {
        int w = wbase + sub * 16 + q4 * 4 + r;
        float ang = (float)w * inv;
        float sn = sinf(ang), cs = cosf(ang);
        float q0 = qacc[sub][0][r], q1 = qacc[sub][1][r];
        qsp[w * 40 + c]      = f2bb((q0 * cs - q1 * sn) * scale);
        qsp[w * 40 + c + 16] = f2bb((q1 * cs + q0 * sn) * scale);
        float k0 = kacc[sub][0][r], k1 = kacc[sub][1][r];
        ksp[w * 40 + c]      = f2bb(k0 * cs - k1 * sn);
        ksp[w * 40 + c + 16] = f2bb(k1 * cs + k0 * sn);
      }
  }
  __syncthreads();  // B2

  // ---- V^T projection (MFMA, swapped operands -> transposed output), write vT ----
  {
    f32x4_t vacc[2][2];
#pragma unroll
    for (int dt = 0; dt < 2; ++dt) {
      bf16x8_t awv = *(const bf16x8_t*)(smem + WV_OFF + (dt * 16 + c) * 80 + q4 * 16);
#pragma unroll
      for (int sub = 0; sub < 2; ++sub)
        vacc[dt][sub] = __builtin_amdgcn_mfma_f32_16x16x32_bf16(awv, a_xr[sub], zero, 0, 0, 0);
    }
    unsigned short* vtp = (unsigned short*)(smem + VT_OFF);
#pragma unroll
    for (int dt = 0; dt < 2; ++dt)
#pragma unroll
      for (int sub = 0; sub < 2; ++sub)
#pragma unroll
        for (int r = 0; r < 4; ++r) {
          int d = dt * 16 + q4 * 4 + r;
          int wp = wbase + sub * 16 + c;
          vtp[d * 136 + wp] = f2bb(vacc[dt][sub][r]);
        }
  }

  // ---- S = Q' K'^T (MFMA) ----
  bf16x8_t aq0 = *(const bf16x8_t*)(smem + QS_OFF + (wbase + c) * 80 + q4 * 16);
  bf16x8_t aq1 = *(const bf16x8_t*)(smem + QS_OFF + (wbase + 16 + c) * 80 + q4 * 16);
  f32x4_t sac[2][8];
#pragma unroll
  for (int kt = 0; kt < 8; ++kt) {
    bf16x8_t bk = *(const bf16x8_t*)(smem + KS_OFF + (kt * 16 + c) * 80 + q4 * 16);
    sac[0][kt] = __builtin_amdgcn_mfma_f32_16x16x32_bf16(aq0, bk, zero, 0, 0, 0);
    sac[1][kt] = __builtin_amdgcn_mfma_f32_16x16x32_bf16(aq1, bk, zero, 0, 0, 0);
  }

  // ---- softpick ----
  float dinv_[2][4];
#pragma unroll
  for (int sub = 0; sub < 2; ++sub)
#pragma unroll
    for (int r = 0; r < 4; ++r) {
      float m = sac[sub][0][r];
#pragma unroll
      for (int kt = 1; kt < 8; ++kt) m = fmaxf(m, sac[sub][kt][r]);
      m = fmaxf(m, __shfl_xor(m, 1));
      m = fmaxf(m, __shfl_xor(m, 2));
      m = fmaxf(m, __shfl_xor(m, 4));
      m = fmaxf(m, __shfl_xor(m, 8));
      float em = expf(-m);
      float ss = 0.f;
#pragma unroll
      for (int kt = 0; kt < 8; ++kt) {
        float e = expf(sac[sub][kt][r] - m) - em;
        sac[sub][kt][r] = fmaxf(e, 0.f);
        ss += fabsf(e);
      }
      ss += __shfl_xor(ss, 1);
      ss += __shfl_xor(ss, 2);
      ss += __shfl_xor(ss, 4);
      ss += __shfl_xor(ss, 8);
      dinv_[sub][r] = 1.0f / (ss + 1e-6f);
    }
  __syncthreads();  // B3

  // ---- write P (bf16), then PV (MFMA) ----
  {
    unsigned short* pp = (unsigned short*)(smem + P_OFF);
#pragma unroll
    for (int sub = 0; sub < 2; ++sub)
#pragma unroll
      for (int r = 0; r < 4; ++r) {
        int w = wbase + sub * 16 + q4 * 4 + r;
        float dv = dinv_[sub][r];
#pragma unroll
        for (int kt = 0; kt < 8; ++kt)
          pp[w * 136 + kt * 16 + c] = f2bb(sac[sub][kt][r] * dv);
      }
  }
  f32x4_t oacc[2][2] = {{zero, zero}, {zero, zero}};
#pragma unroll
  for (int ks = 0; ks < 4; ++ks) {
    bf16x8_t ap0 = *(const bf16x8_t*)(smem + P_OFF + (wbase + c) * 272 + ks * 64 + q4 * 16);
    bf16x8_t ap1 = *(const bf16x8_t*)(smem + P_OFF + (wbase + 16 + c) * 272 + ks * 64 + q4 * 16);
    bf16x8_t bv0 = *(const bf16x8_t*)(smem + VT_OFF + (c) * 272 + ks * 64 + q4 * 16);
    bf16x8_t bv1 = *(const bf16x8_t*)(smem + VT_OFF + (16 + c) * 272 + ks * 64 + q4 * 16);
    oacc[0][0] = __builtin_amdgcn_mfma_f32_16x16x32_bf16(ap0, bv0, oacc[0][0], 0, 0, 0);
    oacc[0][1] = __builtin_amdgcn_mfma_f32_16x16x32_bf16(ap0, bv1, oacc[0][1], 0, 0, 0);
    oacc[1][0] = __builtin_amdgcn_mfma_f32_16x16x32_bf16(ap1, bv0, oacc[1][0], 0, 0, 0);
    oacc[1][1] = __builtin_amdgcn_mfma_f32_16x16x32_bf16(ap1, bv1, oacc[1][1], 0, 0, 0);
  }
  {
    __hip_bfloat16* ob = att_out + ((size_t)(b * cH + h) * cW) * cC + g * cHS;
#pragma unroll
    for (int sub = 0; sub < 2; ++sub)
#pragma unroll
      for (int dt = 0; dt < 2; ++dt)
#pragma unroll
        for (int r = 0; r < 4; ++r) {
          int w = wbase + sub * 16 + q4 * 4 + r;
          ob[(size_t)w * cC + dt * 16 + c] = __float2bfloat16(oacc[sub][dt][r]);
        }
  }
}

// ---------------- fused proj + bias + left residual + LN1 -> x1 (bf16) ----------------
// block = 128 rows x full N=256; 4 independent waves (32 rows each), no __syncthreads.
// A tile staged per-wave in swizzled LDS; B (pwT, 128 KB) direct from global (L2-resident).
__global__ __launch_bounds__(256, 2) void proj_ln(
    const __hip_bfloat16* __restrict__ att, const __hip_bfloat16* __restrict__ pwT,
    const float* __restrict__ pb, const float* __restrict__ leftres,
    const float* __restrict__ g1, const float* __restrict__ be1,
    __hip_bfloat16* __restrict__ x1g)
{
  __shared__ __align__(16) char smem[65536];
  const int t = threadIdx.x, lane = t & 63, wid = t >> 6;
  const int c = lane & 15, q4 = lane >> 4;
  const int m0 = blockIdx.x * 128;
  const int wbase = wid * 32;
  char* xbase = smem + wid * 16384;  // this wave's 32 rows x 512B, XOR-swizzled

  // stage own 32 rows of att (bf16, row-major, swizzle byte^((row&7)<<4))
  {
    const char* src = (const char*)(att + (size_t)(m0 + wbase) * 256);
    int col = (lane & 31) * 16, rh = lane >> 5;
#pragma unroll
    for (int p = 0; p < 16; ++p) {
      int row = p * 2 + rh;
      int4 v = *(const int4*)(src + (size_t)row * 512 + col);
      *(int4*)(xbase + row * 512 + (col ^ ((row & 7) << 4))) = v;
    }
  }

  const f32x4_t zero = {0.f, 0.f, 0.f, 0.f};
  f32x4_t oacc[2][16];
#pragma unroll
  for (int sub = 0; sub < 2; ++sub)
#pragma unroll
    for (int nt = 0; nt < 16; ++nt) oacc[sub][nt] = zero;

  const int xsw = (c & 7) << 4;
#pragma unroll
  for (int kc = 0; kc < 8; ++kc) {
    bf16x8_t a0 = *(const bf16x8_t*)(xbase + c * 512 + ((kc * 64 + q4 * 16) ^ xsw));
    bf16x8_t a1 = *(const bf16x8_t*)(xbase + (c + 16) * 512 + ((kc * 64 + q4 * 16) ^ xsw));
#pragma unroll
    for (int nt = 0; nt < 16; ++nt) {
      bf16x8_t bf = *(const bf16x8_t*)(pwT + (size_t)(nt * 16 + c) * 256 + kc * 32 + q4 * 8);
      oacc[0][nt] = __builtin_amdgcn_mfma_f32_16x16x32_bf16(a0, bf, oacc[0][nt], 0, 0, 0);
      oacc[1][nt] = __builtin_amdgcn_mfma_f32_16x16x32_bf16(a1, bf, oacc[1][nt], 0, 0, 0);
    }
  }

  // epilogue: + proj_b + left residual, then LN1 in-register, write bf16 x1
  const int b_ = m0 >> 15, h_ = (m0 >> 7) & 255;
#pragma unroll
  for (int nt = 0; nt < 16; ++nt) {
    int n = nt * 16 + c;
    float pbv = pb[n];
#pragma unroll
    for (int sub = 0; sub < 2; ++sub) {
      int w0 = wbase + sub * 16 + q4 * 4;
      float4 lr = *(const float4*)(leftres + (((size_t)b_ * 256 + n) * 256 + h_) * 128 + w0);
      float la[4] = {lr.x, lr.y, lr.z, lr.w};
#pragma unroll
      for (int r = 0; r < 4; ++r) oacc[sub][nt][r] += pbv + la[r];
    }
  }
  float mu[2][4], rs[2][4];
#pragma unroll
  for (int sub = 0; sub < 2; ++sub)
#pragma unroll
    for (int r = 0; r < 4; ++r) {
      float s = 0.f;
#pragma unroll
      for (int nt = 0; nt < 16; ++nt) s += oacc[sub][nt][r];
      s += __shfl_xor(s, 1); s += __shfl_xor(s, 2); s += __shfl_xor(s, 4); s += __shfl_xor(s, 8);
      float m_ = s * (1.0f / 256.0f);
      float sq = 0.f;
#pragma unroll
      for (int nt = 0; nt < 16; ++nt) { float d = oacc[sub][nt][r] - m_; sq += d * d; }
      sq += __shfl_xor(sq, 1); sq += __shfl_xor(sq, 2); sq += __shfl_xor(sq, 4); sq += __shfl_xor(sq, 8);
      mu[sub][r] = m_;
      rs[sub][r] = rsqrtf(sq * (1.0f / 256.0f) + 1e-5f);
    }
#pragma unroll
  for (int nt = 0; nt < 16; ++nt) {
    int n = nt * 16 + c;
    float gv = g1[n], bv = be1[n];
#pragma unroll
    for (int sub = 0; sub < 2; ++sub)
#pragma unroll
      for (int r = 0; r < 4; ++r) {
        int row = wbase + sub * 16 + q4 * 4 + r;
        x1g[(size_t)(m0 + row) * 256 + n] =
            __float2bfloat16((oacc[sub][nt][r] - mu[sub][r]) * rs[sub][r] * gv + bv);
      }
  }
}

// ---------------- fused FFN: gelu(x1@w1+b1)@w2 + b2 + x1 -> LN2 -> fp32 out ----------------
// block = 128 rows x full N=256; 4 independent waves; hidden never leaves LDS.
__global__ __launch_bounds__(256, 2) void ffn_fused(
    const __hip_bfloat16* __restrict__ x1g, const __hip_bfloat16* __restrict__ w1T,
    const __hip_bfloat16* __restrict__ w2T, const float* __restrict__ b1,
    const float* __restrict__ b2, const float* __restrict__ g2, const float* __restrict__ be2,
    float* __restrict__ outp)
{
  __shared__ __align__(16) char smem[81920];  // x1 4x16KB swz + h 4x4KB swz
  const int t = threadIdx.x, lane = t & 63, wid = t >> 6;
  const int c = lane & 15, q4 = lane >> 4;
  const int m0 = blockIdx.x * 128;
  const int wbase = wid * 32;
  char* xbase = smem + wid * 16384;          // 32 rows x 512B
  char* hbase = smem + 65536 + wid * 4096;   // 32 rows x 128B

  // stage own 32 rows of x1
  {
    const char* src = (const char*)(x1g + (size_t)(m0 + wbase) * 256);
    int col = (lane & 31) * 16, rh = lane >> 5;
#pragma unroll
    for (int p = 0; p < 16; ++p) {
      int row = p * 2 + rh;
      int4 v = *(const int4*)(src + (size_t)row * 512 + col);
      *(int4*)(xbase + row * 512 + (col ^ ((row & 7) << 4))) = v;
    }
  }

  const f32x4_t zero = {0.f, 0.f, 0.f, 0.f};
  f32x4_t oacc[2][16];
#pragma unroll
  for (int sub = 0; sub < 2; ++sub)
#pragma unroll
    for (int nt = 0; nt < 16; ++nt) oacc[sub][nt] = zero;

  const int xsw = (c & 7) << 4;
  for (int j = 0; j < 16; ++j) {
    // ---- h = gelu(x1 @ w1[:, 64j:64j+64] + b1) ----
    f32x4_t hacc[2][4];
#pragma unroll
    for (int sub = 0; sub < 2; ++sub)
#pragma unroll
      for (int nt = 0; nt < 4; ++nt) hacc[sub][nt] = zero;
#pragma unroll
    for (int kc = 0; kc < 8; ++kc) {
      bf16x8_t a0 = *(const bf16x8_t*)(xbase + c * 512 + ((kc * 64 + q4 * 16) ^ xsw));
      bf16x8_t a1 = *(const bf16x8_t*)(xbase + (c + 16) * 512 + ((kc * 64 + q4 * 16) ^ xsw));
#pragma unroll
      for (int nt = 0; nt < 4; ++nt) {
        bf16x8_t bf = *(const bf16x8_t*)(w1T + (size_t)(j * 64 + nt * 16 + c) * 256 + kc * 32 + q4 * 8);
        hacc[0][nt] = __builtin_amdgcn_mfma_f32_16x16x32_bf16(a0, bf, hacc[0][nt], 0, 0, 0);
        hacc[1][nt] = __builtin_amdgcn_mfma_f32_16x16x32_bf16(a1, bf, hacc[1][nt], 0, 0, 0);
      }
    }
#pragma unroll
    for (int nt = 0; nt < 4; ++nt) {
      float b1v = b1[j * 64 + nt * 16 + c];
#pragma unroll
      for (int sub = 0; sub < 2; ++sub)
#pragma unroll
        for (int r = 0; r < 4; ++r) {
          int row = sub * 16 + q4 * 4 + r;
          float v = hacc[sub][nt][r] + b1v;
          v = 0.5f * v * (1.0f + erff(v * 0.7071067811865475f));
          *(unsigned short*)(hbase + row * 128 + (((nt * 16 + c) * 2) ^ ((row & 7) << 4))) = f2bb(v);
        }
    }
    // ---- out += h @ w2[64j:64j+64, :] ----
#pragma unroll
    for (int kc = 0; kc < 2; ++kc) {
      bf16x8_t p0 = *(const bf16x8_t*)(hbase + c * 128 + ((kc * 64 + q4 * 16) ^ xsw));
      bf16x8_t p1 = *(const bf16x8_t*)(hbase + (c + 16) * 128 + ((kc * 64 + q4 * 16) ^ xsw));
#pragma unroll
      for (int nt = 0; nt < 16; ++nt) {
        bf16x8_t bf = *(const bf16x8_t*)(w2T + (size_t)(nt * 16 + c) * 1024 + j * 64 + kc * 32 + q4 * 8);
        oacc[0][nt] = __builtin_amdgcn_mfma_f32_16x16x32_bf16(p0, bf, oacc[0][nt], 0, 0, 0);
        oacc[1][nt] = __builtin_amdgcn_mfma_f32_16x16x32_bf16(p1, bf, oacc[1][nt], 0, 0, 0);
      }
    }
  }

  // ---- epilogue: + b2 + x1 residual (from LDS), LN2 in-register, write fp32 ----
#pragma unroll
  for (int nt = 0; nt < 16; ++nt) {
    float b2v = b2[nt * 16 + c];
#pragma unroll
    for (int sub = 0; sub < 2; ++sub)
#pragma unroll
      for (int r = 0; r < 4; ++r) {
        int row = sub * 16 + q4 * 4 + r;
        unsigned short rv = *(unsigned short*)(xbase + row * 512 + ((((nt * 16 + c) * 2)) ^ ((row & 7) << 4)));
        oacc[sub][nt][r] += b2v + bfu(rv);
      }
  }
  float mu[2][4], rs[2][4];
#pragma unroll
  for (int sub = 0; sub < 2; ++sub)
#pragma unroll
    for (int r = 0; r < 4; ++r) {
      float s = 0.f;
#pragma unroll
      for (int nt = 0; nt < 16; ++nt) s += oacc[sub][nt][r];
      s += __shfl_xor(s, 1); s += __shfl_xor(s, 2); s += __shfl_xor(s, 4); s += __shfl_xor(s, 8);
      float m_ = s * (1.0f / 256.0f);
      float sq = 0.f;
#pragma unroll
      for (int nt = 0; nt < 16; ++nt) { float d = oacc[sub][nt][r] - m_; sq += d * d; }
      sq += __shfl_xor(sq, 1); sq += __shfl_xor(sq, 2); sq += __shfl_xor(sq, 4); sq += __shfl_xor(sq, 8);
      mu[sub][r] = m_;
      rs[sub][r] = rsqrtf(sq * (1.0f / 256.0f) + 1e-5f);
    }
#pragma unroll
  for (int nt = 0; nt < 16; ++nt) {
    int n = nt * 16 + c;
    float gv = g2[n], bv = be2[n];
#pragma unroll
    for (int sub = 0; sub < 2; ++sub)
#pragma unroll
      for (int r = 0; r < 4; ++r) {
        int row = wbase + sub * 16 + q4 * 4 + r;
        outp[(size_t)(m0 + row) * 256 + n] =
            (oacc[sub][nt][r] - mu[sub][r]) * rs[sub][r] * gv + bv;
      }
  }
}

extern "C" void kernel_launch(void* const* d_in, const int* in_sizes, int n_in,
                              void* d_out, int out_size, void* d_ws, size_t ws_size,
                              hipStream_t stream) {
  const float* left   = (const float*)d_in[0];
  const float* right  = (const float*)d_in[1];
  const float* qw     = (const float*)d_in[2];
  const float* kw     = (const float*)d_in[3];
  const float* vw     = (const float*)d_in[4];
  const float* proj_w = (const float*)d_in[5];
  const float* proj_b = (const float*)d_in[6];
  const float* ln1_g  = (const float*)d_in[7];
  const float* ln1_b  = (const float*)d_in[8];
  const float* ln2_g  = (const float*)d_in[9];
  const float* ln2_b  = (const float*)d_in[10];
  const float* w1     = (const float*)d_in[11];
  const float* b1     = (const float*)d_in[12];
  const float* w2     = (const float*)d_in[13];
  const float* b2     = (const float*)d_in[14];

  char* ws = (char*)d_ws;
  __hip_bfloat16* att_out = (__hip_bfloat16*)ws;                 // [M,256] bf16 (67.1 MB)
  __hip_bfloat16* x1      = (__hip_bfloat16*)(ws + 67108864);    // [M,256] bf16
  __hip_bfloat16* pwT     = (__hip_bfloat16*)(ws + 134217728);   // [256][256]
  __hip_bfloat16* w1T     = pwT + 65536;                         // [1024][256]
  __hip_bfloat16* w2T     = w1T + 262144;                        // [256][1024]

  transpose_bf16<<<256, 256, 0, stream>>>(proj_w, pwT, 256, 256);
  transpose_bf16<<<1024, 256, 0, stream>>>(w1, w1T, 256, 1024);
  transpose_bf16<<<1024, 256, 0, stream>>>(w2, w2T, 1024, 256);

  attn_mfma<<<cB * cH * cHN, 256, 0, stream>>>(left, right, qw, kw, vw, att_out);

  // x1 = LN1(att_out @ proj_w + proj_b + left^T)
  proj_ln<<<cM / 128, 256, 0, stream>>>(att_out, pwT, proj_b, left, ln1_g, ln1_b, x1);

  // out = LN2(gelu(x1 @ w1 + b1) @ w2 + b2 + x1)   (fp32 out)
  ffn_fused<<<cM / 128, 256, 0, stream>>>(x1, w1T, w2T, b1, b2, ln2_g, ln2_b, (float*)d_out);
}

// Round 5
// 628.247 us; speedup vs baseline: 1.6316x; 1.6316x over previous
//
#include <hip/hip_runtime.h>
#include <hip/hip_bf16.h>

#define DEV __device__ __forceinline__

typedef __attribute__((ext_vector_type(8))) short bf16x8_t;
typedef __attribute__((ext_vector_type(4))) float f32x4_t;

constexpr int cB = 4, cC = 256, cH = 256, cW = 128, cHN = 8, cHS = 32;
constexpr int cM = cB * cH * cW;  // 131072 rows

DEV float bfu(unsigned int b16) { union { unsigned int u; float f; } v; v.u = b16 << 16; return v.f; }
DEV unsigned short f2bb(float f) { union { __hip_bfloat16 h; unsigned short u; } v; v.h = __float2bfloat16(f); return v.u; }
DEV unsigned int pk2(float a, float b) { return (unsigned)f2bb(a) | ((unsigned)f2bb(b) << 16); }

#define GLOAD_LDS16(g, l) \
  __builtin_amdgcn_global_load_lds((const __attribute__((address_space(1))) void*)(g), \
                                   (__attribute__((address_space(3))) void*)(l), 16, 0, 0)

// ---------------- weight transpose + fp32->bf16 ----------------
__global__ __launch_bounds__(256) void transpose_bf16(const float* __restrict__ src,
                                                      __hip_bfloat16* __restrict__ dst,
                                                      int R, int Ccol) {
  int idx = blockIdx.x * 256 + threadIdx.x;
  if (idx < R * Ccol) {
    int r = idx / Ccol, c = idx - r * Ccol;
    dst[c * R + r] = __float2bfloat16(src[idx]);
  }
}

// ---------------- MFMA attention: grouped proj + RoPE + softpick + PV ----------------
// one block per (b, h, g); 256 threads = 4 waves, each wave owns 32 q-rows.
constexpr int XL_OFF = 0, XR_OFF = 10240, WQ_OFF = 20480, WK_OFF = 23040, WV_OFF = 25600;
constexpr int QS_OFF = 28160, KS_OFF = 38400, VT_OFF = 0, P_OFF = 10240;
constexpr int SMEM_BYTES = 48640;

__global__ __launch_bounds__(256) void attn_mfma(
    const float* __restrict__ left, const float* __restrict__ right,
    const float* __restrict__ qw, const float* __restrict__ kw, const float* __restrict__ vw,
    __hip_bfloat16* __restrict__ att_out)
{
  __shared__ __align__(16) char smem[SMEM_BYTES];

  const int t = threadIdx.x;
  const int g = blockIdx.x & 7;
  const int h = (blockIdx.x >> 3) & 255;
  const int b = blockIdx.x >> 11;
  const size_t HW = (size_t)cH * cW;

  {
    const float* lb = left  + ((size_t)(b * cC + g * cHS) * cH + h) * cW;
    const float* rb = right + ((size_t)(b * cC + g * cHS) * cH + h) * cW;
    int w = t & 127, ih = (t >> 7) * 16;
    unsigned short* xlrow = (unsigned short*)(smem + XL_OFF) + w * 40 + ih;
    unsigned short* xrrow = (unsigned short*)(smem + XR_OFF) + w * 40 + ih;
#pragma unroll
    for (int i = 0; i < 16; i += 2) {
      float a0 = lb[(size_t)(ih + i) * HW + w], a1 = lb[(size_t)(ih + i + 1) * HW + w];
      *(unsigned int*)(xlrow + i) = pk2(a0, a1);
      float c0 = rb[(size_t)(ih + i) * HW + w], c1 = rb[(size_t)(ih + i + 1) * HW + w];
      *(unsigned int*)(xrrow + i) = pk2(c0, c1);
    }
    int o = t >> 3, i0 = (t & 7) * 4;
    {
      float4 v4 = *(const float4*)(qw + g * 1024 + t * 4);
      unsigned short* dst = (unsigned short*)(smem + WQ_OFF) + o * 40 + i0;
      *(unsigned int*)(dst) = pk2(v4.x, v4.y); *(unsigned int*)(dst + 2) = pk2(v4.z, v4.w);
    }
    {
      float4 v4 = *(const float4*)(kw + g * 1024 + t * 4);
      unsigned short* dst = (unsigned short*)(smem + WK_OFF) + o * 40 + i0;
      *(unsigned int*)(dst) = pk2(v4.x, v4.y); *(unsigned int*)(dst + 2) = pk2(v4.z, v4.w);
    }
    {
      float4 v4 = *(const float4*)(vw + g * 1024 + t * 4);
      unsigned short* dst = (unsigned short*)(smem + WV_OFF) + o * 40 + i0;
      *(unsigned int*)(dst) = pk2(v4.x, v4.y); *(unsigned int*)(dst + 2) = pk2(v4.z, v4.w);
    }
  }
  __syncthreads();  // B1

  const int lane = t & 63, wid = t >> 6;
  const int c = lane & 15, q4 = lane >> 4;
  const int wbase = wid * 32;
  const f32x4_t zero = {0.f, 0.f, 0.f, 0.f};

  bf16x8_t a_xl[2], a_xr[2];
#pragma unroll
  for (int sub = 0; sub < 2; ++sub) {
    a_xl[sub] = *(const bf16x8_t*)(smem + XL_OFF + (wbase + sub * 16 + c) * 80 + q4 * 16);
    a_xr[sub] = *(const bf16x8_t*)(smem + XR_OFF + (wbase + sub * 16 + c) * 80 + q4 * 16);
  }
  f32x4_t qacc[2][2], kacc[2][2];
#pragma unroll
  for (int ot = 0; ot < 2; ++ot) {
    bf16x8_t bq = *(const bf16x8_t*)(smem + WQ_OFF + (ot * 16 + c) * 80 + q4 * 16);
    bf16x8_t bk = *(const bf16x8_t*)(smem + WK_OFF + (ot * 16 + c) * 80 + q4 * 16);
#pragma unroll
    for (int sub = 0; sub < 2; ++sub) {
      qacc[sub][ot] = __builtin_amdgcn_mfma_f32_16x16x32_bf16(a_xl[sub], bq, zero, 0, 0, 0);
      kacc[sub][ot] = __builtin_amdgcn_mfma_f32_16x16x32_bf16(a_xr[sub], bk, zero, 0, 0, 0);
    }
  }
  {
    const float scale = 0.17677669529663687f;  // 1/sqrt(32)
    float inv = expf((float)c * -0.28782313662425572f);  // 100^(-c/16)
    unsigned short* qsp = (unsigned short*)(smem + QS_OFF);
    unsigned short* ksp = (unsigned short*)(smem + KS_OFF);
#pragma unroll
    for (int sub = 0; sub < 2; ++sub)
#pragma unroll
      for (int r = 0; r < 4; ++r) {
        int w = wbase + sub * 16 + q4 * 4 + r;
        float ang = (float)w * inv;
        float sn = sinf(ang), cs = cosf(ang);
        float q0 = qacc[sub][0][r], q1 = qacc[sub][1][r];
        qsp[w * 40 + c]      = f2bb((q0 * cs - q1 * sn) * scale);
        qsp[w * 40 + c + 16] = f2bb((q1 * cs + q0 * sn) * scale);
        float k0 = kacc[sub][0][r], k1 = kacc[sub][1][r];
        ksp[w * 40 + c]      = f2bb(k0 * cs - k1 * sn);
        ksp[w * 40 + c + 16] = f2bb(k1 * cs + k0 * sn);
      }
  }
  __syncthreads();  // B2

  {
    f32x4_t vacc[2][2];
#pragma unroll
    for (int dt = 0; dt < 2; ++dt) {
      bf16x8_t awv = *(const bf16x8_t*)(smem + WV_OFF + (dt * 16 + c) * 80 + q4 * 16);
#pragma unroll
      for (int sub = 0; sub < 2; ++sub)
        vacc[dt][sub] = __builtin_amdgcn_mfma_f32_16x16x32_bf16(awv, a_xr[sub], zero, 0, 0, 0);
    }
    unsigned short* vtp = (unsigned short*)(smem + VT_OFF);
#pragma unroll
    for (int dt = 0; dt < 2; ++dt)
#pragma unroll
      for (int sub = 0; sub < 2; ++sub)
#pragma unroll
        for (int r = 0; r < 4; ++r) {
          int d = dt * 16 + q4 * 4 + r;
          int wp = wbase + sub * 16 + c;
          vtp[d * 136 + wp] = f2bb(vacc[dt][sub][r]);
        }
  }

  bf16x8_t aq0 = *(const bf16x8_t*)(smem + QS_OFF + (wbase + c) * 80 + q4 * 16);
  bf16x8_t aq1 = *(const bf16x8_t*)(smem + QS_OFF + (wbase + 16 + c) * 80 + q4 * 16);
  f32x4_t sac[2][8];
#pragma unroll
  for (int kt = 0; kt < 8; ++kt) {
    bf16x8_t bk = *(const bf16x8_t*)(smem + KS_OFF + (kt * 16 + c) * 80 + q4 * 16);
    sac[0][kt] = __builtin_amdgcn_mfma_f32_16x16x32_bf16(aq0, bk, zero, 0, 0, 0);
    sac[1][kt] = __builtin_amdgcn_mfma_f32_16x16x32_bf16(aq1, bk, zero, 0, 0, 0);
  }

  float dinv_[2][4];
#pragma unroll
  for (int sub = 0; sub < 2; ++sub)
#pragma unroll
    for (int r = 0; r < 4; ++r) {
      float m = sac[sub][0][r];
#pragma unroll
      for (int kt = 1; kt < 8; ++kt) m = fmaxf(m, sac[sub][kt][r]);
      m = fmaxf(m, __shfl_xor(m, 1));
      m = fmaxf(m, __shfl_xor(m, 2));
      m = fmaxf(m, __shfl_xor(m, 4));
      m = fmaxf(m, __shfl_xor(m, 8));
      float em = expf(-m);
      float ss = 0.f;
#pragma unroll
      for (int kt = 0; kt < 8; ++kt) {
        float e = expf(sac[sub][kt][r] - m) - em;
        sac[sub][kt][r] = fmaxf(e, 0.f);
        ss += fabsf(e);
      }
      ss += __shfl_xor(ss, 1);
      ss += __shfl_xor(ss, 2);
      ss += __shfl_xor(ss, 4);
      ss += __shfl_xor(ss, 8);
      dinv_[sub][r] = 1.0f / (ss + 1e-6f);
    }
  __syncthreads();  // B3

  {
    unsigned short* pp = (unsigned short*)(smem + P_OFF);
#pragma unroll
    for (int sub = 0; sub < 2; ++sub)
#pragma unroll
      for (int r = 0; r < 4; ++r) {
        int w = wbase + sub * 16 + q4 * 4 + r;
        float dv = dinv_[sub][r];
#pragma unroll
        for (int kt = 0; kt < 8; ++kt)
          pp[w * 136 + kt * 16 + c] = f2bb(sac[sub][kt][r] * dv);
      }
  }
  f32x4_t oacc[2][2] = {{zero, zero}, {zero, zero}};
#pragma unroll
  for (int ks = 0; ks < 4; ++ks) {
    bf16x8_t ap0 = *(const bf16x8_t*)(smem + P_OFF + (wbase + c) * 272 + ks * 64 + q4 * 16);
    bf16x8_t ap1 = *(const bf16x8_t*)(smem + P_OFF + (wbase + 16 + c) * 272 + ks * 64 + q4 * 16);
    bf16x8_t bv0 = *(const bf16x8_t*)(smem + VT_OFF + (c) * 272 + ks * 64 + q4 * 16);
    bf16x8_t bv1 = *(const bf16x8_t*)(smem + VT_OFF + (16 + c) * 272 + ks * 64 + q4 * 16);
    oacc[0][0] = __builtin_amdgcn_mfma_f32_16x16x32_bf16(ap0, bv0, oacc[0][0], 0, 0, 0);
    oacc[0][1] = __builtin_amdgcn_mfma_f32_16x16x32_bf16(ap0, bv1, oacc[0][1], 0, 0, 0);
    oacc[1][0] = __builtin_amdgcn_mfma_f32_16x16x32_bf16(ap1, bv0, oacc[1][0], 0, 0, 0);
    oacc[1][1] = __builtin_amdgcn_mfma_f32_16x16x32_bf16(ap1, bv1, oacc[1][1], 0, 0, 0);
  }
  {
    __hip_bfloat16* ob = att_out + ((size_t)(b * cH + h) * cW) * cC + g * cHS;
#pragma unroll
    for (int sub = 0; sub < 2; ++sub)
#pragma unroll
      for (int dt = 0; dt < 2; ++dt)
#pragma unroll
        for (int r = 0; r < 4; ++r) {
          int w = wbase + sub * 16 + q4 * 4 + r;
          ob[(size_t)w * cC + dt * 16 + c] = __float2bfloat16(oacc[sub][dt][r]);
        }
  }
}

// ---------------- m97-structure bf16 GEMM: C = A[M,K] @ Bt[N,K]^T, 128x128 tile ----------------
// BK=32, global_load_lds staging (linear LDS), 4 waves x 64x64, fused epilogues.
// EPI 0: + bias + left^T residual -> bf16 (pre-LN1)
// EPI 1: + bias -> exact GELU -> bf16 (ffn hidden)
// EPI 2: + bias + x1 residual -> bf16 (pre-LN2)
template<int EPI>
__global__ __launch_bounds__(256) void gemm128(
    const __hip_bfloat16* __restrict__ A, const __hip_bfloat16* __restrict__ Bt,
    const int K, const int N,
    const float* __restrict__ bias, const float* __restrict__ leftres,
    const __hip_bfloat16* __restrict__ x1res,
    __hip_bfloat16* __restrict__ outb)
{
  __shared__ __align__(16) char smem[16384];  // As [128][32] bf16, Bs [128][32] bf16 (linear)
  char* As = smem;
  char* Bs = smem + 8192;
  const int t = threadIdx.x;
  const int m0 = blockIdx.y * 128, n0 = blockIdx.x * 128;
  const int lane = t & 63, wid = t >> 6;
  const int r16 = lane & 15, kq = lane >> 4;
  const int wr = (wid >> 1) * 64, wc = (wid & 1) * 64;

  // staging geometry: instr (wid, i): rows (i*4+wid)*16 + lane/4, col chunk (lane&3)*8 elems
  const int ld_l4 = lane >> 2, ld_c8 = (lane & 3) * 8;

  f32x4_t acc[4][4];
#pragma unroll
  for (int fi = 0; fi < 4; ++fi)
#pragma unroll
    for (int fj = 0; fj < 4; ++fj) acc[fi][fj] = {0.f, 0.f, 0.f, 0.f};

  for (int k0 = 0; k0 < K; k0 += 32) {
#pragma unroll
    for (int i = 0; i < 2; ++i) {
      int chunk = i * 4 + wid;
      int row = chunk * 16 + ld_l4;
      GLOAD_LDS16(A  + (size_t)(m0 + row) * K + k0 + ld_c8, As + chunk * 1024);
      GLOAD_LDS16(Bt + (size_t)(n0 + row) * K + k0 + ld_c8, Bs + chunk * 1024);
    }
    __syncthreads();
    bf16x8_t af[4], bf[4];
#pragma unroll
    for (int fi = 0; fi < 4; ++fi)
      af[fi] = *(const bf16x8_t*)(As + (wr + fi * 16 + r16) * 64 + kq * 16);
#pragma unroll
    for (int fj = 0; fj < 4; ++fj)
      bf[fj] = *(const bf16x8_t*)(Bs + (wc + fj * 16 + r16) * 64 + kq * 16);
#pragma unroll
    for (int fi = 0; fi < 4; ++fi)
#pragma unroll
      for (int fj = 0; fj < 4; ++fj)
        acc[fi][fj] = __builtin_amdgcn_mfma_f32_16x16x32_bf16(af[fi], bf[fj], acc[fi][fj], 0, 0, 0);
    __syncthreads();
  }

#pragma unroll
  for (int fi = 0; fi < 4; ++fi)
#pragma unroll
    for (int fj = 0; fj < 4; ++fj) {
      int nn = n0 + wc + fj * 16 + r16;
      float bias_v = bias[nn];
      int mbase = m0 + wr + fi * 16 + kq * 4;
      if (EPI == 0) {
        int b_ = mbase >> 15, rem = mbase & 32767, h_ = rem >> 7, w0 = rem & 127;
        float4 lr = *(const float4*)(leftres + (((size_t)b_ * 256 + nn) * 256 + h_) * 128 + w0);
        float la[4] = {lr.x, lr.y, lr.z, lr.w};
#pragma unroll
        for (int r = 0; r < 4; ++r)
          outb[(size_t)(mbase + r) * N + nn] = __float2bfloat16(acc[fi][fj][r] + bias_v + la[r]);
      } else if (EPI == 1) {
#pragma unroll
        for (int r = 0; r < 4; ++r) {
          float val = acc[fi][fj][r] + bias_v;
          val = 0.5f * val * (1.0f + erff(val * 0.7071067811865475f));
          outb[(size_t)(mbase + r) * N + nn] = __float2bfloat16(val);
        }
      } else {
#pragma unroll
        for (int r = 0; r < 4; ++r) {
          float val = acc[fi][fj][r] + bias_v + __bfloat162float(x1res[(size_t)(mbase + r) * 256 + nn]);
          outb[(size_t)(mbase + r) * N + nn] = __float2bfloat16(val);
        }
      }
    }
}

// ---------------- LayerNorm over C=256, one wave per row ----------------
template<bool F32OUT>
__global__ __launch_bounds__(256) void ln_kernel(const __hip_bfloat16* __restrict__ in,
                                                 void* __restrict__ outp,
                                                 const float* __restrict__ g,
                                                 const float* __restrict__ b) {
  int row = blockIdx.x * 4 + (threadIdx.x >> 6);
  int lane = threadIdx.x & 63;
  uint2 u = ((const uint2*)in)[(size_t)row * 64 + lane];
  float v[4] = { bfu(u.x & 0xffff), bfu(u.x >> 16), bfu(u.y & 0xffff), bfu(u.y >> 16) };
  float s = v[0] + v[1] + v[2] + v[3];
#pragma unroll
  for (int off = 1; off < 64; off <<= 1) s += __shfl_xor(s, off);
  float mu = s * (1.0f / 256.0f);
  float d0 = v[0] - mu, d1 = v[1] - mu, d2 = v[2] - mu, d3 = v[3] - mu;
  float sq = d0 * d0 + d1 * d1 + d2 * d2 + d3 * d3;
#pragma unroll
  for (int off = 1; off < 64; off <<= 1) sq += __shfl_xor(sq, off);
  float r = rsqrtf(sq * (1.0f / 256.0f) + 1e-5f);
  int col = lane * 4;
  float o0 = d0 * r * g[col + 0] + b[col + 0];
  float o1 = d1 * r * g[col + 1] + b[col + 1];
  float o2 = d2 * r * g[col + 2] + b[col + 2];
  float o3 = d3 * r * g[col + 3] + b[col + 3];
  if (F32OUT) {
    float4 of = make_float4(o0, o1, o2, o3);
    ((float4*)outp)[(size_t)row * 64 + lane] = of;
  } else {
    uint2 ou;
    ou.x = (unsigned)f2bb(o0) | ((unsigned)f2bb(o1) << 16);
    ou.y = (unsigned)f2bb(o2) | ((unsigned)f2bb(o3) << 16);
    ((uint2*)outp)[(size_t)row * 64 + lane] = ou;
  }
}

extern "C" void kernel_launch(void* const* d_in, const int* in_sizes, int n_in,
                              void* d_out, int out_size, void* d_ws, size_t ws_size,
                              hipStream_t stream) {
  const float* left   = (const float*)d_in[0];
  const float* right  = (const float*)d_in[1];
  const float* qw     = (const float*)d_in[2];
  const float* kw     = (const float*)d_in[3];
  const float* vw     = (const float*)d_in[4];
  const float* proj_w = (const float*)d_in[5];
  const float* proj_b = (const float*)d_in[6];
  const float* ln1_g  = (const float*)d_in[7];
  const float* ln1_b  = (const float*)d_in[8];
  const float* ln2_g  = (const float*)d_in[9];
  const float* ln2_b  = (const float*)d_in[10];
  const float* w1     = (const float*)d_in[11];
  const float* b1     = (const float*)d_in[12];
  const float* w2     = (const float*)d_in[13];
  const float* b2     = (const float*)d_in[14];

  char* ws = (char*)d_ws;
  // lifetimes: att_out(attn->proj), x1pre(proj->ln1), hidden(ffn1->ffn2) overlap region [0,268MB):
  //   att_out [0,67MB) dead before ffn1 writes hidden [0,268MB); x1pre [67,134MB) dead after ln1.
  __hip_bfloat16* hidden  = (__hip_bfloat16*)ws;                 // [M,1024] bf16
  __hip_bfloat16* att_out = (__hip_bfloat16*)ws;                 // [M,256]  bf16
  __hip_bfloat16* x1pre   = (__hip_bfloat16*)(ws + 67108864);    // [M,256]  bf16
  __hip_bfloat16* x1      = (__hip_bfloat16*)(ws + 268435456);   // [M,256]  bf16
  __hip_bfloat16* pre2    = (__hip_bfloat16*)(ws + 335544320);   // [M,256]  bf16
  __hip_bfloat16* pwT     = (__hip_bfloat16*)(ws + 402653184);   // [256][256]
  __hip_bfloat16* w1T     = pwT + 65536;                         // [1024][256]
  __hip_bfloat16* w2T     = w1T + 262144;                        // [256][1024]

  transpose_bf16<<<256, 256, 0, stream>>>(proj_w, pwT, 256, 256);
  transpose_bf16<<<1024, 256, 0, stream>>>(w1, w1T, 256, 1024);
  transpose_bf16<<<1024, 256, 0, stream>>>(w2, w2T, 1024, 256);

  attn_mfma<<<cB * cH * cHN, 256, 0, stream>>>(left, right, qw, kw, vw, att_out);

  // x1pre = att_out @ proj_w + proj_b + left^T
  gemm128<0><<<dim3(2, 1024), 256, 0, stream>>>(att_out, pwT, 256, 256, proj_b, left, nullptr, x1pre);
  // x1 = LN1(x1pre)
  ln_kernel<false><<<32768, 256, 0, stream>>>(x1pre, x1, ln1_g, ln1_b);
  // hidden = gelu(x1 @ w1 + b1)
  gemm128<1><<<dim3(8, 1024), 256, 0, stream>>>(x1, w1T, 256, 1024, b1, nullptr, nullptr, hidden);
  // pre2 = hidden @ w2 + b2 + x1
  gemm128<2><<<dim3(2, 1024), 256, 0, stream>>>(hidden, w2T, 1024, 256, b2, nullptr, x1, pre2);
  // out = LN2(pre2)  (fp32)
  ln_kernel<true><<<32768, 256, 0, stream>>>(pre2, d_out, ln2_g, ln2_b);
}

// Round 6
// 537.298 us; speedup vs baseline: 1.9078x; 1.1693x over previous
//
#include <hip/hip_runtime.h>
#include <hip/hip_bf16.h>

#define DEV __device__ __forceinline__

typedef __attribute__((ext_vector_type(8))) short bf16x8_t;
typedef __attribute__((ext_vector_type(4))) float f32x4_t;

constexpr int cB = 4, cC = 256, cH = 256, cW = 128, cHN = 8, cHS = 32;
constexpr int cM = cB * cH * cW;  // 131072 rows

DEV float bfu(unsigned int b16) { union { unsigned int u; float f; } v; v.u = b16 << 16; return v.f; }
DEV unsigned short f2bb(float f) { union { __hip_bfloat16 h; unsigned short u; } v; v.h = __float2bfloat16(f); return v.u; }
DEV unsigned int pk2(float a, float b) { return (unsigned)f2bb(a) | ((unsigned)f2bb(b) << 16); }

#define GLOAD_LDS16(g, l) \
  __builtin_amdgcn_global_load_lds((const __attribute__((address_space(1))) void*)(g), \
                                   (__attribute__((address_space(3))) void*)(l), 16, 0, 0)

// fast exact-GELU: A&S 7.1.26 erf approximation (max abs err 1.5e-7)
DEV float gelu_fast(float v) {
  float ax = fabsf(v) * 0.7071067811865475f;
  float t = __builtin_amdgcn_rcpf(1.0f + 0.3275911f * ax);
  float poly = ((((1.061405429f * t - 1.453152027f) * t + 1.421413741f) * t
                 - 0.284496736f) * t + 0.254829592f) * t;
  float e = __expf(-ax * ax);
  float erfv = 1.0f - poly * e;  // erf(|v|/sqrt2)
  float phi = 0.5f + 0.5f * copysignf(erfv, v);
  return v * phi;
}

// ---------------- weight transpose + fp32->bf16 ----------------
__global__ __launch_bounds__(256) void transpose_bf16(const float* __restrict__ src,
                                                      __hip_bfloat16* __restrict__ dst,
                                                      int R, int Ccol) {
  int idx = blockIdx.x * 256 + threadIdx.x;
  if (idx < R * Ccol) {
    int r = idx / Ccol, c = idx - r * Ccol;
    dst[c * R + r] = __float2bfloat16(src[idx]);
  }
}

// ---------------- MFMA attention: grouped proj + RoPE + softpick + PV ----------------
constexpr int XL_OFF = 0, XR_OFF = 10240, WQ_OFF = 20480, WK_OFF = 23040, WV_OFF = 25600;
constexpr int QS_OFF = 28160, KS_OFF = 38400, VT_OFF = 0, P_OFF = 10240;
constexpr int SMEM_BYTES = 48640;

__global__ __launch_bounds__(256) void attn_mfma(
    const float* __restrict__ left, const float* __restrict__ right,
    const float* __restrict__ qw, const float* __restrict__ kw, const float* __restrict__ vw,
    __hip_bfloat16* __restrict__ att_out)
{
  __shared__ __align__(16) char smem[SMEM_BYTES];

  const int t = threadIdx.x;
  const int g = blockIdx.x & 7;
  const int h = (blockIdx.x >> 3) & 255;
  const int b = blockIdx.x >> 11;
  const size_t HW = (size_t)cH * cW;

  {
    const float* lb = left  + ((size_t)(b * cC + g * cHS) * cH + h) * cW;
    const float* rb = right + ((size_t)(b * cC + g * cHS) * cH + h) * cW;
    int w = t & 127, ih = (t >> 7) * 16;
    unsigned short* xlrow = (unsigned short*)(smem + XL_OFF) + w * 40 + ih;
    unsigned short* xrrow = (unsigned short*)(smem + XR_OFF) + w * 40 + ih;
#pragma unroll
    for (int i = 0; i < 16; i += 2) {
      float a0 = lb[(size_t)(ih + i) * HW + w], a1 = lb[(size_t)(ih + i + 1) * HW + w];
      *(unsigned int*)(xlrow + i) = pk2(a0, a1);
      float c0 = rb[(size_t)(ih + i) * HW + w], c1 = rb[(size_t)(ih + i + 1) * HW + w];
      *(unsigned int*)(xrrow + i) = pk2(c0, c1);
    }
    int o = t >> 3, i0 = (t & 7) * 4;
    {
      float4 v4 = *(const float4*)(qw + g * 1024 + t * 4);
      unsigned short* dst = (unsigned short*)(smem + WQ_OFF) + o * 40 + i0;
      *(unsigned int*)(dst) = pk2(v4.x, v4.y); *(unsigned int*)(dst + 2) = pk2(v4.z, v4.w);
    }
    {
      float4 v4 = *(const float4*)(kw + g * 1024 + t * 4);
      unsigned short* dst = (unsigned short*)(smem + WK_OFF) + o * 40 + i0;
      *(unsigned int*)(dst) = pk2(v4.x, v4.y); *(unsigned int*)(dst + 2) = pk2(v4.z, v4.w);
    }
    {
      float4 v4 = *(const float4*)(vw + g * 1024 + t * 4);
      unsigned short* dst = (unsigned short*)(smem + WV_OFF) + o * 40 + i0;
      *(unsigned int*)(dst) = pk2(v4.x, v4.y); *(unsigned int*)(dst + 2) = pk2(v4.z, v4.w);
    }
  }
  __syncthreads();  // B1

  const int lane = t & 63, wid = t >> 6;
  const int c = lane & 15, q4 = lane >> 4;
  const int wbase = wid * 32;
  const f32x4_t zero = {0.f, 0.f, 0.f, 0.f};

  bf16x8_t a_xl[2], a_xr[2];
#pragma unroll
  for (int sub = 0; sub < 2; ++sub) {
    a_xl[sub] = *(const bf16x8_t*)(smem + XL_OFF + (wbase + sub * 16 + c) * 80 + q4 * 16);
    a_xr[sub] = *(const bf16x8_t*)(smem + XR_OFF + (wbase + sub * 16 + c) * 80 + q4 * 16);
  }
  f32x4_t qacc[2][2], kacc[2][2];
#pragma unroll
  for (int ot = 0; ot < 2; ++ot) {
    bf16x8_t bq = *(const bf16x8_t*)(smem + WQ_OFF + (ot * 16 + c) * 80 + q4 * 16);
    bf16x8_t bk = *(const bf16x8_t*)(smem + WK_OFF + (ot * 16 + c) * 80 + q4 * 16);
#pragma unroll
    for (int sub = 0; sub < 2; ++sub) {
      qacc[sub][ot] = __builtin_amdgcn_mfma_f32_16x16x32_bf16(a_xl[sub], bq, zero, 0, 0, 0);
      kacc[sub][ot] = __builtin_amdgcn_mfma_f32_16x16x32_bf16(a_xr[sub], bk, zero, 0, 0, 0);
    }
  }
  {
    const float scale = 0.17677669529663687f;  // 1/sqrt(32)
    float inv = expf((float)c * -0.28782313662425572f);  // 100^(-c/16)
    unsigned short* qsp = (unsigned short*)(smem + QS_OFF);
    unsigned short* ksp = (unsigned short*)(smem + KS_OFF);
#pragma unroll
    for (int sub = 0; sub < 2; ++sub)
#pragma unroll
      for (int r = 0; r < 4; ++r) {
        int w = wbase + sub * 16 + q4 * 4 + r;
        float ang = (float)w * inv;
        float sn = sinf(ang), cs = cosf(ang);
        float q0 = qacc[sub][0][r], q1 = qacc[sub][1][r];
        qsp[w * 40 + c]      = f2bb((q0 * cs - q1 * sn) * scale);
        qsp[w * 40 + c + 16] = f2bb((q1 * cs + q0 * sn) * scale);
        float k0 = kacc[sub][0][r], k1 = kacc[sub][1][r];
        ksp[w * 40 + c]      = f2bb(k0 * cs - k1 * sn);
        ksp[w * 40 + c + 16] = f2bb(k1 * cs + k0 * sn);
      }
  }
  __syncthreads();  // B2

  {
    f32x4_t vacc[2][2];
#pragma unroll
    for (int dt = 0; dt < 2; ++dt) {
      bf16x8_t awv = *(const bf16x8_t*)(smem + WV_OFF + (dt * 16 + c) * 80 + q4 * 16);
#pragma unroll
      for (int sub = 0; sub < 2; ++sub)
        vacc[dt][sub] = __builtin_amdgcn_mfma_f32_16x16x32_bf16(awv, a_xr[sub], zero, 0, 0, 0);
    }
    unsigned short* vtp = (unsigned short*)(smem + VT_OFF);
#pragma unroll
    for (int dt = 0; dt < 2; ++dt)
#pragma unroll
      for (int sub = 0; sub < 2; ++sub)
#pragma unroll
        for (int r = 0; r < 4; ++r) {
          int d = dt * 16 + q4 * 4 + r;
          int wp = wbase + sub * 16 + c;
          vtp[d * 136 + wp] = f2bb(vacc[dt][sub][r]);
        }
  }

  bf16x8_t aq0 = *(const bf16x8_t*)(smem + QS_OFF + (wbase + c) * 80 + q4 * 16);
  bf16x8_t aq1 = *(const bf16x8_t*)(smem + QS_OFF + (wbase + 16 + c) * 80 + q4 * 16);
  f32x4_t sac[2][8];
#pragma unroll
  for (int kt = 0; kt < 8; ++kt) {
    bf16x8_t bk = *(const bf16x8_t*)(smem + KS_OFF + (kt * 16 + c) * 80 + q4 * 16);
    sac[0][kt] = __builtin_amdgcn_mfma_f32_16x16x32_bf16(aq0, bk, zero, 0, 0, 0);
    sac[1][kt] = __builtin_amdgcn_mfma_f32_16x16x32_bf16(aq1, bk, zero, 0, 0, 0);
  }

  float dinv_[2][4];
#pragma unroll
  for (int sub = 0; sub < 2; ++sub)
#pragma unroll
    for (int r = 0; r < 4; ++r) {
      float m = sac[sub][0][r];
#pragma unroll
      for (int kt = 1; kt < 8; ++kt) m = fmaxf(m, sac[sub][kt][r]);
      m = fmaxf(m, __shfl_xor(m, 1));
      m = fmaxf(m, __shfl_xor(m, 2));
      m = fmaxf(m, __shfl_xor(m, 4));
      m = fmaxf(m, __shfl_xor(m, 8));
      float em = expf(-m);
      float ss = 0.f;
#pragma unroll
      for (int kt = 0; kt < 8; ++kt) {
        float e = expf(sac[sub][kt][r] - m) - em;
        sac[sub][kt][r] = fmaxf(e, 0.f);
        ss += fabsf(e);
      }
      ss += __shfl_xor(ss, 1);
      ss += __shfl_xor(ss, 2);
      ss += __shfl_xor(ss, 4);
      ss += __shfl_xor(ss, 8);
      dinv_[sub][r] = 1.0f / (ss + 1e-6f);
    }
  __syncthreads();  // B3

  {
    unsigned short* pp = (unsigned short*)(smem + P_OFF);
#pragma unroll
    for (int sub = 0; sub < 2; ++sub)
#pragma unroll
      for (int r = 0; r < 4; ++r) {
        int w = wbase + sub * 16 + q4 * 4 + r;
        float dv = dinv_[sub][r];
#pragma unroll
        for (int kt = 0; kt < 8; ++kt)
          pp[w * 136 + kt * 16 + c] = f2bb(sac[sub][kt][r] * dv);
      }
  }
  f32x4_t oacc[2][2] = {{zero, zero}, {zero, zero}};
#pragma unroll
  for (int ks = 0; ks < 4; ++ks) {
    bf16x8_t ap0 = *(const bf16x8_t*)(smem + P_OFF + (wbase + c) * 272 + ks * 64 + q4 * 16);
    bf16x8_t ap1 = *(const bf16x8_t*)(smem + P_OFF + (wbase + 16 + c) * 272 + ks * 64 + q4 * 16);
    bf16x8_t bv0 = *(const bf16x8_t*)(smem + VT_OFF + (c) * 272 + ks * 64 + q4 * 16);
    bf16x8_t bv1 = *(const bf16x8_t*)(smem + VT_OFF + (16 + c) * 272 + ks * 64 + q4 * 16);
    oacc[0][0] = __builtin_amdgcn_mfma_f32_16x16x32_bf16(ap0, bv0, oacc[0][0], 0, 0, 0);
    oacc[0][1] = __builtin_amdgcn_mfma_f32_16x16x32_bf16(ap0, bv1, oacc[0][1], 0, 0, 0);
    oacc[1][0] = __builtin_amdgcn_mfma_f32_16x16x32_bf16(ap1, bv0, oacc[1][0], 0, 0, 0);
    oacc[1][1] = __builtin_amdgcn_mfma_f32_16x16x32_bf16(ap1, bv1, oacc[1][1], 0, 0, 0);
  }
  {
    __hip_bfloat16* ob = att_out + ((size_t)(b * cH + h) * cW) * cC + g * cHS;
#pragma unroll
    for (int sub = 0; sub < 2; ++sub)
#pragma unroll
      for (int dt = 0; dt < 2; ++dt)
#pragma unroll
        for (int r = 0; r < 4; ++r) {
          int w = wbase + sub * 16 + q4 * 4 + r;
          ob[(size_t)w * cC + dt * 16 + c] = __float2bfloat16(oacc[sub][dt][r]);
        }
  }
}

// ---------------- GEMM + GELU (ffn1): hidden = gelu(x1 @ w1T^T + b1), 128x128 tile ----------------
// 1D grid 8192, XCD-swizzled: id&7 = xcd owns bands [xcd*128, xcd*128+128); 8 n-tiles per band
// run consecutively on the same XCD so the A band stays L2-resident.
__global__ __launch_bounds__(256) void gemm_gelu(
    const __hip_bfloat16* __restrict__ A, const __hip_bfloat16* __restrict__ Bt,
    const int K, const int N, const float* __restrict__ bias,
    __hip_bfloat16* __restrict__ outb)
{
  __shared__ __align__(16) char smem[16384];
  char* As = smem;
  char* Bs = smem + 8192;
  const int t = threadIdx.x;
  const int id = blockIdx.x;
  const int slot = id >> 3;
  const int by = (id & 7) * 128 + (slot >> 3);
  const int bx = slot & 7;
  const int m0 = by * 128, n0 = bx * 128;
  const int lane = t & 63, wid = t >> 6;
  const int r16 = lane & 15, kq = lane >> 4;
  const int wr = (wid >> 1) * 64, wc = (wid & 1) * 64;
  const int ld_l4 = lane >> 2, ld_c8 = (lane & 3) * 8;

  f32x4_t acc[4][4];
#pragma unroll
  for (int fi = 0; fi < 4; ++fi)
#pragma unroll
    for (int fj = 0; fj < 4; ++fj) acc[fi][fj] = {0.f, 0.f, 0.f, 0.f};

  for (int k0 = 0; k0 < K; k0 += 32) {
#pragma unroll
    for (int i = 0; i < 2; ++i) {
      int chunk = i * 4 + wid;
      int row = chunk * 16 + ld_l4;
      GLOAD_LDS16(A  + (size_t)(m0 + row) * K + k0 + ld_c8, As + chunk * 1024);
      GLOAD_LDS16(Bt + (size_t)(n0 + row) * K + k0 + ld_c8, Bs + chunk * 1024);
    }
    __syncthreads();
    bf16x8_t af[4], bf[4];
#pragma unroll
    for (int fi = 0; fi < 4; ++fi)
      af[fi] = *(const bf16x8_t*)(As + (wr + fi * 16 + r16) * 64 + kq * 16);
#pragma unroll
    for (int fj = 0; fj < 4; ++fj)
      bf[fj] = *(const bf16x8_t*)(Bs + (wc + fj * 16 + r16) * 64 + kq * 16);
#pragma unroll
    for (int fi = 0; fi < 4; ++fi)
#pragma unroll
      for (int fj = 0; fj < 4; ++fj)
        acc[fi][fj] = __builtin_amdgcn_mfma_f32_16x16x32_bf16(af[fi], bf[fj], acc[fi][fj], 0, 0, 0);
    __syncthreads();
  }

#pragma unroll
  for (int fi = 0; fi < 4; ++fi)
#pragma unroll
    for (int fj = 0; fj < 4; ++fj) {
      int nn = n0 + wc + fj * 16 + r16;
      float bias_v = bias[nn];
      int mbase = m0 + wr + fi * 16 + kq * 4;
#pragma unroll
      for (int r = 0; r < 4; ++r)
        outb[(size_t)(mbase + r) * N + nn] = __float2bfloat16(gelu_fast(acc[fi][fj][r] + bias_v));
    }
}

// ---------------- full-row GEMM + residual + LayerNorm, BM=128 x BN=256 (full width) ----------------
// 4 waves, each owns 32 rows x 256 cols (acc[2][16]); LN computed in-register per row.
// FFN2=false: proj — A=att_out, Bt=pwT (K=256), +proj_b +left^T residual, LN1 -> bf16 x1
// FFN2=true : ffn2 — A=hidden,  Bt=w2T (K=1024), +b2 +x1 residual (bf16), LN2 -> fp32 d_out
template<int KK, bool FFN2>
__global__ __launch_bounds__(256, 2) void gemm_ln(
    const __hip_bfloat16* __restrict__ A, const __hip_bfloat16* __restrict__ Bt,
    const float* __restrict__ bias, const float* __restrict__ leftres,
    const __hip_bfloat16* __restrict__ resbf,
    const float* __restrict__ g, const float* __restrict__ be,
    void* __restrict__ outp)
{
  __shared__ __align__(16) char smem[24576];  // As 128x32 (8KB) + Bs 256x32 (16KB), linear
  char* As = smem;
  char* Bs = smem + 8192;
  const int t = threadIdx.x, lane = t & 63, wid = t >> 6;
  const int c = lane & 15, q4 = lane >> 4;
  const int m0 = blockIdx.x * 128;
  const int wr = wid * 32;
  const f32x4_t zero = {0.f, 0.f, 0.f, 0.f};

  f32x4_t acc[2][16];
#pragma unroll
  for (int fi = 0; fi < 2; ++fi)
#pragma unroll
    for (int fj = 0; fj < 16; ++fj) acc[fi][fj] = zero;

  for (int k0 = 0; k0 < KK; k0 += 32) {
#pragma unroll
    for (int i = 0; i < 2; ++i) {
      int chunk = (wid * 2 + i) * 64 + lane;
      int row = chunk >> 2, c8 = (chunk & 3) * 8;
      GLOAD_LDS16(A + (size_t)(m0 + row) * KK + k0 + c8, As + (wid * 2 + i) * 1024);
    }
#pragma unroll
    for (int i = 0; i < 4; ++i) {
      int chunk = (wid * 4 + i) * 64 + lane;
      int row = chunk >> 2, c8 = (chunk & 3) * 8;
      GLOAD_LDS16(Bt + (size_t)row * KK + k0 + c8, Bs + (wid * 4 + i) * 1024);
    }
    __syncthreads();
    bf16x8_t af0 = *(const bf16x8_t*)(As + (wr + c) * 64 + q4 * 16);
    bf16x8_t af1 = *(const bf16x8_t*)(As + (wr + 16 + c) * 64 + q4 * 16);
#pragma unroll
    for (int fj = 0; fj < 16; ++fj) {
      bf16x8_t bf = *(const bf16x8_t*)(Bs + (fj * 16 + c) * 64 + q4 * 16);
      acc[0][fj] = __builtin_amdgcn_mfma_f32_16x16x32_bf16(af0, bf, acc[0][fj], 0, 0, 0);
      acc[1][fj] = __builtin_amdgcn_mfma_f32_16x16x32_bf16(af1, bf, acc[1][fj], 0, 0, 0);
    }
    __syncthreads();
  }

  // ---- epilogue: bias + residual ----
  if (!FFN2) {
    const int b_ = m0 >> 15, h_ = (m0 >> 7) & 255;
#pragma unroll
    for (int fj = 0; fj < 16; ++fj) {
      int n = fj * 16 + c;
      float bv = bias[n];
#pragma unroll
      for (int fi = 0; fi < 2; ++fi) {
        int w0 = wr + fi * 16 + q4 * 4;
        float4 lr = *(const float4*)(leftres + (((size_t)b_ * 256 + n) * 256 + h_) * 128 + w0);
        float la[4] = {lr.x, lr.y, lr.z, lr.w};
#pragma unroll
        for (int r = 0; r < 4; ++r) acc[fi][fj][r] += bv + la[r];
      }
    }
  } else {
#pragma unroll
    for (int fj = 0; fj < 16; ++fj) {
      int n = fj * 16 + c;
      float bv = bias[n];
#pragma unroll
      for (int fi = 0; fi < 2; ++fi)
#pragma unroll
        for (int r = 0; r < 4; ++r) {
          int row = wr + fi * 16 + q4 * 4 + r;
          acc[fi][fj][r] += bv + __bfloat162float(resbf[(size_t)(m0 + row) * 256 + n]);
        }
    }
  }

  // ---- LayerNorm in-register (row = 16 frags across fj, 16 lanes across c) ----
  float mu[2][4], rs[2][4];
#pragma unroll
  for (int fi = 0; fi < 2; ++fi)
#pragma unroll
    for (int r = 0; r < 4; ++r) {
      float s = 0.f;
#pragma unroll
      for (int fj = 0; fj < 16; ++fj) s += acc[fi][fj][r];
      s += __shfl_xor(s, 1); s += __shfl_xor(s, 2); s += __shfl_xor(s, 4); s += __shfl_xor(s, 8);
      float m_ = s * (1.0f / 256.0f);
      float sq = 0.f;
#pragma unroll
      for (int fj = 0; fj < 16; ++fj) { float d = acc[fi][fj][r] - m_; sq += d * d; }
      sq += __shfl_xor(sq, 1); sq += __shfl_xor(sq, 2); sq += __shfl_xor(sq, 4); sq += __shfl_xor(sq, 8);
      mu[fi][r] = m_;
      rs[fi][r] = rsqrtf(sq * (1.0f / 256.0f) + 1e-5f);
    }
#pragma unroll
  for (int fj = 0; fj < 16; ++fj) {
    int n = fj * 16 + c;
    float gv = g[n], bev = be[n];
#pragma unroll
    for (int fi = 0; fi < 2; ++fi)
#pragma unroll
      for (int r = 0; r < 4; ++r) {
        int row = wr + fi * 16 + q4 * 4 + r;
        float val = (acc[fi][fj][r] - mu[fi][r]) * rs[fi][r] * gv + bev;
        if (FFN2)
          ((float*)outp)[(size_t)(m0 + row) * 256 + n] = val;
        else
          ((__hip_bfloat16*)outp)[(size_t)(m0 + row) * 256 + n] = __float2bfloat16(val);
      }
  }
}

extern "C" void kernel_launch(void* const* d_in, const int* in_sizes, int n_in,
                              void* d_out, int out_size, void* d_ws, size_t ws_size,
                              hipStream_t stream) {
  const float* left   = (const float*)d_in[0];
  const float* right  = (const float*)d_in[1];
  const float* qw     = (const float*)d_in[2];
  const float* kw     = (const float*)d_in[3];
  const float* vw     = (const float*)d_in[4];
  const float* proj_w = (const float*)d_in[5];
  const float* proj_b = (const float*)d_in[6];
  const float* ln1_g  = (const float*)d_in[7];
  const float* ln1_b  = (const float*)d_in[8];
  const float* ln2_g  = (const float*)d_in[9];
  const float* ln2_b  = (const float*)d_in[10];
  const float* w1     = (const float*)d_in[11];
  const float* b1     = (const float*)d_in[12];
  const float* w2     = (const float*)d_in[13];
  const float* b2     = (const float*)d_in[14];

  char* ws = (char*)d_ws;
  __hip_bfloat16* att_out = (__hip_bfloat16*)ws;                 // [M,256]  bf16 [0, 67MB)
  __hip_bfloat16* x1      = (__hip_bfloat16*)(ws + 67108864);    // [M,256]  bf16 [67,134MB)
  __hip_bfloat16* hidden  = (__hip_bfloat16*)(ws + 134217728);   // [M,1024] bf16 [134,402MB)
  __hip_bfloat16* pwT     = (__hip_bfloat16*)(ws + 402653184);   // [256][256]
  __hip_bfloat16* w1T     = pwT + 65536;                         // [1024][256]
  __hip_bfloat16* w2T     = w1T + 262144;                        // [256][1024]

  transpose_bf16<<<256, 256, 0, stream>>>(proj_w, pwT, 256, 256);
  transpose_bf16<<<1024, 256, 0, stream>>>(w1, w1T, 256, 1024);
  transpose_bf16<<<1024, 256, 0, stream>>>(w2, w2T, 1024, 256);

  attn_mfma<<<cB * cH * cHN, 256, 0, stream>>>(left, right, qw, kw, vw, att_out);

  // x1 = LN1(att_out @ proj_w + proj_b + left^T)
  gemm_ln<256, false><<<cM / 128, 256, 0, stream>>>(att_out, pwT, proj_b, left, nullptr,
                                                    ln1_g, ln1_b, x1);
  // hidden = gelu(x1 @ w1 + b1)   (XCD-swizzled 1D grid)
  gemm_gelu<<<8192, 256, 0, stream>>>(x1, w1T, 256, 1024, b1, hidden);
  // out = LN2(hidden @ w2 + b2 + x1)   (fp32 out)
  gemm_ln<1024, true><<<cM / 128, 256, 0, stream>>>(hidden, w2T, b2, nullptr, x1,
                                                    ln2_g, ln2_b, d_out);
}

// Round 7
// 487.286 us; speedup vs baseline: 2.1036x; 1.1026x over previous
//
#include <hip/hip_runtime.h>
#include <hip/hip_bf16.h>

#define DEV __device__ __forceinline__

typedef __attribute__((ext_vector_type(8))) short bf16x8_t;
typedef __attribute__((ext_vector_type(4))) float f32x4_t;

constexpr int cB = 4, cC = 256, cH = 256, cW = 128, cHN = 8, cHS = 32;
constexpr int cM = cB * cH * cW;  // 131072 rows

DEV float bfu(unsigned int b16) { union { unsigned int u; float f; } v; v.u = b16 << 16; return v.f; }
DEV unsigned short f2bb(float f) { union { __hip_bfloat16 h; unsigned short u; } v; v.h = __float2bfloat16(f); return v.u; }
DEV unsigned int pk2(float a, float b) { return (unsigned)f2bb(a) | ((unsigned)f2bb(b) << 16); }

#define GLOAD_LDS16(g, l) \
  __builtin_amdgcn_global_load_lds((const __attribute__((address_space(1))) void*)(g), \
                                   (__attribute__((address_space(3))) void*)(l), 16, 0, 0)

// fast exact-GELU: A&S 7.1.26 erf approximation (max abs err 1.5e-7)
DEV float gelu_fast(float v) {
  float ax = fabsf(v) * 0.7071067811865475f;
  float t = __builtin_amdgcn_rcpf(1.0f + 0.3275911f * ax);
  float poly = ((((1.061405429f * t - 1.453152027f) * t + 1.421413741f) * t
                 - 0.284496736f) * t + 0.254829592f) * t;
  float e = __expf(-ax * ax);
  float erfv = 1.0f - poly * e;  // erf(|v|/sqrt2)
  float phi = 0.5f + 0.5f * copysignf(erfv, v);
  return v * phi;
}

// ---------------- weight transpose + fp32->bf16 ----------------
__global__ __launch_bounds__(256) void transpose_bf16(const float* __restrict__ src,
                                                      __hip_bfloat16* __restrict__ dst,
                                                      int R, int Ccol) {
  int idx = blockIdx.x * 256 + threadIdx.x;
  if (idx < R * Ccol) {
    int r = idx / Ccol, c = idx - r * Ccol;
    dst[c * R + r] = __float2bfloat16(src[idx]);
  }
}

// ---------------- RoPE sin/cos table: [w=128][c=16] -> (sin, cos) ----------------
__global__ __launch_bounds__(256) void rope_init(float2* __restrict__ tab) {
  int i = blockIdx.x * 256 + threadIdx.x;  // 2048 entries
  int w = i >> 4, c = i & 15;
  float inv = expf((float)c * -0.28782313662425572f);  // 100^(-c/16)
  float ang = (float)w * inv;
  tab[i] = make_float2(sinf(ang), cosf(ang));
}

// ---------------- MFMA attention: grouped proj + RoPE + softpick + PV ----------------
// one block per (b, h, g); 256 threads = 4 waves, each wave owns 32 q-rows.
// P and V^T use a PERMUTED k layout: column k stored at pos (k&15)*8 + (k>>4) in both,
// so MFMA's sum over storage order equals the sum over k (order-independent).
constexpr int XL_OFF = 0, XR_OFF = 10240, WQ_OFF = 20480, WK_OFF = 23040, WV_OFF = 25600;
constexpr int QS_OFF = 28160, KS_OFF = 38400, VT_OFF = 0, P_OFF = 10240;
constexpr int SMEM_BYTES = 48640;

__global__ __launch_bounds__(256) void attn_mfma(
    const float* __restrict__ left, const float* __restrict__ right,
    const float* __restrict__ qw, const float* __restrict__ kw, const float* __restrict__ vw,
    const float2* __restrict__ rope,
    __hip_bfloat16* __restrict__ att_out)
{
  __shared__ __align__(16) char smem[SMEM_BYTES];

  const int t = threadIdx.x;
  const int g = blockIdx.x & 7;
  const int h = (blockIdx.x >> 3) & 255;
  const int b = blockIdx.x >> 11;
  const size_t HW = (size_t)cH * cW;

  {
    const float* lb = left  + ((size_t)(b * cC + g * cHS) * cH + h) * cW;
    const float* rb = right + ((size_t)(b * cC + g * cHS) * cH + h) * cW;
    int w = t & 127, ih = (t >> 7) * 16;
    unsigned short* xlrow = (unsigned short*)(smem + XL_OFF) + w * 40 + ih;
    unsigned short* xrrow = (unsigned short*)(smem + XR_OFF) + w * 40 + ih;
#pragma unroll
    for (int i = 0; i < 16; i += 2) {
      float a0 = lb[(size_t)(ih + i) * HW + w], a1 = lb[(size_t)(ih + i + 1) * HW + w];
      *(unsigned int*)(xlrow + i) = pk2(a0, a1);
      float c0 = rb[(size_t)(ih + i) * HW + w], c1 = rb[(size_t)(ih + i + 1) * HW + w];
      *(unsigned int*)(xrrow + i) = pk2(c0, c1);
    }
    int o = t >> 3, i0 = (t & 7) * 4;
    {
      float4 v4 = *(const float4*)(qw + g * 1024 + t * 4);
      unsigned short* dst = (unsigned short*)(smem + WQ_OFF) + o * 40 + i0;
      *(unsigned int*)(dst) = pk2(v4.x, v4.y); *(unsigned int*)(dst + 2) = pk2(v4.z, v4.w);
    }
    {
      float4 v4 = *(const float4*)(kw + g * 1024 + t * 4);
      unsigned short* dst = (unsigned short*)(smem + WK_OFF) + o * 40 + i0;
      *(unsigned int*)(dst) = pk2(v4.x, v4.y); *(unsigned int*)(dst + 2) = pk2(v4.z, v4.w);
    }
    {
      float4 v4 = *(const float4*)(vw + g * 1024 + t * 4);
      unsigned short* dst = (unsigned short*)(smem + WV_OFF) + o * 40 + i0;
      *(unsigned int*)(dst) = pk2(v4.x, v4.y); *(unsigned int*)(dst + 2) = pk2(v4.z, v4.w);
    }
  }
  __syncthreads();  // B1

  const int lane = t & 63, wid = t >> 6;
  const int c = lane & 15, q4 = lane >> 4;
  const int wbase = wid * 32;
  const f32x4_t zero = {0.f, 0.f, 0.f, 0.f};

  bf16x8_t a_xl[2], a_xr[2];
#pragma unroll
  for (int sub = 0; sub < 2; ++sub) {
    a_xl[sub] = *(const bf16x8_t*)(smem + XL_OFF + (wbase + sub * 16 + c) * 80 + q4 * 16);
    a_xr[sub] = *(const bf16x8_t*)(smem + XR_OFF + (wbase + sub * 16 + c) * 80 + q4 * 16);
  }
  f32x4_t qacc[2][2], kacc[2][2];
#pragma unroll
  for (int ot = 0; ot < 2; ++ot) {
    bf16x8_t bq = *(const bf16x8_t*)(smem + WQ_OFF + (ot * 16 + c) * 80 + q4 * 16);
    bf16x8_t bk = *(const bf16x8_t*)(smem + WK_OFF + (ot * 16 + c) * 80 + q4 * 16);
#pragma unroll
    for (int sub = 0; sub < 2; ++sub) {
      qacc[sub][ot] = __builtin_amdgcn_mfma_f32_16x16x32_bf16(a_xl[sub], bq, zero, 0, 0, 0);
      kacc[sub][ot] = __builtin_amdgcn_mfma_f32_16x16x32_bf16(a_xr[sub], bk, zero, 0, 0, 0);
    }
  }
  {
    const float scale = 0.17677669529663687f;  // 1/sqrt(32)
    unsigned short* qsp = (unsigned short*)(smem + QS_OFF);
    unsigned short* ksp = (unsigned short*)(smem + KS_OFF);
#pragma unroll
    for (int sub = 0; sub < 2; ++sub)
#pragma unroll
      for (int r = 0; r < 4; ++r) {
        int w = wbase + sub * 16 + q4 * 4 + r;
        float2 sc = rope[w * 16 + c];
        float sn = sc.x, cs = sc.y;
        float q0 = qacc[sub][0][r], q1 = qacc[sub][1][r];
        qsp[w * 40 + c]      = f2bb((q0 * cs - q1 * sn) * scale);
        qsp[w * 40 + c + 16] = f2bb((q1 * cs + q0 * sn) * scale);
        float k0 = kacc[sub][0][r], k1 = kacc[sub][1][r];
        ksp[w * 40 + c]      = f2bb(k0 * cs - k1 * sn);
        ksp[w * 40 + c + 16] = f2bb(k1 * cs + k0 * sn);
      }
  }
  __syncthreads();  // B2

  // ---- V^T projection; write vT in permuted-k layout: elem (d, k=wp) at pos c*8 + wid*2 + sub
  {
    f32x4_t vacc[2][2];
#pragma unroll
    for (int dt = 0; dt < 2; ++dt) {
      bf16x8_t awv = *(const bf16x8_t*)(smem + WV_OFF + (dt * 16 + c) * 80 + q4 * 16);
#pragma unroll
      for (int sub = 0; sub < 2; ++sub)
        vacc[dt][sub] = __builtin_amdgcn_mfma_f32_16x16x32_bf16(awv, a_xr[sub], zero, 0, 0, 0);
    }
    unsigned short* vtp = (unsigned short*)(smem + VT_OFF);
#pragma unroll
    for (int dt = 0; dt < 2; ++dt)
#pragma unroll
      for (int r = 0; r < 4; ++r) {
        int d = dt * 16 + q4 * 4 + r;
        *(unsigned int*)(vtp + d * 136 + c * 8 + wid * 2) = pk2(vacc[dt][0][r], vacc[dt][1][r]);
      }
  }

  bf16x8_t aq0 = *(const bf16x8_t*)(smem + QS_OFF + (wbase + c) * 80 + q4 * 16);
  bf16x8_t aq1 = *(const bf16x8_t*)(smem + QS_OFF + (wbase + 16 + c) * 80 + q4 * 16);
  f32x4_t sac[2][8];
#pragma unroll
  for (int kt = 0; kt < 8; ++kt) {
    bf16x8_t bk = *(const bf16x8_t*)(smem + KS_OFF + (kt * 16 + c) * 80 + q4 * 16);
    sac[0][kt] = __builtin_amdgcn_mfma_f32_16x16x32_bf16(aq0, bk, zero, 0, 0, 0);
    sac[1][kt] = __builtin_amdgcn_mfma_f32_16x16x32_bf16(aq1, bk, zero, 0, 0, 0);
  }

  float dinv_[2][4];
#pragma unroll
  for (int sub = 0; sub < 2; ++sub)
#pragma unroll
    for (int r = 0; r < 4; ++r) {
      float m = sac[sub][0][r];
#pragma unroll
      for (int kt = 1; kt < 8; ++kt) m = fmaxf(m, sac[sub][kt][r]);
      m = fmaxf(m, __shfl_xor(m, 1));
      m = fmaxf(m, __shfl_xor(m, 2));
      m = fmaxf(m, __shfl_xor(m, 4));
      m = fmaxf(m, __shfl_xor(m, 8));
      float em = __expf(-m);
      float ss = 0.f;
#pragma unroll
      for (int kt = 0; kt < 8; ++kt) {
        float e = __expf(sac[sub][kt][r] - m) - em;
        sac[sub][kt][r] = fmaxf(e, 0.f);
        ss += fabsf(e);
      }
      ss += __shfl_xor(ss, 1);
      ss += __shfl_xor(ss, 2);
      ss += __shfl_xor(ss, 4);
      ss += __shfl_xor(ss, 8);
      dinv_[sub][r] = 1.0f / (ss + 1e-6f);
    }
  __syncthreads();  // B3

  // ---- write P in permuted-k layout: elem (w, k=kt*16+c) at pos c*8+kt -> b128 per (sub,r)
  {
    unsigned short* pp = (unsigned short*)(smem + P_OFF);
#pragma unroll
    for (int sub = 0; sub < 2; ++sub)
#pragma unroll
      for (int r = 0; r < 4; ++r) {
        int w = wbase + sub * 16 + q4 * 4 + r;
        float dv = dinv_[sub][r];
        uint4 u;
        u.x = pk2(sac[sub][0][r] * dv, sac[sub][1][r] * dv);
        u.y = pk2(sac[sub][2][r] * dv, sac[sub][3][r] * dv);
        u.z = pk2(sac[sub][4][r] * dv, sac[sub][5][r] * dv);
        u.w = pk2(sac[sub][6][r] * dv, sac[sub][7][r] * dv);
        *(uint4*)(pp + w * 136 + c * 8) = u;  // byte addr w*272 + c*16, 16B-aligned
      }
  }
  f32x4_t oacc[2][2] = {{zero, zero}, {zero, zero}};
#pragma unroll
  for (int ks = 0; ks < 4; ++ks) {
    bf16x8_t ap0 = *(const bf16x8_t*)(smem + P_OFF + (wbase + c) * 272 + ks * 64 + q4 * 16);
    bf16x8_t ap1 = *(const bf16x8_t*)(smem + P_OFF + (wbase + 16 + c) * 272 + ks * 64 + q4 * 16);
    bf16x8_t bv0 = *(const bf16x8_t*)(smem + VT_OFF + (c) * 272 + ks * 64 + q4 * 16);
    bf16x8_t bv1 = *(const bf16x8_t*)(smem + VT_OFF + (16 + c) * 272 + ks * 64 + q4 * 16);
    oacc[0][0] = __builtin_amdgcn_mfma_f32_16x16x32_bf16(ap0, bv0, oacc[0][0], 0, 0, 0);
    oacc[0][1] = __builtin_amdgcn_mfma_f32_16x16x32_bf16(ap0, bv1, oacc[0][1], 0, 0, 0);
    oacc[1][0] = __builtin_amdgcn_mfma_f32_16x16x32_bf16(ap1, bv0, oacc[1][0], 0, 0, 0);
    oacc[1][1] = __builtin_amdgcn_mfma_f32_16x16x32_bf16(ap1, bv1, oacc[1][1], 0, 0, 0);
  }
  {
    __hip_bfloat16* ob = att_out + ((size_t)(b * cH + h) * cW) * cC + g * cHS;
#pragma unroll
    for (int sub = 0; sub < 2; ++sub)
#pragma unroll
      for (int dt = 0; dt < 2; ++dt)
#pragma unroll
        for (int r = 0; r < 4; ++r) {
          int w = wbase + sub * 16 + q4 * 4 + r;
          ob[(size_t)w * cC + dt * 16 + c] = __float2bfloat16(oacc[sub][dt][r]);
        }
  }
}

// ---------------- GEMM + GELU (ffn1): 128x128 tile, 2-phase dbuf pipeline ----------------
// XCD-swizzled 1D grid; counted vmcnt keeps next tile's loads in flight across barriers.
template<int K>
__global__ __launch_bounds__(256) void gemm_gelu(
    const __hip_bfloat16* __restrict__ A, const __hip_bfloat16* __restrict__ Bt,
    const int N, const float* __restrict__ bias,
    __hip_bfloat16* __restrict__ outb)
{
  __shared__ __align__(16) char smem[32768];  // 2 x (As 8KB + Bs 8KB)
  const int t = threadIdx.x;
  const int id = blockIdx.x;
  const int slot = id >> 3;
  const int by = (id & 7) * 128 + (slot >> 3);
  const int bx = slot & 7;
  const int m0 = by * 128, n0 = bx * 128;
  const int lane = t & 63, wid = t >> 6;
  const int r16 = lane & 15, kq = lane >> 4;
  const int wr = (wid >> 1) * 64, wc = (wid & 1) * 64;
  const int ld_l4 = lane >> 2, ld_c8 = (lane & 3) * 8;

  const __hip_bfloat16* Abase = A  + (size_t)m0 * K + ld_c8;
  const __hip_bfloat16* Bbase = Bt + (size_t)n0 * K + ld_c8;

  f32x4_t acc[4][4];
#pragma unroll
  for (int fi = 0; fi < 4; ++fi)
#pragma unroll
    for (int fj = 0; fj < 4; ++fj) acc[fi][fj] = {0.f, 0.f, 0.f, 0.f};

  auto stage = [&](int buf, int k0) {
    char* As = smem + buf * 16384;
    char* Bs = As + 8192;
#pragma unroll
    for (int i = 0; i < 2; ++i) {
      int chunk = i * 4 + wid;
      int row = chunk * 16 + ld_l4;
      GLOAD_LDS16(Abase + (size_t)row * K + k0, As + chunk * 1024);
      GLOAD_LDS16(Bbase + (size_t)row * K + k0, Bs + chunk * 1024);
    }
  };

  constexpr int NK = K >> 5;
  stage(0, 0);
  for (int tt = 0; tt < NK; ++tt) {
    if (tt + 1 < NK) {
      stage((tt + 1) & 1, (tt + 1) << 5);
      asm volatile("s_waitcnt vmcnt(4)" ::: "memory");  // cur tile landed; next 4 in flight
    } else {
      asm volatile("s_waitcnt vmcnt(0)" ::: "memory");
    }
    __builtin_amdgcn_s_barrier();
    char* As = smem + (tt & 1) * 16384;
    char* Bs = As + 8192;
    bf16x8_t af[4], bf[4];
#pragma unroll
    for (int fi = 0; fi < 4; ++fi)
      af[fi] = *(const bf16x8_t*)(As + (wr + fi * 16 + r16) * 64 + kq * 16);
#pragma unroll
    for (int fj = 0; fj < 4; ++fj)
      bf[fj] = *(const bf16x8_t*)(Bs + (wc + fj * 16 + r16) * 64 + kq * 16);
#pragma unroll
    for (int fi = 0; fi < 4; ++fi)
#pragma unroll
      for (int fj = 0; fj < 4; ++fj)
        acc[fi][fj] = __builtin_amdgcn_mfma_f32_16x16x32_bf16(af[fi], bf[fj], acc[fi][fj], 0, 0, 0);
    __builtin_amdgcn_s_barrier();  // WAR: all reads done before next stage overwrites
  }

#pragma unroll
  for (int fi = 0; fi < 4; ++fi)
#pragma unroll
    for (int fj = 0; fj < 4; ++fj) {
      int nn = n0 + wc + fj * 16 + r16;
      float bias_v = bias[nn];
      int mbase = m0 + wr + fi * 16 + kq * 4;
#pragma unroll
      for (int r = 0; r < 4; ++r)
        outb[(size_t)(mbase + r) * N + nn] = __float2bfloat16(gelu_fast(acc[fi][fj][r] + bias_v));
    }
}

// ---------------- full-row GEMM + residual + LayerNorm, BM=128 x BN=256, 2-phase dbuf ----------------
// FFN2=false: proj — +proj_b +left^T residual, LN1 -> bf16 x1
// FFN2=true : ffn2 — +b2 +x1 residual (bf16), LN2 -> fp32 d_out
template<int KK, bool FFN2>
__global__ __launch_bounds__(256, 2) void gemm_ln(
    const __hip_bfloat16* __restrict__ A, const __hip_bfloat16* __restrict__ Bt,
    const float* __restrict__ bias, const float* __restrict__ leftres,
    const __hip_bfloat16* __restrict__ resbf,
    const float* __restrict__ g, const float* __restrict__ be,
    void* __restrict__ outp)
{
  __shared__ __align__(16) char smem[49152];  // 2 x (As 8KB + Bs 16KB)
  const int t = threadIdx.x, lane = t & 63, wid = t >> 6;
  const int c = lane & 15, q4 = lane >> 4;
  const int m0 = blockIdx.x * 128;
  const int wr = wid * 32;
  const f32x4_t zero = {0.f, 0.f, 0.f, 0.f};

  f32x4_t acc[2][16];
#pragma unroll
  for (int fi = 0; fi < 2; ++fi)
#pragma unroll
    for (int fj = 0; fj < 16; ++fj) acc[fi][fj] = zero;

  auto stage = [&](int buf, int k0) {
    char* As = smem + buf * 24576;
    char* Bs = As + 8192;
#pragma unroll
    for (int i = 0; i < 2; ++i) {
      int chunk = (wid * 2 + i) * 64 + lane;
      int row = chunk >> 2, c8 = (chunk & 3) * 8;
      GLOAD_LDS16(A + (size_t)(m0 + row) * KK + k0 + c8, As + (wid * 2 + i) * 1024);
    }
#pragma unroll
    for (int i = 0; i < 4; ++i) {
      int chunk = (wid * 4 + i) * 64 + lane;
      int row = chunk >> 2, c8 = (chunk & 3) * 8;
      GLOAD_LDS16(Bt + (size_t)row * KK + k0 + c8, Bs + (wid * 4 + i) * 1024);
    }
  };

  constexpr int NK = KK >> 5;
  stage(0, 0);
  for (int tt = 0; tt < NK; ++tt) {
    if (tt + 1 < NK) {
      stage((tt + 1) & 1, (tt + 1) << 5);
      asm volatile("s_waitcnt vmcnt(6)" ::: "memory");
    } else {
      asm volatile("s_waitcnt vmcnt(0)" ::: "memory");
    }
    __builtin_amdgcn_s_barrier();
    char* As = smem + (tt & 1) * 24576;
    char* Bs = As + 8192;
    bf16x8_t af0 = *(const bf16x8_t*)(As + (wr + c) * 64 + q4 * 16);
    bf16x8_t af1 = *(const bf16x8_t*)(As + (wr + 16 + c) * 64 + q4 * 16);
#pragma unroll
    for (int fj = 0; fj < 16; ++fj) {
      bf16x8_t bf = *(const bf16x8_t*)(Bs + (fj * 16 + c) * 64 + q4 * 16);
      acc[0][fj] = __builtin_amdgcn_mfma_f32_16x16x32_bf16(af0, bf, acc[0][fj], 0, 0, 0);
      acc[1][fj] = __builtin_amdgcn_mfma_f32_16x16x32_bf16(af1, bf, acc[1][fj], 0, 0, 0);
    }
    __builtin_amdgcn_s_barrier();
  }

  // ---- epilogue: bias + residual ----
  if (!FFN2) {
    const int b_ = m0 >> 15, h_ = (m0 >> 7) & 255;
#pragma unroll
    for (int fj = 0; fj < 16; ++fj) {
      int n = fj * 16 + c;
      float bv = bias[n];
#pragma unroll
      for (int fi = 0; fi < 2; ++fi) {
        int w0 = wr + fi * 16 + q4 * 4;
        float4 lr = *(const float4*)(leftres + (((size_t)b_ * 256 + n) * 256 + h_) * 128 + w0);
        float la[4] = {lr.x, lr.y, lr.z, lr.w};
#pragma unroll
        for (int r = 0; r < 4; ++r) acc[fi][fj][r] += bv + la[r];
      }
    }
  } else {
#pragma unroll
    for (int fj = 0; fj < 16; ++fj) {
      int n = fj * 16 + c;
      float bv = bias[n];
#pragma unroll
      for (int fi = 0; fi < 2; ++fi)
#pragma unroll
        for (int r = 0; r < 4; ++r) {
          int row = wr + fi * 16 + q4 * 4 + r;
          acc[fi][fj][r] += bv + __bfloat162float(resbf[(size_t)(m0 + row) * 256 + n]);
        }
    }
  }

  // ---- LayerNorm in-register ----
  float mu[2][4], rs[2][4];
#pragma unroll
  for (int fi = 0; fi < 2; ++fi)
#pragma unroll
    for (int r = 0; r < 4; ++r) {
      float s = 0.f;
#pragma unroll
      for (int fj = 0; fj < 16; ++fj) s += acc[fi][fj][r];
      s += __shfl_xor(s, 1); s += __shfl_xor(s, 2); s += __shfl_xor(s, 4); s += __shfl_xor(s, 8);
      float m_ = s * (1.0f / 256.0f);
      float sq = 0.f;
#pragma unroll
      for (int fj = 0; fj < 16; ++fj) { float d = acc[fi][fj][r] - m_; sq += d * d; }
      sq += __shfl_xor(sq, 1); sq += __shfl_xor(sq, 2); sq += __shfl_xor(sq, 4); sq += __shfl_xor(sq, 8);
      mu[fi][r] = m_;
      rs[fi][r] = rsqrtf(sq * (1.0f / 256.0f) + 1e-5f);
    }
#pragma unroll
  for (int fj = 0; fj < 16; ++fj) {
    int n = fj * 16 + c;
    float gv = g[n], bev = be[n];
#pragma unroll
    for (int fi = 0; fi < 2; ++fi)
#pragma unroll
      for (int r = 0; r < 4; ++r) {
        int row = wr + fi * 16 + q4 * 4 + r;
        float val = (acc[fi][fj][r] - mu[fi][r]) * rs[fi][r] * gv + bev;
        if (FFN2)
          ((float*)outp)[(size_t)(m0 + row) * 256 + n] = val;
        else
          ((__hip_bfloat16*)outp)[(size_t)(m0 + row) * 256 + n] = __float2bfloat16(val);
      }
  }
}

extern "C" void kernel_launch(void* const* d_in, const int* in_sizes, int n_in,
                              void* d_out, int out_size, void* d_ws, size_t ws_size,
                              hipStream_t stream) {
  const float* left   = (const float*)d_in[0];
  const float* right  = (const float*)d_in[1];
  const float* qw     = (const float*)d_in[2];
  const float* kw     = (const float*)d_in[3];
  const float* vw     = (const float*)d_in[4];
  const float* proj_w = (const float*)d_in[5];
  const float* proj_b = (const float*)d_in[6];
  const float* ln1_g  = (const float*)d_in[7];
  const float* ln1_b  = (const float*)d_in[8];
  const float* ln2_g  = (const float*)d_in[9];
  const float* ln2_b  = (const float*)d_in[10];
  const float* w1     = (const float*)d_in[11];
  const float* b1     = (const float*)d_in[12];
  const float* w2     = (const float*)d_in[13];
  const float* b2     = (const float*)d_in[14];

  char* ws = (char*)d_ws;
  __hip_bfloat16* att_out = (__hip_bfloat16*)ws;                 // [M,256]  bf16 [0, 67MB)
  __hip_bfloat16* x1      = (__hip_bfloat16*)(ws + 67108864);    // [M,256]  bf16 [67,134MB)
  __hip_bfloat16* hidden  = (__hip_bfloat16*)(ws + 134217728);   // [M,1024] bf16 [134,402MB)
  float2*         rope    = (float2*)(ws + 134217728);           // 16KB, lifetime disjoint from hidden
  __hip_bfloat16* pwT     = (__hip_bfloat16*)(ws + 402653184);   // [256][256]
  __hip_bfloat16* w1T     = pwT + 65536;                         // [1024][256]
  __hip_bfloat16* w2T     = w1T + 262144;                        // [256][1024]

  transpose_bf16<<<256, 256, 0, stream>>>(proj_w, pwT, 256, 256);
  transpose_bf16<<<1024, 256, 0, stream>>>(w1, w1T, 256, 1024);
  transpose_bf16<<<1024, 256, 0, stream>>>(w2, w2T, 1024, 256);
  rope_init<<<8, 256, 0, stream>>>(rope);

  attn_mfma<<<cB * cH * cHN, 256, 0, stream>>>(left, right, qw, kw, vw, rope, att_out);

  // x1 = LN1(att_out @ proj_w + proj_b + left^T)
  gemm_ln<256, false><<<cM / 128, 256, 0, stream>>>(att_out, pwT, proj_b, left, nullptr,
                                                    ln1_g, ln1_b, x1);
  // hidden = gelu(x1 @ w1 + b1)   (XCD-swizzled 1D grid)
  gemm_gelu<256><<<8192, 256, 0, stream>>>(x1, w1T, 1024, b1, hidden);
  // out = LN2(hidden @ w2 + b2 + x1)   (fp32 out)
  gemm_ln<1024, true><<<cM / 128, 256, 0, stream>>>(hidden, w2T, b2, nullptr, x1,
                                                    ln2_g, ln2_b, d_out);
}

// Round 8
// 483.550 us; speedup vs baseline: 2.1199x; 1.0077x over previous
//
#include <hip/hip_runtime.h>
#include <hip/hip_bf16.h>

#define DEV __device__ __forceinline__

typedef __attribute__((ext_vector_type(8))) short bf16x8_t;
typedef __attribute__((ext_vector_type(4))) float f32x4_t;

constexpr int cB = 4, cC = 256, cH = 256, cW = 128, cHN = 8, cHS = 32;
constexpr int cM = cB * cH * cW;  // 131072 rows

DEV float bfu(unsigned int b16) { union { unsigned int u; float f; } v; v.u = b16 << 16; return v.f; }
DEV unsigned short f2bb(float f) { union { __hip_bfloat16 h; unsigned short u; } v; v.h = __float2bfloat16(f); return v.u; }
DEV unsigned int pk2(float a, float b) { return (unsigned)f2bb(a) | ((unsigned)f2bb(b) << 16); }

#define GLOAD_LDS16(g, l) \
  __builtin_amdgcn_global_load_lds((const __attribute__((address_space(1))) void*)(g), \
                                   (__attribute__((address_space(3))) void*)(l), 16, 0, 0)

// fast exact-GELU: A&S 7.1.26 erf approximation (max abs err 1.5e-7)
DEV float gelu_fast(float v) {
  float ax = fabsf(v) * 0.7071067811865475f;
  float t = __builtin_amdgcn_rcpf(1.0f + 0.3275911f * ax);
  float poly = ((((1.061405429f * t - 1.453152027f) * t + 1.421413741f) * t
                 - 0.284496736f) * t + 0.254829592f) * t;
  float e = __expf(-ax * ax);
  float erfv = 1.0f - poly * e;  // erf(|v|/sqrt2)
  float phi = 0.5f + 0.5f * copysignf(erfv, v);
  return v * phi;
}

// ---------------- weight transpose + fp32->bf16 ----------------
__global__ __launch_bounds__(256) void transpose_bf16(const float* __restrict__ src,
                                                      __hip_bfloat16* __restrict__ dst,
                                                      int R, int Ccol) {
  int idx = blockIdx.x * 256 + threadIdx.x;
  if (idx < R * Ccol) {
    int r = idx / Ccol, c = idx - r * Ccol;
    dst[c * R + r] = __float2bfloat16(src[idx]);
  }
}

// ---------------- RoPE sin/cos table: [w=128][c=16] -> (sin, cos) ----------------
__global__ __launch_bounds__(256) void rope_init(float2* __restrict__ tab) {
  int i = blockIdx.x * 256 + threadIdx.x;  // 2048 entries
  int w = i >> 4, c = i & 15;
  float inv = expf((float)c * -0.28782313662425572f);  // 100^(-c/16)
  float ang = (float)w * inv;
  tab[i] = make_float2(sinf(ang), cosf(ang));
}

// ---------------- MFMA attention: grouped proj + RoPE + softpick + PV ----------------
constexpr int XL_OFF = 0, XR_OFF = 10240, WQ_OFF = 20480, WK_OFF = 23040, WV_OFF = 25600;
constexpr int QS_OFF = 28160, KS_OFF = 38400, VT_OFF = 0, P_OFF = 10240;
constexpr int SMEM_BYTES = 48640;

__global__ __launch_bounds__(256) void attn_mfma(
    const float* __restrict__ left, const float* __restrict__ right,
    const float* __restrict__ qw, const float* __restrict__ kw, const float* __restrict__ vw,
    const float2* __restrict__ rope,
    __hip_bfloat16* __restrict__ att_out)
{
  __shared__ __align__(16) char smem[SMEM_BYTES];

  const int t = threadIdx.x;
  const int g = blockIdx.x & 7;
  const int h = (blockIdx.x >> 3) & 255;
  const int b = blockIdx.x >> 11;
  const size_t HW = (size_t)cH * cW;

  {
    const float* lb = left  + ((size_t)(b * cC + g * cHS) * cH + h) * cW;
    const float* rb = right + ((size_t)(b * cC + g * cHS) * cH + h) * cW;
    int w = t & 127, ih = (t >> 7) * 16;
    unsigned short* xlrow = (unsigned short*)(smem + XL_OFF) + w * 40 + ih;
    unsigned short* xrrow = (unsigned short*)(smem + XR_OFF) + w * 40 + ih;
#pragma unroll
    for (int i = 0; i < 16; i += 2) {
      float a0 = lb[(size_t)(ih + i) * HW + w], a1 = lb[(size_t)(ih + i + 1) * HW + w];
      *(unsigned int*)(xlrow + i) = pk2(a0, a1);
      float c0 = rb[(size_t)(ih + i) * HW + w], c1 = rb[(size_t)(ih + i + 1) * HW + w];
      *(unsigned int*)(xrrow + i) = pk2(c0, c1);
    }
    int o = t >> 3, i0 = (t & 7) * 4;
    {
      float4 v4 = *(const float4*)(qw + g * 1024 + t * 4);
      unsigned short* dst = (unsigned short*)(smem + WQ_OFF) + o * 40 + i0;
      *(unsigned int*)(dst) = pk2(v4.x, v4.y); *(unsigned int*)(dst + 2) = pk2(v4.z, v4.w);
    }
    {
      float4 v4 = *(const float4*)(kw + g * 1024 + t * 4);
      unsigned short* dst = (unsigned short*)(smem + WK_OFF) + o * 40 + i0;
      *(unsigned int*)(dst) = pk2(v4.x, v4.y); *(unsigned int*)(dst + 2) = pk2(v4.z, v4.w);
    }
    {
      float4 v4 = *(const float4*)(vw + g * 1024 + t * 4);
      unsigned short* dst = (unsigned short*)(smem + WV_OFF) + o * 40 + i0;
      *(unsigned int*)(dst) = pk2(v4.x, v4.y); *(unsigned int*)(dst + 2) = pk2(v4.z, v4.w);
    }
  }
  __syncthreads();  // B1

  const int lane = t & 63, wid = t >> 6;
  const int c = lane & 15, q4 = lane >> 4;
  const int wbase = wid * 32;
  const f32x4_t zero = {0.f, 0.f, 0.f, 0.f};

  bf16x8_t a_xl[2], a_xr[2];
#pragma unroll
  for (int sub = 0; sub < 2; ++sub) {
    a_xl[sub] = *(const bf16x8_t*)(smem + XL_OFF + (wbase + sub * 16 + c) * 80 + q4 * 16);
    a_xr[sub] = *(const bf16x8_t*)(smem + XR_OFF + (wbase + sub * 16 + c) * 80 + q4 * 16);
  }
  f32x4_t qacc[2][2], kacc[2][2];
#pragma unroll
  for (int ot = 0; ot < 2; ++ot) {
    bf16x8_t bq = *(const bf16x8_t*)(smem + WQ_OFF + (ot * 16 + c) * 80 + q4 * 16);
    bf16x8_t bk = *(const bf16x8_t*)(smem + WK_OFF + (ot * 16 + c) * 80 + q4 * 16);
#pragma unroll
    for (int sub = 0; sub < 2; ++sub) {
      qacc[sub][ot] = __builtin_amdgcn_mfma_f32_16x16x32_bf16(a_xl[sub], bq, zero, 0, 0, 0);
      kacc[sub][ot] = __builtin_amdgcn_mfma_f32_16x16x32_bf16(a_xr[sub], bk, zero, 0, 0, 0);
    }
  }
  {
    const float scale = 0.17677669529663687f;  // 1/sqrt(32)
    unsigned short* qsp = (unsigned short*)(smem + QS_OFF);
    unsigned short* ksp = (unsigned short*)(smem + KS_OFF);
#pragma unroll
    for (int sub = 0; sub < 2; ++sub)
#pragma unroll
      for (int r = 0; r < 4; ++r) {
        int w = wbase + sub * 16 + q4 * 4 + r;
        float2 sc = rope[w * 16 + c];
        float sn = sc.x, cs = sc.y;
        float q0 = qacc[sub][0][r], q1 = qacc[sub][1][r];
        qsp[w * 40 + c]      = f2bb((q0 * cs - q1 * sn) * scale);
        qsp[w * 40 + c + 16] = f2bb((q1 * cs + q0 * sn) * scale);
        float k0 = kacc[sub][0][r], k1 = kacc[sub][1][r];
        ksp[w * 40 + c]      = f2bb(k0 * cs - k1 * sn);
        ksp[w * 40 + c + 16] = f2bb(k1 * cs + k0 * sn);
      }
  }
  __syncthreads();  // B2

  // ---- V^T projection; permuted-k layout: elem (d, k=wp) at pos c*8 + wid*2 + sub
  {
    f32x4_t vacc[2][2];
#pragma unroll
    for (int dt = 0; dt < 2; ++dt) {
      bf16x8_t awv = *(const bf16x8_t*)(smem + WV_OFF + (dt * 16 + c) * 80 + q4 * 16);
#pragma unroll
      for (int sub = 0; sub < 2; ++sub)
        vacc[dt][sub] = __builtin_amdgcn_mfma_f32_16x16x32_bf16(awv, a_xr[sub], zero, 0, 0, 0);
    }
    unsigned short* vtp = (unsigned short*)(smem + VT_OFF);
#pragma unroll
    for (int dt = 0; dt < 2; ++dt)
#pragma unroll
      for (int r = 0; r < 4; ++r) {
        int d = dt * 16 + q4 * 4 + r;
        *(unsigned int*)(vtp + d * 136 + c * 8 + wid * 2) = pk2(vacc[dt][0][r], vacc[dt][1][r]);
      }
  }

  bf16x8_t aq0 = *(const bf16x8_t*)(smem + QS_OFF + (wbase + c) * 80 + q4 * 16);
  bf16x8_t aq1 = *(const bf16x8_t*)(smem + QS_OFF + (wbase + 16 + c) * 80 + q4 * 16);
  f32x4_t sac[2][8];
#pragma unroll
  for (int kt = 0; kt < 8; ++kt) {
    bf16x8_t bk = *(const bf16x8_t*)(smem + KS_OFF + (kt * 16 + c) * 80 + q4 * 16);
    sac[0][kt] = __builtin_amdgcn_mfma_f32_16x16x32_bf16(aq0, bk, zero, 0, 0, 0);
    sac[1][kt] = __builtin_amdgcn_mfma_f32_16x16x32_bf16(aq1, bk, zero, 0, 0, 0);
  }

  float dinv_[2][4];
#pragma unroll
  for (int sub = 0; sub < 2; ++sub)
#pragma unroll
    for (int r = 0; r < 4; ++r) {
      float m = sac[sub][0][r];
#pragma unroll
      for (int kt = 1; kt < 8; ++kt) m = fmaxf(m, sac[sub][kt][r]);
      m = fmaxf(m, __shfl_xor(m, 1));
      m = fmaxf(m, __shfl_xor(m, 2));
      m = fmaxf(m, __shfl_xor(m, 4));
      m = fmaxf(m, __shfl_xor(m, 8));
      float em = __expf(-m);
      float ss = 0.f;
#pragma unroll
      for (int kt = 0; kt < 8; ++kt) {
        float e = __expf(sac[sub][kt][r] - m) - em;
        sac[sub][kt][r] = fmaxf(e, 0.f);
        ss += fabsf(e);
      }
      ss += __shfl_xor(ss, 1);
      ss += __shfl_xor(ss, 2);
      ss += __shfl_xor(ss, 4);
      ss += __shfl_xor(ss, 8);
      dinv_[sub][r] = 1.0f / (ss + 1e-6f);
    }
  __syncthreads();  // B3

  // ---- write P in permuted-k layout ----
  {
    unsigned short* pp = (unsigned short*)(smem + P_OFF);
#pragma unroll
    for (int sub = 0; sub < 2; ++sub)
#pragma unroll
      for (int r = 0; r < 4; ++r) {
        int w = wbase + sub * 16 + q4 * 4 + r;
        float dv = dinv_[sub][r];
        uint4 u;
        u.x = pk2(sac[sub][0][r] * dv, sac[sub][1][r] * dv);
        u.y = pk2(sac[sub][2][r] * dv, sac[sub][3][r] * dv);
        u.z = pk2(sac[sub][4][r] * dv, sac[sub][5][r] * dv);
        u.w = pk2(sac[sub][6][r] * dv, sac[sub][7][r] * dv);
        *(uint4*)(pp + w * 136 + c * 8) = u;
      }
  }
  f32x4_t oacc[2][2] = {{zero, zero}, {zero, zero}};
#pragma unroll
  for (int ks = 0; ks < 4; ++ks) {
    bf16x8_t ap0 = *(const bf16x8_t*)(smem + P_OFF + (wbase + c) * 272 + ks * 64 + q4 * 16);
    bf16x8_t ap1 = *(const bf16x8_t*)(smem + P_OFF + (wbase + 16 + c) * 272 + ks * 64 + q4 * 16);
    bf16x8_t bv0 = *(const bf16x8_t*)(smem + VT_OFF + (c) * 272 + ks * 64 + q4 * 16);
    bf16x8_t bv1 = *(const bf16x8_t*)(smem + VT_OFF + (16 + c) * 272 + ks * 64 + q4 * 16);
    oacc[0][0] = __builtin_amdgcn_mfma_f32_16x16x32_bf16(ap0, bv0, oacc[0][0], 0, 0, 0);
    oacc[0][1] = __builtin_amdgcn_mfma_f32_16x16x32_bf16(ap0, bv1, oacc[0][1], 0, 0, 0);
    oacc[1][0] = __builtin_amdgcn_mfma_f32_16x16x32_bf16(ap1, bv0, oacc[1][0], 0, 0, 0);
    oacc[1][1] = __builtin_amdgcn_mfma_f32_16x16x32_bf16(ap1, bv1, oacc[1][1], 0, 0, 0);
  }
  {
    __hip_bfloat16* ob = att_out + ((size_t)(b * cH + h) * cW) * cC + g * cHS;
#pragma unroll
    for (int sub = 0; sub < 2; ++sub)
#pragma unroll
      for (int dt = 0; dt < 2; ++dt)
#pragma unroll
        for (int r = 0; r < 4; ++r) {
          int w = wbase + sub * 16 + q4 * 4 + r;
          ob[(size_t)w * cC + dt * 16 + c] = __float2bfloat16(oacc[sub][dt][r]);
        }
  }
}

// ---------------- persistent-B GEMM + GELU (ffn1): hidden = gelu(x1 @ w1T^T + b1) ----------------
// grid 1024 = 8 n-stripes x 128 m-groups; id = stripe*128 + mgroup -> id%8 = mgroup%8, so the
// 8 stripe-siblings sharing an A band land on the same XCD (L2 reuse of A).
// B stripe [128n][256k] (64KB) staged ONCE, XOR-swizzled (slot ^= row&7) -> 2-way-free reads.
// A m-tiles [128][32] double-buffered, swizzled (slot ^= (row>>1)&3), counted vmcnt pipeline.
__global__ __launch_bounds__(256) void ffn1_persist(
    const __hip_bfloat16* __restrict__ A, const __hip_bfloat16* __restrict__ Bt,
    const float* __restrict__ bias, __hip_bfloat16* __restrict__ outb)
{
  constexpr int K = 256, N = 1024;
  __shared__ __align__(16) char smem[81920];  // Bres 64KB + A dbuf 2x8KB
  char* Bres = smem;
  char* Abuf = smem + 65536;
  const int t = threadIdx.x, lane = t & 63, wid = t >> 6;
  const int stripe = blockIdx.x >> 7, mgroup = blockIdx.x & 127;
  const int n0 = stripe * 128;
  const int mbase0 = mgroup * 1024;  // 8 m-tiles x 128 rows
  const int r16 = lane & 15, kq = lane >> 4;
  const int wr = (wid >> 1) * 64, wc = (wid & 1) * 64;
  const f32x4_t zero = {0.f, 0.f, 0.f, 0.f};

  // ---- stage B stripe once (swizzled source, linear dest) ----
#pragma unroll
  for (int i = 0; i < 16; ++i) {
    int chunk = i * 4 + wid;                 // 64 chunks x 1024B
    int row = chunk * 2 + (lane >> 5);       // 2 rows (512B) per chunk
    int slot = lane & 31;
    GLOAD_LDS16(Bt + (size_t)(n0 + row) * K + (slot ^ (row & 7)) * 8, Bres + chunk * 1024);
  }

  auto stageA = [&](int buf, int step) {     // step = mt*8 + kk over [0,64)
    int m0 = mbase0 + (step >> 3) * 128;
    int kk = step & 7;
    char* dst = Abuf + buf * 8192;
#pragma unroll
    for (int i = 0; i < 2; ++i) {
      int chunk = i * 4 + wid;               // 8 chunks x 1024B
      int row = chunk * 16 + (lane >> 2);    // 16 rows (64B) per chunk
      int slot = lane & 3;
      GLOAD_LDS16(A + (size_t)(m0 + row) * K + kk * 32 + (slot ^ ((row >> 1) & 3)) * 8,
                  dst + chunk * 1024);
    }
  };
  stageA(0, 0);

  // hoist bias (constant across m-tiles)
  float bv4[4];
#pragma unroll
  for (int fj = 0; fj < 4; ++fj) bv4[fj] = bias[n0 + wc + fj * 16 + r16];

  f32x4_t acc[4][4];
#pragma unroll
  for (int fi = 0; fi < 4; ++fi)
#pragma unroll
    for (int fj = 0; fj < 4; ++fj) acc[fi][fj] = zero;

  for (int step = 0; step < 64; ++step) {
    if (step + 1 < 64) {
      stageA((step + 1) & 1, step + 1);
      asm volatile("s_waitcnt vmcnt(2)" ::: "memory");  // current tile (and B) landed
    } else {
      asm volatile("s_waitcnt vmcnt(0)" ::: "memory");
    }
    __builtin_amdgcn_s_barrier();

    const int kk = step & 7;
    char* As = Abuf + (step & 1) * 8192;
    bf16x8_t af[4], bf[4];
#pragma unroll
    for (int fi = 0; fi < 4; ++fi) {
      int rr = wr + fi * 16 + r16;
      af[fi] = *(const bf16x8_t*)(As + rr * 64 + ((kq ^ ((rr >> 1) & 3)) * 16));
    }
#pragma unroll
    for (int fj = 0; fj < 4; ++fj) {
      int rr = wc + fj * 16 + r16;
      bf[fj] = *(const bf16x8_t*)(Bres + rr * 512 + (((kk * 4 + kq) ^ (rr & 7)) * 16));
    }
#pragma unroll
    for (int fi = 0; fi < 4; ++fi)
#pragma unroll
      for (int fj = 0; fj < 4; ++fj)
        acc[fi][fj] = __builtin_amdgcn_mfma_f32_16x16x32_bf16(af[fi], bf[fj], acc[fi][fj], 0, 0, 0);
    __builtin_amdgcn_s_barrier();  // WAR before next stage overwrites other A buffer

    if (kk == 7) {
      // epilogue for this m-tile (overlaps next tile's in-flight A loads)
      int m0 = mbase0 + (step >> 3) * 128;
#pragma unroll
      for (int fi = 0; fi < 4; ++fi)
#pragma unroll
        for (int fj = 0; fj < 4; ++fj) {
          int nn = n0 + wc + fj * 16 + r16;
          int mb = m0 + wr + fi * 16 + kq * 4;
#pragma unroll
          for (int r = 0; r < 4; ++r)
            outb[(size_t)(mb + r) * N + nn] = __float2bfloat16(gelu_fast(acc[fi][fj][r] + bv4[fj]));
          acc[fi][fj] = zero;
        }
    }
  }
}

// ---------------- full-row GEMM + residual + LayerNorm, BM=128 x BN=256, 2-phase dbuf ----------------
// FFN2=false: proj — +proj_b +left^T residual, LN1 -> bf16 x1
// FFN2=true : ffn2 — +b2 +x1 residual (bf16), LN2 -> fp32 d_out
template<int KK, bool FFN2>
__global__ __launch_bounds__(256, 2) void gemm_ln(
    const __hip_bfloat16* __restrict__ A, const __hip_bfloat16* __restrict__ Bt,
    const float* __restrict__ bias, const float* __restrict__ leftres,
    const __hip_bfloat16* __restrict__ resbf,
    const float* __restrict__ g, const float* __restrict__ be,
    void* __restrict__ outp)
{
  __shared__ __align__(16) char smem[49152];  // 2 x (As 8KB + Bs 16KB)
  const int t = threadIdx.x, lane = t & 63, wid = t >> 6;
  const int c = lane & 15, q4 = lane >> 4;
  const int m0 = blockIdx.x * 128;
  const int wr = wid * 32;
  const f32x4_t zero = {0.f, 0.f, 0.f, 0.f};

  f32x4_t acc[2][16];
#pragma unroll
  for (int fi = 0; fi < 2; ++fi)
#pragma unroll
    for (int fj = 0; fj < 16; ++fj) acc[fi][fj] = zero;

  auto stage = [&](int buf, int k0) {
    char* As = smem + buf * 24576;
    char* Bs = As + 8192;
#pragma unroll
    for (int i = 0; i < 2; ++i) {
      int chunk = (wid * 2 + i) * 64 + lane;
      int row = chunk >> 2, c8 = (chunk & 3) * 8;
      GLOAD_LDS16(A + (size_t)(m0 + row) * KK + k0 + c8, As + (wid * 2 + i) * 1024);
    }
#pragma unroll
    for (int i = 0; i < 4; ++i) {
      int chunk = (wid * 4 + i) * 64 + lane;
      int row = chunk >> 2, c8 = (chunk & 3) * 8;
      GLOAD_LDS16(Bt + (size_t)row * KK + k0 + c8, Bs + (wid * 4 + i) * 1024);
    }
  };

  constexpr int NK = KK >> 5;
  stage(0, 0);
  for (int tt = 0; tt < NK; ++tt) {
    if (tt + 1 < NK) {
      stage((tt + 1) & 1, (tt + 1) << 5);
      asm volatile("s_waitcnt vmcnt(6)" ::: "memory");
    } else {
      asm volatile("s_waitcnt vmcnt(0)" ::: "memory");
    }
    __builtin_amdgcn_s_barrier();
    char* As = smem + (tt & 1) * 24576;
    char* Bs = As + 8192;
    bf16x8_t af0 = *(const bf16x8_t*)(As + (wr + c) * 64 + q4 * 16);
    bf16x8_t af1 = *(const bf16x8_t*)(As + (wr + 16 + c) * 64 + q4 * 16);
#pragma unroll
    for (int fj = 0; fj < 16; ++fj) {
      bf16x8_t bf = *(const bf16x8_t*)(Bs + (fj * 16 + c) * 64 + q4 * 16);
      acc[0][fj] = __builtin_amdgcn_mfma_f32_16x16x32_bf16(af0, bf, acc[0][fj], 0, 0, 0);
      acc[1][fj] = __builtin_amdgcn_mfma_f32_16x16x32_bf16(af1, bf, acc[1][fj], 0, 0, 0);
    }
    __builtin_amdgcn_s_barrier();
  }

  // ---- epilogue: bias + residual ----
  if (!FFN2) {
    const int b_ = m0 >> 15, h_ = (m0 >> 7) & 255;
#pragma unroll
    for (int fj = 0; fj < 16; ++fj) {
      int n = fj * 16 + c;
      float bv = bias[n];
#pragma unroll
      for (int fi = 0; fi < 2; ++fi) {
        int w0 = wr + fi * 16 + q4 * 4;
        float4 lr = *(const float4*)(leftres + (((size_t)b_ * 256 + n) * 256 + h_) * 128 + w0);
        float la[4] = {lr.x, lr.y, lr.z, lr.w};
#pragma unroll
        for (int r = 0; r < 4; ++r) acc[fi][fj][r] += bv + la[r];
      }
    }
  } else {
#pragma unroll
    for (int fj = 0; fj < 16; ++fj) {
      int n = fj * 16 + c;
      float bv = bias[n];
#pragma unroll
      for (int fi = 0; fi < 2; ++fi)
#pragma unroll
        for (int r = 0; r < 4; ++r) {
          int row = wr + fi * 16 + q4 * 4 + r;
          acc[fi][fj][r] += bv + __bfloat162float(resbf[(size_t)(m0 + row) * 256 + n]);
        }
    }
  }

  // ---- LayerNorm in-register ----
  float mu[2][4], rs[2][4];
#pragma unroll
  for (int fi = 0; fi < 2; ++fi)
#pragma unroll
    for (int r = 0; r < 4; ++r) {
      float s = 0.f;
#pragma unroll
      for (int fj = 0; fj < 16; ++fj) s += acc[fi][fj][r];
      s += __shfl_xor(s, 1); s += __shfl_xor(s, 2); s += __shfl_xor(s, 4); s += __shfl_xor(s, 8);
      float m_ = s * (1.0f / 256.0f);
      float sq = 0.f;
#pragma unroll
      for (int fj = 0; fj < 16; ++fj) { float d = acc[fi][fj][r] - m_; sq += d * d; }
      sq += __shfl_xor(sq, 1); sq += __shfl_xor(sq, 2); sq += __shfl_xor(sq, 4); sq += __shfl_xor(sq, 8);
      mu[fi][r] = m_;
      rs[fi][r] = rsqrtf(sq * (1.0f / 256.0f) + 1e-5f);
    }
#pragma unroll
  for (int fj = 0; fj < 16; ++fj) {
    int n = fj * 16 + c;
    float gv = g[n], bev = be[n];
#pragma unroll
    for (int fi = 0; fi < 2; ++fi)
#pragma unroll
      for (int r = 0; r < 4; ++r) {
        int row = wr + fi * 16 + q4 * 4 + r;
        float val = (acc[fi][fj][r] - mu[fi][r]) * rs[fi][r] * gv + bev;
        if (FFN2)
          ((float*)outp)[(size_t)(m0 + row) * 256 + n] = val;
        else
          ((__hip_bfloat16*)outp)[(size_t)(m0 + row) * 256 + n] = __float2bfloat16(val);
      }
  }
}

extern "C" void kernel_launch(void* const* d_in, const int* in_sizes, int n_in,
                              void* d_out, int out_size, void* d_ws, size_t ws_size,
                              hipStream_t stream) {
  const float* left   = (const float*)d_in[0];
  const float* right  = (const float*)d_in[1];
  const float* qw     = (const float*)d_in[2];
  const float* kw     = (const float*)d_in[3];
  const float* vw     = (const float*)d_in[4];
  const float* proj_w = (const float*)d_in[5];
  const float* proj_b = (const float*)d_in[6];
  const float* ln1_g  = (const float*)d_in[7];
  const float* ln1_b  = (const float*)d_in[8];
  const float* ln2_g  = (const float*)d_in[9];
  const float* ln2_b  = (const float*)d_in[10];
  const float* w1     = (const float*)d_in[11];
  const float* b1     = (const float*)d_in[12];
  const float* w2     = (const float*)d_in[13];
  const float* b2     = (const float*)d_in[14];

  char* ws = (char*)d_ws;
  __hip_bfloat16* att_out = (__hip_bfloat16*)ws;                 // [M,256]  bf16 [0, 67MB)
  __hip_bfloat16* x1      = (__hip_bfloat16*)(ws + 67108864);    // [M,256]  bf16 [67,134MB)
  __hip_bfloat16* hidden  = (__hip_bfloat16*)(ws + 134217728);   // [M,1024] bf16 [134,402MB)
  float2*         rope    = (float2*)(ws + 134217728);           // 16KB, lifetime disjoint from hidden
  __hip_bfloat16* pwT     = (__hip_bfloat16*)(ws + 402653184);   // [256][256]
  __hip_bfloat16* w1T     = pwT + 65536;                         // [1024][256]
  __hip_bfloat16* w2T     = w1T + 262144;                        // [256][1024]

  transpose_bf16<<<256, 256, 0, stream>>>(proj_w, pwT, 256, 256);
  transpose_bf16<<<1024, 256, 0, stream>>>(w1, w1T, 256, 1024);
  transpose_bf16<<<1024, 256, 0, stream>>>(w2, w2T, 1024, 256);
  rope_init<<<8, 256, 0, stream>>>(rope);

  attn_mfma<<<cB * cH * cHN, 256, 0, stream>>>(left, right, qw, kw, vw, rope, att_out);

  // x1 = LN1(att_out @ proj_w + proj_b + left^T)
  gemm_ln<256, false><<<cM / 128, 256, 0, stream>>>(att_out, pwT, proj_b, left, nullptr,
                                                    ln1_g, ln1_b, x1);
  // hidden = gelu(x1 @ w1 + b1)   (persistent-B, XCD-affine grid)
  ffn1_persist<<<1024, 256, 0, stream>>>(x1, w1T, b1, hidden);
  // out = LN2(hidden @ w2 + b2 + x1)   (fp32 out)
  gemm_ln<1024, true><<<cM / 128, 256, 0, stream>>>(hidden, w2T, b2, nullptr, x1,
                                                    ln2_g, ln2_b, d_out);
}

// Round 10
// 448.444 us; speedup vs baseline: 2.2858x; 1.0783x over previous
//
#include <hip/hip_runtime.h>
#include <hip/hip_bf16.h>

#define DEV __device__ __forceinline__

typedef __attribute__((ext_vector_type(8))) short bf16x8_t;
typedef __attribute__((ext_vector_type(4))) float f32x4_t;

constexpr int cB = 4, cC = 256, cH = 256, cW = 128, cHN = 8, cHS = 32;
constexpr int cM = cB * cH * cW;  // 131072 rows

DEV float bfu(unsigned int b16) { union { unsigned int u; float f; } v; v.u = b16 << 16; return v.f; }
DEV unsigned short f2bb(float f) { union { __hip_bfloat16 h; unsigned short u; } v; v.h = __float2bfloat16(f); return v.u; }
DEV unsigned int pk2(float a, float b) { return (unsigned)f2bb(a) | ((unsigned)f2bb(b) << 16); }

#define GLOAD_LDS16(g, l) \
  __builtin_amdgcn_global_load_lds((const __attribute__((address_space(1))) void*)(g), \
                                   (__attribute__((address_space(3))) void*)(l), 16, 0, 0)

// fast exact-GELU: A&S 7.1.26 erf approximation (max abs err 1.5e-7) — proven absmax 0.031
DEV float gelu_fast(float v) {
  float ax = fabsf(v) * 0.7071067811865475f;
  float t = __builtin_amdgcn_rcpf(1.0f + 0.3275911f * ax);
  float poly = ((((1.061405429f * t - 1.453152027f) * t + 1.421413741f) * t
                 - 0.284496736f) * t + 0.254829592f) * t;
  float e = __expf(-ax * ax);
  float erfv = 1.0f - poly * e;  // erf(|v|/sqrt2)
  float phi = 0.5f + 0.5f * copysignf(erfv, v);
  return v * phi;
}

// ---------------- weight transpose + fp32->bf16 ----------------
__global__ __launch_bounds__(256) void transpose_bf16(const float* __restrict__ src,
                                                      __hip_bfloat16* __restrict__ dst,
                                                      int R, int Ccol) {
  int idx = blockIdx.x * 256 + threadIdx.x;
  if (idx < R * Ccol) {
    int r = idx / Ccol, c = idx - r * Ccol;
    dst[c * R + r] = __float2bfloat16(src[idx]);
  }
}

// transpose for w2 with k-permutation matching ffn1's packed-store layout:
// within each 64-k group, orig k -> pos ((k&15)<<2) | ((k>>4)&3)
__global__ __launch_bounds__(256) void transpose_perm_bf16(const float* __restrict__ src,
                                                           __hip_bfloat16* __restrict__ dst,
                                                           int R, int Ccol) {
  int idx = blockIdx.x * 256 + threadIdx.x;
  if (idx < R * Ccol) {
    int r = idx / Ccol, c = idx - r * Ccol;  // r = k, c = n
    int pk = (r & ~63) | ((r & 15) << 2) | ((r >> 4) & 3);
    dst[c * R + pk] = __float2bfloat16(src[idx]);
  }
}

// ---------------- RoPE sin/cos table: [w=128][c=16] -> (sin, cos) ----------------
__global__ __launch_bounds__(256) void rope_init(float2* __restrict__ tab) {
  int i = blockIdx.x * 256 + threadIdx.x;  // 2048 entries
  int w = i >> 4, c = i & 15;
  float inv = expf((float)c * -0.28782313662425572f);  // 100^(-c/16)
  float ang = (float)w * inv;
  tab[i] = make_float2(sinf(ang), cosf(ang));
}

// ---------------- MFMA attention: grouped proj + RoPE + softpick + PV ----------------
constexpr int XL_OFF = 0, XR_OFF = 10240, WQ_OFF = 20480, WK_OFF = 23040, WV_OFF = 25600;
constexpr int QS_OFF = 28160, KS_OFF = 38400, VT_OFF = 0, P_OFF = 10240;
constexpr int SMEM_BYTES = 48640;

__global__ __launch_bounds__(256) void attn_mfma(
    const float* __restrict__ left, const float* __restrict__ right,
    const float* __restrict__ qw, const float* __restrict__ kw, const float* __restrict__ vw,
    const float2* __restrict__ rope,
    __hip_bfloat16* __restrict__ att_out)
{
  __shared__ __align__(16) char smem[SMEM_BYTES];

  const int t = threadIdx.x;
  const int g = blockIdx.x & 7;
  const int h = (blockIdx.x >> 3) & 255;
  const int b = blockIdx.x >> 11;
  const size_t HW = (size_t)cH * cW;

  {
    const float* lb = left  + ((size_t)(b * cC + g * cHS) * cH + h) * cW;
    const float* rb = right + ((size_t)(b * cC + g * cHS) * cH + h) * cW;
    int w = t & 127, ih = (t >> 7) * 16;
    unsigned short* xlrow = (unsigned short*)(smem + XL_OFF) + w * 40 + ih;
    unsigned short* xrrow = (unsigned short*)(smem + XR_OFF) + w * 40 + ih;
#pragma unroll
    for (int i = 0; i < 16; i += 2) {
      float a0 = lb[(size_t)(ih + i) * HW + w], a1 = lb[(size_t)(ih + i + 1) * HW + w];
      *(unsigned int*)(xlrow + i) = pk2(a0, a1);
      float c0 = rb[(size_t)(ih + i) * HW + w], c1 = rb[(size_t)(ih + i + 1) * HW + w];
      *(unsigned int*)(xrrow + i) = pk2(c0, c1);
    }
    int o = t >> 3, i0 = (t & 7) * 4;
    {
      float4 v4 = *(const float4*)(qw + g * 1024 + t * 4);
      unsigned short* dst = (unsigned short*)(smem + WQ_OFF) + o * 40 + i0;
      *(unsigned int*)(dst) = pk2(v4.x, v4.y); *(unsigned int*)(dst + 2) = pk2(v4.z, v4.w);
    }
    {
      float4 v4 = *(const float4*)(kw + g * 1024 + t * 4);
      unsigned short* dst = (unsigned short*)(smem + WK_OFF) + o * 40 + i0;
      *(unsigned int*)(dst) = pk2(v4.x, v4.y); *(unsigned int*)(dst + 2) = pk2(v4.z, v4.w);
    }
    {
      float4 v4 = *(const float4*)(vw + g * 1024 + t * 4);
      unsigned short* dst = (unsigned short*)(smem + WV_OFF) + o * 40 + i0;
      *(unsigned int*)(dst) = pk2(v4.x, v4.y); *(unsigned int*)(dst + 2) = pk2(v4.z, v4.w);
    }
  }
  __syncthreads();  // B1

  const int lane = t & 63, wid = t >> 6;
  const int c = lane & 15, q4 = lane >> 4;
  const int wbase = wid * 32;
  const f32x4_t zero = {0.f, 0.f, 0.f, 0.f};

  bf16x8_t a_xl[2], a_xr[2];
#pragma unroll
  for (int sub = 0; sub < 2; ++sub) {
    a_xl[sub] = *(const bf16x8_t*)(smem + XL_OFF + (wbase + sub * 16 + c) * 80 + q4 * 16);
    a_xr[sub] = *(const bf16x8_t*)(smem + XR_OFF + (wbase + sub * 16 + c) * 80 + q4 * 16);
  }
  f32x4_t qacc[2][2], kacc[2][2];
#pragma unroll
  for (int ot = 0; ot < 2; ++ot) {
    bf16x8_t bq = *(const bf16x8_t*)(smem + WQ_OFF + (ot * 16 + c) * 80 + q4 * 16);
    bf16x8_t bk = *(const bf16x8_t*)(smem + WK_OFF + (ot * 16 + c) * 80 + q4 * 16);
#pragma unroll
    for (int sub = 0; sub < 2; ++sub) {
      qacc[sub][ot] = __builtin_amdgcn_mfma_f32_16x16x32_bf16(a_xl[sub], bq, zero, 0, 0, 0);
      kacc[sub][ot] = __builtin_amdgcn_mfma_f32_16x16x32_bf16(a_xr[sub], bk, zero, 0, 0, 0);
    }
  }
  {
    const float scale = 0.17677669529663687f;  // 1/sqrt(32)
    unsigned short* qsp = (unsigned short*)(smem + QS_OFF);
    unsigned short* ksp = (unsigned short*)(smem + KS_OFF);
#pragma unroll
    for (int sub = 0; sub < 2; ++sub)
#pragma unroll
      for (int r = 0; r < 4; ++r) {
        int w = wbase + sub * 16 + q4 * 4 + r;
        float2 sc = rope[w * 16 + c];
        float sn = sc.x, cs = sc.y;
        float q0 = qacc[sub][0][r], q1 = qacc[sub][1][r];
        qsp[w * 40 + c]      = f2bb((q0 * cs - q1 * sn) * scale);
        qsp[w * 40 + c + 16] = f2bb((q1 * cs + q0 * sn) * scale);
        float k0 = kacc[sub][0][r], k1 = kacc[sub][1][r];
        ksp[w * 40 + c]      = f2bb(k0 * cs - k1 * sn);
        ksp[w * 40 + c + 16] = f2bb(k1 * cs + k0 * sn);
      }
  }
  __syncthreads();  // B2

  // ---- V^T projection; permuted-k layout: elem (d, k=wp) at pos c*8 + wid*2 + sub
  {
    f32x4_t vacc[2][2];
#pragma unroll
    for (int dt = 0; dt < 2; ++dt) {
      bf16x8_t awv = *(const bf16x8_t*)(smem + WV_OFF + (dt * 16 + c) * 80 + q4 * 16);
#pragma unroll
      for (int sub = 0; sub < 2; ++sub)
        vacc[dt][sub] = __builtin_amdgcn_mfma_f32_16x16x32_bf16(awv, a_xr[sub], zero, 0, 0, 0);
    }
    unsigned short* vtp = (unsigned short*)(smem + VT_OFF);
#pragma unroll
    for (int dt = 0; dt < 2; ++dt)
#pragma unroll
      for (int r = 0; r < 4; ++r) {
        int d = dt * 16 + q4 * 4 + r;
        *(unsigned int*)(vtp + d * 136 + c * 8 + wid * 2) = pk2(vacc[dt][0][r], vacc[dt][1][r]);
      }
  }

  bf16x8_t aq0 = *(const bf16x8_t*)(smem + QS_OFF + (wbase + c) * 80 + q4 * 16);
  bf16x8_t aq1 = *(const bf16x8_t*)(smem + QS_OFF + (wbase + 16 + c) * 80 + q4 * 16);
  f32x4_t sac[2][8];
#pragma unroll
  for (int kt = 0; kt < 8; ++kt) {
    bf16x8_t bk = *(const bf16x8_t*)(smem + KS_OFF + (kt * 16 + c) * 80 + q4 * 16);
    sac[0][kt] = __builtin_amdgcn_mfma_f32_16x16x32_bf16(aq0, bk, zero, 0, 0, 0);
    sac[1][kt] = __builtin_amdgcn_mfma_f32_16x16x32_bf16(aq1, bk, zero, 0, 0, 0);
  }

  float dinv_[2][4];
#pragma unroll
  for (int sub = 0; sub < 2; ++sub)
#pragma unroll
    for (int r = 0; r < 4; ++r) {
      float m = sac[sub][0][r];
#pragma unroll
      for (int kt = 1; kt < 8; ++kt) m = fmaxf(m, sac[sub][kt][r]);
      m = fmaxf(m, __shfl_xor(m, 1));
      m = fmaxf(m, __shfl_xor(m, 2));
      m = fmaxf(m, __shfl_xor(m, 4));
      m = fmaxf(m, __shfl_xor(m, 8));
      float em = __expf(-m);
      float ss = 0.f;
#pragma unroll
      for (int kt = 0; kt < 8; ++kt) {
        float e = __expf(sac[sub][kt][r] - m) - em;
        sac[sub][kt][r] = fmaxf(e, 0.f);
        ss += fabsf(e);
      }
      ss += __shfl_xor(ss, 1);
      ss += __shfl_xor(ss, 2);
      ss += __shfl_xor(ss, 4);
      ss += __shfl_xor(ss, 8);
      dinv_[sub][r] = 1.0f / (ss + 1e-6f);
    }
  __syncthreads();  // B3

  // ---- write P in permuted-k layout ----
  {
    unsigned short* pp = (unsigned short*)(smem + P_OFF);
#pragma unroll
    for (int sub = 0; sub < 2; ++sub)
#pragma unroll
      for (int r = 0; r < 4; ++r) {
        int w = wbase + sub * 16 + q4 * 4 + r;
        float dv = dinv_[sub][r];
        uint4 u;
        u.x = pk2(sac[sub][0][r] * dv, sac[sub][1][r] * dv);
        u.y = pk2(sac[sub][2][r] * dv, sac[sub][3][r] * dv);
        u.z = pk2(sac[sub][4][r] * dv, sac[sub][5][r] * dv);
        u.w = pk2(sac[sub][6][r] * dv, sac[sub][7][r] * dv);
        *(uint4*)(pp + w * 136 + c * 8) = u;
      }
  }
  f32x4_t oacc[2][2] = {{zero, zero}, {zero, zero}};
#pragma unroll
  for (int ks = 0; ks < 4; ++ks) {
    bf16x8_t ap0 = *(const bf16x8_t*)(smem + P_OFF + (wbase + c) * 272 + ks * 64 + q4 * 16);
    bf16x8_t ap1 = *(const bf16x8_t*)(smem + P_OFF + (wbase + 16 + c) * 272 + ks * 64 + q4 * 16);
    bf16x8_t bv0 = *(const bf16x8_t*)(smem + VT_OFF + (c) * 272 + ks * 64 + q4 * 16);
    bf16x8_t bv1 = *(const bf16x8_t*)(smem + VT_OFF + (16 + c) * 272 + ks * 64 + q4 * 16);
    oacc[0][0] = __builtin_amdgcn_mfma_f32_16x16x32_bf16(ap0, bv0, oacc[0][0], 0, 0, 0);
    oacc[0][1] = __builtin_amdgcn_mfma_f32_16x16x32_bf16(ap0, bv1, oacc[0][1], 0, 0, 0);
    oacc[1][0] = __builtin_amdgcn_mfma_f32_16x16x32_bf16(ap1, bv0, oacc[1][0], 0, 0, 0);
    oacc[1][1] = __builtin_amdgcn_mfma_f32_16x16x32_bf16(ap1, bv1, oacc[1][1], 0, 0, 0);
  }
  {
    __hip_bfloat16* ob = att_out + ((size_t)(b * cH + h) * cW) * cC + g * cHS;
#pragma unroll
    for (int sub = 0; sub < 2; ++sub)
#pragma unroll
      for (int dt = 0; dt < 2; ++dt)
#pragma unroll
        for (int r = 0; r < 4; ++r) {
          int w = wbase + sub * 16 + q4 * 4 + r;
          ob[(size_t)w * cC + dt * 16 + c] = __float2bfloat16(oacc[sub][dt][r]);
        }
  }
}

// ---------------- ffn1 GEMM: hidden = gelu(x1 @ w1T^T + b1), permuted-k packed stores ----------------
// 128x128 tile, XCD-swizzled 1D grid, 2-phase dbuf + counted vmcnt.
// sched_barrier(0) after the rendezvous barrier pins ds_reads AFTER it (guide rule #18):
// raw s_barrier is not a compiler fence, and a hoisted ds_read races other waves' gload_lds.
__global__ __launch_bounds__(256) void ffn1_gemm(
    const __hip_bfloat16* __restrict__ A, const __hip_bfloat16* __restrict__ Bt,
    const float* __restrict__ bias, __hip_bfloat16* __restrict__ outb)
{
  constexpr int K = 256, N = 1024;
  __shared__ __align__(16) char smem[32768];  // 2 x (As 8KB + Bs 8KB)
  const int t = threadIdx.x;
  const int id = blockIdx.x;
  const int slot = id >> 3;
  const int by = (id & 7) * 128 + (slot >> 3);
  const int bx = slot & 7;
  const int m0 = by * 128, n0 = bx * 128;
  const int lane = t & 63, wid = t >> 6;
  const int r16 = lane & 15, kq = lane >> 4;
  const int wr = (wid >> 1) * 64, wc = (wid & 1) * 64;
  const int ld_l4 = lane >> 2, ld_c8 = (lane & 3) * 8;

  const __hip_bfloat16* Abase = A  + (size_t)m0 * K + ld_c8;
  const __hip_bfloat16* Bbase = Bt + (size_t)n0 * K + ld_c8;

  f32x4_t acc[4][4];
#pragma unroll
  for (int fi = 0; fi < 4; ++fi)
#pragma unroll
    for (int fj = 0; fj < 4; ++fj) acc[fi][fj] = {0.f, 0.f, 0.f, 0.f};

  auto stage = [&](int buf, int k0) {
    char* As = smem + buf * 16384;
    char* Bs = As + 8192;
#pragma unroll
    for (int i = 0; i < 2; ++i) {
      int chunk = i * 4 + wid;
      int row = chunk * 16 + ld_l4;
      GLOAD_LDS16(Abase + (size_t)row * K + k0, As + chunk * 1024);
      GLOAD_LDS16(Bbase + (size_t)row * K + k0, Bs + chunk * 1024);
    }
  };

  constexpr int NK = K >> 5;
  stage(0, 0);
  for (int tt = 0; tt < NK; ++tt) {
    if (tt + 1 < NK) {
      stage((tt + 1) & 1, (tt + 1) << 5);
      asm volatile("s_waitcnt vmcnt(4)" ::: "memory");  // cur tile landed; next 4 in flight
    } else {
      asm volatile("s_waitcnt vmcnt(0)" ::: "memory");
    }
    __builtin_amdgcn_s_barrier();
    __builtin_amdgcn_sched_barrier(0);  // pin ds_reads after the rendezvous
    char* As = smem + (tt & 1) * 16384;
    char* Bs = As + 8192;
    bf16x8_t af[4], bf[4];
#pragma unroll
    for (int fi = 0; fi < 4; ++fi)
      af[fi] = *(const bf16x8_t*)(As + (wr + fi * 16 + r16) * 64 + kq * 16);
#pragma unroll
    for (int fj = 0; fj < 4; ++fj)
      bf[fj] = *(const bf16x8_t*)(Bs + (wc + fj * 16 + r16) * 64 + kq * 16);
#pragma unroll
    for (int fi = 0; fi < 4; ++fi)
#pragma unroll
      for (int fj = 0; fj < 4; ++fj)
        acc[fi][fj] = __builtin_amdgcn_mfma_f32_16x16x32_bf16(af[fi], bf[fj], acc[fi][fj], 0, 0, 0);
    __builtin_amdgcn_sched_barrier(0);  // keep reads+MFMAs before the WAR barrier
    __builtin_amdgcn_s_barrier();       // WAR: all reads done before next stage overwrites
  }

  // ---- epilogue: bias + gelu, packed permuted stores (16 x uint2 per thread) ----
  float bv[4];
#pragma unroll
  for (int fj = 0; fj < 4; ++fj) bv[fj] = bias[n0 + wc + fj * 16 + r16];
  __hip_bfloat16* obase = outb + (size_t)(m0 + wr + kq * 4) * N + n0 + wc + r16 * 4;
#pragma unroll
  for (int fi = 0; fi < 4; ++fi)
#pragma unroll
    for (int r = 0; r < 4; ++r) {
      float v0 = gelu_fast(acc[fi][0][r] + bv[0]);
      float v1 = gelu_fast(acc[fi][1][r] + bv[1]);
      float v2 = gelu_fast(acc[fi][2][r] + bv[2]);
      float v3 = gelu_fast(acc[fi][3][r] + bv[3]);
      uint2 u;
      u.x = pk2(v0, v1);
      u.y = pk2(v2, v3);
      *(uint2*)(obase + (size_t)(fi * 16 + r) * N) = u;
    }
}

// ---------------- full-row GEMM + residual + LayerNorm, BM=128 x BN=256, 2-phase dbuf ----------------
// FFN2=false: proj — +proj_b +left^T residual, LN1 -> bf16 x1
// FFN2=true : ffn2 — +b2 +x1 residual (bf16), LN2 -> fp32 d_out  (A and Bt k-permuted identically)
template<int KK, bool FFN2>
__global__ __launch_bounds__(256, 2) void gemm_ln(
    const __hip_bfloat16* __restrict__ A, const __hip_bfloat16* __restrict__ Bt,
    const float* __restrict__ bias, const float* __restrict__ leftres,
    const __hip_bfloat16* __restrict__ resbf,
    const float* __restrict__ g, const float* __restrict__ be,
    void* __restrict__ outp)
{
  __shared__ __align__(16) char smem[49152];  // 2 x (As 8KB + Bs 16KB)
  const int t = threadIdx.x, lane = t & 63, wid = t >> 6;
  const int c = lane & 15, q4 = lane >> 4;
  const int m0 = blockIdx.x * 128;
  const int wr = wid * 32;
  const f32x4_t zero = {0.f, 0.f, 0.f, 0.f};

  f32x4_t acc[2][16];
#pragma unroll
  for (int fi = 0; fi < 2; ++fi)
#pragma unroll
    for (int fj = 0; fj < 16; ++fj) acc[fi][fj] = zero;

  auto stage = [&](int buf, int k0) {
    char* As = smem + buf * 24576;
    char* Bs = As + 8192;
#pragma unroll
    for (int i = 0; i < 2; ++i) {
      int chunk = (wid * 2 + i) * 64 + lane;
      int row = chunk >> 2, c8 = (chunk & 3) * 8;
      GLOAD_LDS16(A + (size_t)(m0 + row) * KK + k0 + c8, As + (wid * 2 + i) * 1024);
    }
#pragma unroll
    for (int i = 0; i < 4; ++i) {
      int chunk = (wid * 4 + i) * 64 + lane;
      int row = chunk >> 2, c8 = (chunk & 3) * 8;
      GLOAD_LDS16(Bt + (size_t)row * KK + k0 + c8, Bs + (wid * 4 + i) * 1024);
    }
  };

  constexpr int NK = KK >> 5;
  stage(0, 0);
  for (int tt = 0; tt < NK; ++tt) {
    if (tt + 1 < NK) {
      stage((tt + 1) & 1, (tt + 1) << 5);
      asm volatile("s_waitcnt vmcnt(6)" ::: "memory");
    } else {
      asm volatile("s_waitcnt vmcnt(0)" ::: "memory");
    }
    __builtin_amdgcn_s_barrier();
    __builtin_amdgcn_sched_barrier(0);  // pin ds_reads after the rendezvous
    char* As = smem + (tt & 1) * 24576;
    char* Bs = As + 8192;
    bf16x8_t af0 = *(const bf16x8_t*)(As + (wr + c) * 64 + q4 * 16);
    bf16x8_t af1 = *(const bf16x8_t*)(As + (wr + 16 + c) * 64 + q4 * 16);
#pragma unroll
    for (int fj = 0; fj < 16; ++fj) {
      bf16x8_t bf = *(const bf16x8_t*)(Bs + (fj * 16 + c) * 64 + q4 * 16);
      acc[0][fj] = __builtin_amdgcn_mfma_f32_16x16x32_bf16(af0, bf, acc[0][fj], 0, 0, 0);
      acc[1][fj] = __builtin_amdgcn_mfma_f32_16x16x32_bf16(af1, bf, acc[1][fj], 0, 0, 0);
    }
    __builtin_amdgcn_sched_barrier(0);
    __builtin_amdgcn_s_barrier();
  }

  // ---- epilogue: bias + residual ----
  if (!FFN2) {
    const int b_ = m0 >> 15, h_ = (m0 >> 7) & 255;
#pragma unroll
    for (int fj = 0; fj < 16; ++fj) {
      int n = fj * 16 + c;
      float bv = bias[n];
#pragma unroll
      for (int fi = 0; fi < 2; ++fi) {
        int w0 = wr + fi * 16 + q4 * 4;
        float4 lr = *(const float4*)(leftres + (((size_t)b_ * 256 + n) * 256 + h_) * 128 + w0);
        float la[4] = {lr.x, lr.y, lr.z, lr.w};
#pragma unroll
        for (int r = 0; r < 4; ++r) acc[fi][fj][r] += bv + la[r];
      }
    }
  } else {
#pragma unroll
    for (int fj = 0; fj < 16; ++fj) {
      int n = fj * 16 + c;
      float bv = bias[n];
#pragma unroll
      for (int fi = 0; fi < 2; ++fi)
#pragma unroll
        for (int r = 0; r < 4; ++r) {
          int row = wr + fi * 16 + q4 * 4 + r;
          acc[fi][fj][r] += bv + __bfloat162float(resbf[(size_t)(m0 + row) * 256 + n]);
        }
    }
  }

  // ---- LayerNorm in-register ----
  float mu[2][4], rs[2][4];
#pragma unroll
  for (int fi = 0; fi < 2; ++fi)
#pragma unroll
    for (int r = 0; r < 4; ++r) {
      float s = 0.f;
#pragma unroll
      for (int fj = 0; fj < 16; ++fj) s += acc[fi][fj][r];
      s += __shfl_xor(s, 1); s += __shfl_xor(s, 2); s += __shfl_xor(s, 4); s += __shfl_xor(s, 8);
      float m_ = s * (1.0f / 256.0f);
      float sq = 0.f;
#pragma unroll
      for (int fj = 0; fj < 16; ++fj) { float d = acc[fi][fj][r] - m_; sq += d * d; }
      sq += __shfl_xor(sq, 1); sq += __shfl_xor(sq, 2); sq += __shfl_xor(sq, 4); sq += __shfl_xor(sq, 8);
      mu[fi][r] = m_;
      rs[fi][r] = rsqrtf(sq * (1.0f / 256.0f) + 1e-5f);
    }
#pragma unroll
  for (int fj = 0; fj < 16; ++fj) {
    int n = fj * 16 + c;
    float gv = g[n], bev = be[n];
#pragma unroll
    for (int fi = 0; fi < 2; ++fi)
#pragma unroll
      for (int r = 0; r < 4; ++r) {
        int row = wr + fi * 16 + q4 * 4 + r;
        float val = (acc[fi][fj][r] - mu[fi][r]) * rs[fi][r] * gv + bev;
        if (FFN2)
          ((float*)outp)[(size_t)(m0 + row) * 256 + n] = val;
        else
          ((__hip_bfloat16*)outp)[(size_t)(m0 + row) * 256 + n] = __float2bfloat16(val);
      }
  }
}

extern "C" void kernel_launch(void* const* d_in, const int* in_sizes, int n_in,
                              void* d_out, int out_size, void* d_ws, size_t ws_size,
                              hipStream_t stream) {
  const float* left   = (const float*)d_in[0];
  const float* right  = (const float*)d_in[1];
  const float* qw     = (const float*)d_in[2];
  const float* kw     = (const float*)d_in[3];
  const float* vw     = (const float*)d_in[4];
  const float* proj_w = (const float*)d_in[5];
  const float* proj_b = (const float*)d_in[6];
  const float* ln1_g  = (const float*)d_in[7];
  const float* ln1_b  = (const float*)d_in[8];
  const float* ln2_g  = (const float*)d_in[9];
  const float* ln2_b  = (const float*)d_in[10];
  const float* w1     = (const float*)d_in[11];
  const float* b1     = (const float*)d_in[12];
  const float* w2     = (const float*)d_in[13];
  const float* b2     = (const float*)d_in[14];

  char* ws = (char*)d_ws;
  __hip_bfloat16* att_out = (__hip_bfloat16*)ws;                 // [M,256]  bf16 [0, 67MB)
  __hip_bfloat16* x1      = (__hip_bfloat16*)(ws + 67108864);    // [M,256]  bf16 [67,134MB)
  __hip_bfloat16* hidden  = (__hip_bfloat16*)(ws + 134217728);   // [M,1024] bf16 [134,402MB)
  float2*         rope    = (float2*)(ws + 134217728);           // 16KB, lifetime disjoint from hidden
  __hip_bfloat16* pwT     = (__hip_bfloat16*)(ws + 402653184);   // [256][256]
  __hip_bfloat16* w1T     = pwT + 65536;                         // [1024][256]
  __hip_bfloat16* w2T     = w1T + 262144;                        // [256][1024], k-permuted

  transpose_bf16<<<256, 256, 0, stream>>>(proj_w, pwT, 256, 256);
  transpose_bf16<<<1024, 256, 0, stream>>>(w1, w1T, 256, 1024);
  transpose_perm_bf16<<<1024, 256, 0, stream>>>(w2, w2T, 1024, 256);
  rope_init<<<8, 256, 0, stream>>>(rope);

  attn_mfma<<<cB * cH * cHN, 256, 0, stream>>>(left, right, qw, kw, vw, rope, att_out);

  // x1 = LN1(att_out @ proj_w + proj_b + left^T)
  gemm_ln<256, false><<<cM / 128, 256, 0, stream>>>(att_out, pwT, proj_b, left, nullptr,
                                                    ln1_g, ln1_b, x1);
  // hidden = gelu(x1 @ w1 + b1)   (XCD-swizzled grid, permuted-k packed stores)
  ffn1_gemm<<<8192, 256, 0, stream>>>(x1, w1T, b1, hidden);
  // out = LN2(hidden @ w2 + b2 + x1)   (fp32 out; hidden and w2T share the k-permutation)
  gemm_ln<1024, true><<<cM / 128, 256, 0, stream>>>(hidden, w2T, b2, nullptr, x1,
                                                    ln2_g, ln2_b, d_out);
}

// Round 11
// 445.106 us; speedup vs baseline: 2.3030x; 1.0075x over previous
//
#include <hip/hip_runtime.h>
#include <hip/hip_bf16.h>

#define DEV __device__ __forceinline__

typedef __attribute__((ext_vector_type(8))) short bf16x8_t;
typedef __attribute__((ext_vector_type(4))) float f32x4_t;

constexpr int cB = 4, cC = 256, cH = 256, cW = 128, cHN = 8, cHS = 32;
constexpr int cM = cB * cH * cW;  // 131072 rows

DEV float bfu(unsigned int b16) { union { unsigned int u; float f; } v; v.u = b16 << 16; return v.f; }
DEV unsigned short f2bb(float f) { union { __hip_bfloat16 h; unsigned short u; } v; v.h = __float2bfloat16(f); return v.u; }
DEV unsigned int pk2(float a, float b) { return (unsigned)f2bb(a) | ((unsigned)f2bb(b) << 16); }

#define GLOAD_LDS16(g, l) \
  __builtin_amdgcn_global_load_lds((const __attribute__((address_space(1))) void*)(g), \
                                   (__attribute__((address_space(3))) void*)(l), 16, 0, 0)

// fast exact-GELU: A&S 7.1.26 erf approximation (max abs err 1.5e-7) — proven absmax 0.031
DEV float gelu_fast(float v) {
  float ax = fabsf(v) * 0.7071067811865475f;
  float t = __builtin_amdgcn_rcpf(1.0f + 0.3275911f * ax);
  float poly = ((((1.061405429f * t - 1.453152027f) * t + 1.421413741f) * t
                 - 0.284496736f) * t + 0.254829592f) * t;
  float e = __expf(-ax * ax);
  float erfv = 1.0f - poly * e;  // erf(|v|/sqrt2)
  float phi = 0.5f + 0.5f * copysignf(erfv, v);
  return v * phi;
}

// ---------------- weight transpose + fp32->bf16 ----------------
__global__ __launch_bounds__(256) void transpose_bf16(const float* __restrict__ src,
                                                      __hip_bfloat16* __restrict__ dst,
                                                      int R, int Ccol) {
  int idx = blockIdx.x * 256 + threadIdx.x;
  if (idx < R * Ccol) {
    int r = idx / Ccol, c = idx - r * Ccol;
    dst[c * R + r] = __float2bfloat16(src[idx]);
  }
}

// transpose for w2 with k-permutation matching ffn1's packed-store layout:
// within each 64-k group, orig k -> pos ((k&15)<<2) | ((k>>4)&3)
__global__ __launch_bounds__(256) void transpose_perm_bf16(const float* __restrict__ src,
                                                           __hip_bfloat16* __restrict__ dst,
                                                           int R, int Ccol) {
  int idx = blockIdx.x * 256 + threadIdx.x;
  if (idx < R * Ccol) {
    int r = idx / Ccol, c = idx - r * Ccol;  // r = k, c = n
    int pk = (r & ~63) | ((r & 15) << 2) | ((r >> 4) & 3);
    dst[c * R + pk] = __float2bfloat16(src[idx]);
  }
}

// ---------------- RoPE sin/cos table: [w=128][c=16] -> (sin, cos) ----------------
__global__ __launch_bounds__(256) void rope_init(float2* __restrict__ tab) {
  int i = blockIdx.x * 256 + threadIdx.x;  // 2048 entries
  int w = i >> 4, c = i & 15;
  float inv = expf((float)c * -0.28782313662425572f);  // 100^(-c/16)
  float ang = (float)w * inv;
  tab[i] = make_float2(sinf(ang), cosf(ang));
}

// ---------------- MFMA attention: grouped proj + RoPE + softpick + PV ----------------
constexpr int XL_OFF = 0, XR_OFF = 10240, WQ_OFF = 20480, WK_OFF = 23040, WV_OFF = 25600;
constexpr int QS_OFF = 28160, KS_OFF = 38400, VT_OFF = 0, P_OFF = 10240;
constexpr int SMEM_BYTES = 48640;

__global__ __launch_bounds__(256) void attn_mfma(
    const float* __restrict__ left, const float* __restrict__ right,
    const float* __restrict__ qw, const float* __restrict__ kw, const float* __restrict__ vw,
    const float2* __restrict__ rope,
    __hip_bfloat16* __restrict__ att_out)
{
  __shared__ __align__(16) char smem[SMEM_BYTES];

  const int t = threadIdx.x;
  const int g = blockIdx.x & 7;
  const int h = (blockIdx.x >> 3) & 255;
  const int b = blockIdx.x >> 11;
  const size_t HW = (size_t)cH * cW;

  {
    const float* lb = left  + ((size_t)(b * cC + g * cHS) * cH + h) * cW;
    const float* rb = right + ((size_t)(b * cC + g * cHS) * cH + h) * cW;
    int w = t & 127, ih = (t >> 7) * 16;
    unsigned short* xlrow = (unsigned short*)(smem + XL_OFF) + w * 40 + ih;
    unsigned short* xrrow = (unsigned short*)(smem + XR_OFF) + w * 40 + ih;
#pragma unroll
    for (int i = 0; i < 16; i += 2) {
      float a0 = lb[(size_t)(ih + i) * HW + w], a1 = lb[(size_t)(ih + i + 1) * HW + w];
      *(unsigned int*)(xlrow + i) = pk2(a0, a1);
      float c0 = rb[(size_t)(ih + i) * HW + w], c1 = rb[(size_t)(ih + i + 1) * HW + w];
      *(unsigned int*)(xrrow + i) = pk2(c0, c1);
    }
    int o = t >> 3, i0 = (t & 7) * 4;
    {
      float4 v4 = *(const float4*)(qw + g * 1024 + t * 4);
      unsigned short* dst = (unsigned short*)(smem + WQ_OFF) + o * 40 + i0;
      *(unsigned int*)(dst) = pk2(v4.x, v4.y); *(unsigned int*)(dst + 2) = pk2(v4.z, v4.w);
    }
    {
      float4 v4 = *(const float4*)(kw + g * 1024 + t * 4);
      unsigned short* dst = (unsigned short*)(smem + WK_OFF) + o * 40 + i0;
      *(unsigned int*)(dst) = pk2(v4.x, v4.y); *(unsigned int*)(dst + 2) = pk2(v4.z, v4.w);
    }
    {
      float4 v4 = *(const float4*)(vw + g * 1024 + t * 4);
      unsigned short* dst = (unsigned short*)(smem + WV_OFF) + o * 40 + i0;
      *(unsigned int*)(dst) = pk2(v4.x, v4.y); *(unsigned int*)(dst + 2) = pk2(v4.z, v4.w);
    }
  }
  __syncthreads();  // B1

  const int lane = t & 63, wid = t >> 6;
  const int c = lane & 15, q4 = lane >> 4;
  const int wbase = wid * 32;
  const f32x4_t zero = {0.f, 0.f, 0.f, 0.f};

  bf16x8_t a_xl[2], a_xr[2];
#pragma unroll
  for (int sub = 0; sub < 2; ++sub) {
    a_xl[sub] = *(const bf16x8_t*)(smem + XL_OFF + (wbase + sub * 16 + c) * 80 + q4 * 16);
    a_xr[sub] = *(const bf16x8_t*)(smem + XR_OFF + (wbase + sub * 16 + c) * 80 + q4 * 16);
  }
  f32x4_t qacc[2][2], kacc[2][2];
#pragma unroll
  for (int ot = 0; ot < 2; ++ot) {
    bf16x8_t bq = *(const bf16x8_t*)(smem + WQ_OFF + (ot * 16 + c) * 80 + q4 * 16);
    bf16x8_t bk = *(const bf16x8_t*)(smem + WK_OFF + (ot * 16 + c) * 80 + q4 * 16);
#pragma unroll
    for (int sub = 0; sub < 2; ++sub) {
      qacc[sub][ot] = __builtin_amdgcn_mfma_f32_16x16x32_bf16(a_xl[sub], bq, zero, 0, 0, 0);
      kacc[sub][ot] = __builtin_amdgcn_mfma_f32_16x16x32_bf16(a_xr[sub], bk, zero, 0, 0, 0);
    }
  }
  {
    const float scale = 0.17677669529663687f;  // 1/sqrt(32)
    unsigned short* qsp = (unsigned short*)(smem + QS_OFF);
    unsigned short* ksp = (unsigned short*)(smem + KS_OFF);
#pragma unroll
    for (int sub = 0; sub < 2; ++sub)
#pragma unroll
      for (int r = 0; r < 4; ++r) {
        int w = wbase + sub * 16 + q4 * 4 + r;
        float2 sc = rope[w * 16 + c];
        float sn = sc.x, cs = sc.y;
        float q0 = qacc[sub][0][r], q1 = qacc[sub][1][r];
        qsp[w * 40 + c]      = f2bb((q0 * cs - q1 * sn) * scale);
        qsp[w * 40 + c + 16] = f2bb((q1 * cs + q0 * sn) * scale);
        float k0 = kacc[sub][0][r], k1 = kacc[sub][1][r];
        ksp[w * 40 + c]      = f2bb(k0 * cs - k1 * sn);
        ksp[w * 40 + c + 16] = f2bb(k1 * cs + k0 * sn);
      }
  }
  __syncthreads();  // B2

  // ---- V^T projection; permuted-k layout: elem (d, k=wp) at pos c*8 + wid*2 + sub
  {
    f32x4_t vacc[2][2];
#pragma unroll
    for (int dt = 0; dt < 2; ++dt) {
      bf16x8_t awv = *(const bf16x8_t*)(smem + WV_OFF + (dt * 16 + c) * 80 + q4 * 16);
#pragma unroll
      for (int sub = 0; sub < 2; ++sub)
        vacc[dt][sub] = __builtin_amdgcn_mfma_f32_16x16x32_bf16(awv, a_xr[sub], zero, 0, 0, 0);
    }
    unsigned short* vtp = (unsigned short*)(smem + VT_OFF);
#pragma unroll
    for (int dt = 0; dt < 2; ++dt)
#pragma unroll
      for (int r = 0; r < 4; ++r) {
        int d = dt * 16 + q4 * 4 + r;
        *(unsigned int*)(vtp + d * 136 + c * 8 + wid * 2) = pk2(vacc[dt][0][r], vacc[dt][1][r]);
      }
  }

  bf16x8_t aq0 = *(const bf16x8_t*)(smem + QS_OFF + (wbase + c) * 80 + q4 * 16);
  bf16x8_t aq1 = *(const bf16x8_t*)(smem + QS_OFF + (wbase + 16 + c) * 80 + q4 * 16);
  f32x4_t sac[2][8];
#pragma unroll
  for (int kt = 0; kt < 8; ++kt) {
    bf16x8_t bk = *(const bf16x8_t*)(smem + KS_OFF + (kt * 16 + c) * 80 + q4 * 16);
    sac[0][kt] = __builtin_amdgcn_mfma_f32_16x16x32_bf16(aq0, bk, zero, 0, 0, 0);
    sac[1][kt] = __builtin_amdgcn_mfma_f32_16x16x32_bf16(aq1, bk, zero, 0, 0, 0);
  }

  float dinv_[2][4];
#pragma unroll
  for (int sub = 0; sub < 2; ++sub)
#pragma unroll
    for (int r = 0; r < 4; ++r) {
      float m = sac[sub][0][r];
#pragma unroll
      for (int kt = 1; kt < 8; ++kt) m = fmaxf(m, sac[sub][kt][r]);
      m = fmaxf(m, __shfl_xor(m, 1));
      m = fmaxf(m, __shfl_xor(m, 2));
      m = fmaxf(m, __shfl_xor(m, 4));
      m = fmaxf(m, __shfl_xor(m, 8));
      float em = __expf(-m);
      float ss = 0.f;
#pragma unroll
      for (int kt = 0; kt < 8; ++kt) {
        float e = __expf(sac[sub][kt][r] - m) - em;
        sac[sub][kt][r] = fmaxf(e, 0.f);
        ss += fabsf(e);
      }
      ss += __shfl_xor(ss, 1);
      ss += __shfl_xor(ss, 2);
      ss += __shfl_xor(ss, 4);
      ss += __shfl_xor(ss, 8);
      dinv_[sub][r] = 1.0f / (ss + 1e-6f);
    }
  __syncthreads();  // B3

  // ---- write P in permuted-k layout ----
  {
    unsigned short* pp = (unsigned short*)(smem + P_OFF);
#pragma unroll
    for (int sub = 0; sub < 2; ++sub)
#pragma unroll
      for (int r = 0; r < 4; ++r) {
        int w = wbase + sub * 16 + q4 * 4 + r;
        float dv = dinv_[sub][r];
        uint4 u;
        u.x = pk2(sac[sub][0][r] * dv, sac[sub][1][r] * dv);
        u.y = pk2(sac[sub][2][r] * dv, sac[sub][3][r] * dv);
        u.z = pk2(sac[sub][4][r] * dv, sac[sub][5][r] * dv);
        u.w = pk2(sac[sub][6][r] * dv, sac[sub][7][r] * dv);
        *(uint4*)(pp + w * 136 + c * 8) = u;
      }
  }
  f32x4_t oacc[2][2] = {{zero, zero}, {zero, zero}};
#pragma unroll
  for (int ks = 0; ks < 4; ++ks) {
    bf16x8_t ap0 = *(const bf16x8_t*)(smem + P_OFF + (wbase + c) * 272 + ks * 64 + q4 * 16);
    bf16x8_t ap1 = *(const bf16x8_t*)(smem + P_OFF + (wbase + 16 + c) * 272 + ks * 64 + q4 * 16);
    bf16x8_t bv0 = *(const bf16x8_t*)(smem + VT_OFF + (c) * 272 + ks * 64 + q4 * 16);
    bf16x8_t bv1 = *(const bf16x8_t*)(smem + VT_OFF + (16 + c) * 272 + ks * 64 + q4 * 16);
    oacc[0][0] = __builtin_amdgcn_mfma_f32_16x16x32_bf16(ap0, bv0, oacc[0][0], 0, 0, 0);
    oacc[0][1] = __builtin_amdgcn_mfma_f32_16x16x32_bf16(ap0, bv1, oacc[0][1], 0, 0, 0);
    oacc[1][0] = __builtin_amdgcn_mfma_f32_16x16x32_bf16(ap1, bv0, oacc[1][0], 0, 0, 0);
    oacc[1][1] = __builtin_amdgcn_mfma_f32_16x16x32_bf16(ap1, bv1, oacc[1][1], 0, 0, 0);
  }
  {
    __hip_bfloat16* ob = att_out + ((size_t)(b * cH + h) * cW) * cC + g * cHS;
#pragma unroll
    for (int sub = 0; sub < 2; ++sub)
#pragma unroll
      for (int dt = 0; dt < 2; ++dt)
#pragma unroll
        for (int r = 0; r < 4; ++r) {
          int w = wbase + sub * 16 + q4 * 4 + r;
          ob[(size_t)w * cC + dt * 16 + c] = __float2bfloat16(oacc[sub][dt][r]);
        }
  }
}

// ---------------- ffn1 GEMM: hidden = gelu(x1 @ w1T^T + b1) ----------------
// 128x128 tile, XCD-swizzled 1D grid, 3-buffer 2-deep prefetch, counted vmcnt.
// LDS tiles bank-conflict-free via source-side slot swizzle (slot ^= (row>>1)&3, rule #21):
// linear layout was an 8-way conflict on every ds_read_b128 (bank = 16*row+4*kq mod 32).
__global__ __launch_bounds__(256) void ffn1_gemm(
    const __hip_bfloat16* __restrict__ A, const __hip_bfloat16* __restrict__ Bt,
    const float* __restrict__ bias, __hip_bfloat16* __restrict__ outb)
{
  constexpr int K = 256, N = 1024;
  __shared__ __align__(16) char smem[49152];  // 3 x (As 8KB + Bs 8KB)
  const int t = threadIdx.x;
  const int id = blockIdx.x;
  const int slot = id >> 3;
  const int by = (id & 7) * 128 + (slot >> 3);
  const int bx = slot & 7;
  const int m0 = by * 128, n0 = bx * 128;
  const int lane = t & 63, wid = t >> 6;
  const int r16 = lane & 15, kq = lane >> 4;
  const int wr = (wid >> 1) * 64, wc = (wid & 1) * 64;

  f32x4_t acc[4][4];
#pragma unroll
  for (int fi = 0; fi < 4; ++fi)
#pragma unroll
    for (int fj = 0; fj < 4; ++fj) acc[fi][fj] = {0.f, 0.f, 0.f, 0.f};

  auto stage = [&](int buf, int k0) {
    char* As = smem + buf * 16384;
    char* Bs = As + 8192;
#pragma unroll
    for (int i = 0; i < 2; ++i) {
      int chunk = i * 4 + wid;
      int row = chunk * 16 + (lane >> 2);
      int sw = (((lane & 3) ^ ((row >> 1) & 3))) * 8;  // swizzled 16B slot in source
      GLOAD_LDS16(A  + (size_t)(m0 + row) * K + k0 + sw, As + chunk * 1024);
      GLOAD_LDS16(Bt + (size_t)(n0 + row) * K + k0 + sw, Bs + chunk * 1024);
    }
  };

  constexpr int NK = K >> 5;  // 8
  stage(0, 0);
  stage(1, 32);
  for (int tt = 0; tt < NK; ++tt) {
    if (tt + 2 < NK) {
      stage((tt + 2) % 3, (tt + 2) << 5);
      asm volatile("s_waitcnt vmcnt(8)" ::: "memory");   // cur tile landed; 2 tiles in flight
    } else if (tt + 1 < NK) {
      asm volatile("s_waitcnt vmcnt(4)" ::: "memory");
    } else {
      asm volatile("s_waitcnt vmcnt(0)" ::: "memory");
    }
    __builtin_amdgcn_s_barrier();
    __builtin_amdgcn_sched_barrier(0);  // pin ds_reads after the rendezvous (rule #18)
    char* As = smem + (tt % 3) * 16384;
    char* Bs = As + 8192;
    bf16x8_t af[4], bf[4];
#pragma unroll
    for (int fi = 0; fi < 4; ++fi) {
      int rr = wr + fi * 16 + r16;
      af[fi] = *(const bf16x8_t*)(As + rr * 64 + ((kq ^ ((rr >> 1) & 3)) * 16));
    }
#pragma unroll
    for (int fj = 0; fj < 4; ++fj) {
      int rr = wc + fj * 16 + r16;
      bf[fj] = *(const bf16x8_t*)(Bs + rr * 64 + ((kq ^ ((rr >> 1) & 3)) * 16));
    }
#pragma unroll
    for (int fi = 0; fi < 4; ++fi)
#pragma unroll
      for (int fj = 0; fj < 4; ++fj)
        acc[fi][fj] = __builtin_amdgcn_mfma_f32_16x16x32_bf16(af[fi], bf[fj], acc[fi][fj], 0, 0, 0);
    __builtin_amdgcn_sched_barrier(0);  // keep reads+MFMAs before the WAR barrier
    __builtin_amdgcn_s_barrier();       // WAR: all reads done before later stages overwrite
  }

  // ---- epilogue: bias + gelu, packed permuted stores (16 x uint2 per thread) ----
  float bv[4];
#pragma unroll
  for (int fj = 0; fj < 4; ++fj) bv[fj] = bias[n0 + wc + fj * 16 + r16];
  __hip_bfloat16* obase = outb + (size_t)(m0 + wr + kq * 4) * N + n0 + wc + r16 * 4;
#pragma unroll
  for (int fi = 0; fi < 4; ++fi)
#pragma unroll
    for (int r = 0; r < 4; ++r) {
      float v0 = gelu_fast(acc[fi][0][r] + bv[0]);
      float v1 = gelu_fast(acc[fi][1][r] + bv[1]);
      float v2 = gelu_fast(acc[fi][2][r] + bv[2]);
      float v3 = gelu_fast(acc[fi][3][r] + bv[3]);
      uint2 u;
      u.x = pk2(v0, v1);
      u.y = pk2(v2, v3);
      *(uint2*)(obase + (size_t)(fi * 16 + r) * N) = u;
    }
}

// ---------------- full-row GEMM + residual + LayerNorm, BM=128 x BN=256 ----------------
// 3-buffer 2-deep prefetch + swizzled tiles (same scheme as ffn1_gemm).
// FFN2=false: proj — +proj_b +left^T residual, LN1 -> bf16 x1
// FFN2=true : ffn2 — +b2 +x1 residual (bf16), LN2 -> fp32 d_out  (A and Bt k-permuted identically)
template<int KK, bool FFN2>
__global__ __launch_bounds__(256, 2) void gemm_ln(
    const __hip_bfloat16* __restrict__ A, const __hip_bfloat16* __restrict__ Bt,
    const float* __restrict__ bias, const float* __restrict__ leftres,
    const __hip_bfloat16* __restrict__ resbf,
    const float* __restrict__ g, const float* __restrict__ be,
    void* __restrict__ outp)
{
  __shared__ __align__(16) char smem[73728];  // 3 x (As 8KB + Bs 16KB)
  const int t = threadIdx.x, lane = t & 63, wid = t >> 6;
  const int c = lane & 15, q4 = lane >> 4;
  const int m0 = blockIdx.x * 128;
  const int wr = wid * 32;
  const f32x4_t zero = {0.f, 0.f, 0.f, 0.f};

  f32x4_t acc[2][16];
#pragma unroll
  for (int fi = 0; fi < 2; ++fi)
#pragma unroll
    for (int fj = 0; fj < 16; ++fj) acc[fi][fj] = zero;

  auto stage = [&](int buf, int k0) {
    char* As = smem + buf * 24576;
    char* Bs = As + 8192;
#pragma unroll
    for (int i = 0; i < 2; ++i) {
      int chunk = (wid * 2 + i);
      int row = chunk * 16 + (lane >> 2);
      int sw = (((lane & 3) ^ ((row >> 1) & 3))) * 8;
      GLOAD_LDS16(A + (size_t)(m0 + row) * KK + k0 + sw, As + chunk * 1024);
    }
#pragma unroll
    for (int i = 0; i < 4; ++i) {
      int chunk = (wid * 4 + i);
      int row = chunk * 16 + (lane >> 2);
      int sw = (((lane & 3) ^ ((row >> 1) & 3))) * 8;
      GLOAD_LDS16(Bt + (size_t)row * KK + k0 + sw, Bs + chunk * 1024);
    }
  };

  constexpr int NK = KK >> 5;
  stage(0, 0);
  stage(1, 32);
  for (int tt = 0; tt < NK; ++tt) {
    if (tt + 2 < NK) {
      stage((tt + 2) % 3, (tt + 2) << 5);
      asm volatile("s_waitcnt vmcnt(12)" ::: "memory");  // cur tile landed; 2 tiles in flight
    } else if (tt + 1 < NK) {
      asm volatile("s_waitcnt vmcnt(6)" ::: "memory");
    } else {
      asm volatile("s_waitcnt vmcnt(0)" ::: "memory");
    }
    __builtin_amdgcn_s_barrier();
    __builtin_amdgcn_sched_barrier(0);  // pin ds_reads after the rendezvous
    char* As = smem + (tt % 3) * 24576;
    char* Bs = As + 8192;
    int ra0 = wr + c, ra1 = wr + 16 + c;
    bf16x8_t af0 = *(const bf16x8_t*)(As + ra0 * 64 + ((q4 ^ ((ra0 >> 1) & 3)) * 16));
    bf16x8_t af1 = *(const bf16x8_t*)(As + ra1 * 64 + ((q4 ^ ((ra1 >> 1) & 3)) * 16));
#pragma unroll
    for (int fj = 0; fj < 16; ++fj) {
      int rb = fj * 16 + c;
      bf16x8_t bf = *(const bf16x8_t*)(Bs + rb * 64 + ((q4 ^ ((rb >> 1) & 3)) * 16));
      acc[0][fj] = __builtin_amdgcn_mfma_f32_16x16x32_bf16(af0, bf, acc[0][fj], 0, 0, 0);
      acc[1][fj] = __builtin_amdgcn_mfma_f32_16x16x32_bf16(af1, bf, acc[1][fj], 0, 0, 0);
    }
    __builtin_amdgcn_sched_barrier(0);
    __builtin_amdgcn_s_barrier();
  }

  // ---- epilogue: bias + residual ----
  if (!FFN2) {
    const int b_ = m0 >> 15, h_ = (m0 >> 7) & 255;
#pragma unroll
    for (int fj = 0; fj < 16; ++fj) {
      int n = fj * 16 + c;
      float bv = bias[n];
#pragma unroll
      for (int fi = 0; fi < 2; ++fi) {
        int w0 = wr + fi * 16 + q4 * 4;
        float4 lr = *(const float4*)(leftres + (((size_t)b_ * 256 + n) * 256 + h_) * 128 + w0);
        float la[4] = {lr.x, lr.y, lr.z, lr.w};
#pragma unroll
        for (int r = 0; r < 4; ++r) acc[fi][fj][r] += bv + la[r];
      }
    }
  } else {
#pragma unroll
    for (int fj = 0; fj < 16; ++fj) {
      int n = fj * 16 + c;
      float bv = bias[n];
#pragma unroll
      for (int fi = 0; fi < 2; ++fi)
#pragma unroll
        for (int r = 0; r < 4; ++r) {
          int row = wr + fi * 16 + q4 * 4 + r;
          acc[fi][fj][r] += bv + __bfloat162float(resbf[(size_t)(m0 + row) * 256 + n]);
        }
    }
  }

  // ---- LayerNorm in-register ----
  float mu[2][4], rs[2][4];
#pragma unroll
  for (int fi = 0; fi < 2; ++fi)
#pragma unroll
    for (int r = 0; r < 4; ++r) {
      float s = 0.f;
#pragma unroll
      for (int fj = 0; fj < 16; ++fj) s += acc[fi][fj][r];
      s += __shfl_xor(s, 1); s += __shfl_xor(s, 2); s += __shfl_xor(s, 4); s += __shfl_xor(s, 8);
      float m_ = s * (1.0f / 256.0f);
      float sq = 0.f;
#pragma unroll
      for (int fj = 0; fj < 16; ++fj) { float d = acc[fi][fj][r] - m_; sq += d * d; }
      sq += __shfl_xor(sq, 1); sq += __shfl_xor(sq, 2); sq += __shfl_xor(sq, 4); sq += __shfl_xor(sq, 8);
      mu[fi][r] = m_;
      rs[fi][r] = rsqrtf(sq * (1.0f / 256.0f) + 1e-5f);
    }
#pragma unroll
  for (int fj = 0; fj < 16; ++fj) {
    int n = fj * 16 + c;
    float gv = g[n], bev = be[n];
#pragma unroll
    for (int fi = 0; fi < 2; ++fi)
#pragma unroll
      for (int r = 0; r < 4; ++r) {
        int row = wr + fi * 16 + q4 * 4 + r;
        float val = (acc[fi][fj][r] - mu[fi][r]) * rs[fi][r] * gv + bev;
        if (FFN2)
          ((float*)outp)[(size_t)(m0 + row) * 256 + n] = val;
        else
          ((__hip_bfloat16*)outp)[(size_t)(m0 + row) * 256 + n] = __float2bfloat16(val);
      }
  }
}

extern "C" void kernel_launch(void* const* d_in, const int* in_sizes, int n_in,
                              void* d_out, int out_size, void* d_ws, size_t ws_size,
                              hipStream_t stream) {
  const float* left   = (const float*)d_in[0];
  const float* right  = (const float*)d_in[1];
  const float* qw     = (const float*)d_in[2];
  const float* kw     = (const float*)d_in[3];
  const float* vw     = (const float*)d_in[4];
  const float* proj_w = (const float*)d_in[5];
  const float* proj_b = (const float*)d_in[6];
  const float* ln1_g  = (const float*)d_in[7];
  const float* ln1_b  = (const float*)d_in[8];
  const float* ln2_g  = (const float*)d_in[9];
  const float* ln2_b  = (const float*)d_in[10];
  const float* w1     = (const float*)d_in[11];
  const float* b1     = (const float*)d_in[12];
  const float* w2     = (const float*)d_in[13];
  const float* b2     = (const float*)d_in[14];

  char* ws = (char*)d_ws;
  __hip_bfloat16* att_out = (__hip_bfloat16*)ws;                 // [M,256]  bf16 [0, 67MB)
  __hip_bfloat16* x1      = (__hip_bfloat16*)(ws + 67108864);    // [M,256]  bf16 [67,134MB)
  __hip_bfloat16* hidden  = (__hip_bfloat16*)(ws + 134217728);   // [M,1024] bf16 [134,402MB)
  float2*         rope    = (float2*)(ws + 134217728);           // 16KB, lifetime disjoint from hidden
  __hip_bfloat16* pwT     = (__hip_bfloat16*)(ws + 402653184);   // [256][256]
  __hip_bfloat16* w1T     = pwT + 65536;                         // [1024][256]
  __hip_bfloat16* w2T     = w1T + 262144;                        // [256][1024], k-permuted

  transpose_bf16<<<256, 256, 0, stream>>>(proj_w, pwT, 256, 256);
  transpose_bf16<<<1024, 256, 0, stream>>>(w1, w1T, 256, 1024);
  transpose_perm_bf16<<<1024, 256, 0, stream>>>(w2, w2T, 1024, 256);
  rope_init<<<8, 256, 0, stream>>>(rope);

  attn_mfma<<<cB * cH * cHN, 256, 0, stream>>>(left, right, qw, kw, vw, rope, att_out);

  // x1 = LN1(att_out @ proj_w + proj_b + left^T)
  gemm_ln<256, false><<<cM / 128, 256, 0, stream>>>(att_out, pwT, proj_b, left, nullptr,
                                                    ln1_g, ln1_b, x1);
  // hidden = gelu(x1 @ w1 + b1)   (XCD-swizzled grid, swizzled tiles, 2-deep pipeline)
  ffn1_gemm<<<8192, 256, 0, stream>>>(x1, w1T, b1, hidden);
  // out = LN2(hidden @ w2 + b2 + x1)   (fp32 out; hidden and w2T share the k-permutation)
  gemm_ln<1024, true><<<cM / 128, 256, 0, stream>>>(hidden, w2T, b2, nullptr, x1,
                                                    ln2_g, ln2_b, d_out);
}

// Round 12
// 406.555 us; speedup vs baseline: 2.5214x; 1.0948x over previous
//
#include <hip/hip_runtime.h>
#include <hip/hip_bf16.h>

#define DEV __device__ __forceinline__

typedef __attribute__((ext_vector_type(8))) short bf16x8_t;
typedef __attribute__((ext_vector_type(4))) float f32x4_t;

constexpr int cB = 4, cC = 256, cH = 256, cW = 128, cHN = 8, cHS = 32;
constexpr int cM = cB * cH * cW;  // 131072 rows

DEV float bfu(unsigned int b16) { union { unsigned int u; float f; } v; v.u = b16 << 16; return v.f; }
DEV unsigned short f2bb(float f) { union { __hip_bfloat16 h; unsigned short u; } v; v.h = __float2bfloat16(f); return v.u; }
DEV unsigned int pk2(float a, float b) { return (unsigned)f2bb(a) | ((unsigned)f2bb(b) << 16); }

#define GLOAD_LDS16(g, l) \
  __builtin_amdgcn_global_load_lds((const __attribute__((address_space(1))) void*)(g), \
                                   (__attribute__((address_space(3))) void*)(l), 16, 0, 0)

// fast exact-GELU: A&S 7.1.26 erf approximation (max abs err 1.5e-7) — proven absmax 0.031
DEV float gelu_fast(float v) {
  float ax = fabsf(v) * 0.7071067811865475f;
  float t = __builtin_amdgcn_rcpf(1.0f + 0.3275911f * ax);
  float poly = ((((1.061405429f * t - 1.453152027f) * t + 1.421413741f) * t
                 - 0.284496736f) * t + 0.254829592f) * t;
  float e = __expf(-ax * ax);
  float erfv = 1.0f - poly * e;  // erf(|v|/sqrt2)
  float phi = 0.5f + 0.5f * copysignf(erfv, v);
  return v * phi;
}

// ---------------- weight transpose + fp32->bf16 ----------------
__global__ __launch_bounds__(256) void transpose_bf16(const float* __restrict__ src,
                                                      __hip_bfloat16* __restrict__ dst,
                                                      int R, int Ccol) {
  int idx = blockIdx.x * 256 + threadIdx.x;
  if (idx < R * Ccol) {
    int r = idx / Ccol, c = idx - r * Ccol;
    dst[c * R + r] = __float2bfloat16(src[idx]);
  }
}

// transpose for w2 -> fp8 e4m3, scaled x64, with k-permutation matching ffn1's packed stores:
// within each 64-k group, orig k -> pos ((k&15)<<2) | ((k>>4)&3)
__global__ __launch_bounds__(256) void transpose_perm_fp8(const float* __restrict__ src,
                                                          unsigned char* __restrict__ dst,
                                                          int R, int Ccol) {
  int idx = blockIdx.x * 256 + threadIdx.x;
  if (idx < R * Ccol) {
    int r = idx / Ccol, c = idx - r * Ccol;  // r = k, c = n
    int pk = (r & ~63) | ((r & 15) << 2) | ((r >> 4) & 3);
    int u = __builtin_amdgcn_cvt_pk_fp8_f32(src[idx] * 64.0f, 0.0f, 0, false);
    dst[(size_t)c * R + pk] = (unsigned char)(u & 0xff);
  }
}

// ---------------- RoPE sin/cos table: [w=128][c=16] -> (sin, cos) ----------------
__global__ __launch_bounds__(256) void rope_init(float2* __restrict__ tab) {
  int i = blockIdx.x * 256 + threadIdx.x;  // 2048 entries
  int w = i >> 4, c = i & 15;
  float inv = expf((float)c * -0.28782313662425572f);  // 100^(-c/16)
  float ang = (float)w * inv;
  tab[i] = make_float2(sinf(ang), cosf(ang));
}

// ---------------- MFMA attention: grouped proj + RoPE + softpick + PV ----------------
constexpr int XL_OFF = 0, XR_OFF = 10240, WQ_OFF = 20480, WK_OFF = 23040, WV_OFF = 25600;
constexpr int QS_OFF = 28160, KS_OFF = 38400, VT_OFF = 0, P_OFF = 10240;
constexpr int SMEM_BYTES = 48640;

__global__ __launch_bounds__(256) void attn_mfma(
    const float* __restrict__ left, const float* __restrict__ right,
    const float* __restrict__ qw, const float* __restrict__ kw, const float* __restrict__ vw,
    const float2* __restrict__ rope,
    __hip_bfloat16* __restrict__ att_out)
{
  __shared__ __align__(16) char smem[SMEM_BYTES];

  const int t = threadIdx.x;
  const int g = blockIdx.x & 7;
  const int h = (blockIdx.x >> 3) & 255;
  const int b = blockIdx.x >> 11;
  const size_t HW = (size_t)cH * cW;

  {
    const float* lb = left  + ((size_t)(b * cC + g * cHS) * cH + h) * cW;
    const float* rb = right + ((size_t)(b * cC + g * cHS) * cH + h) * cW;
    int w = t & 127, ih = (t >> 7) * 16;
    unsigned short* xlrow = (unsigned short*)(smem + XL_OFF) + w * 40 + ih;
    unsigned short* xrrow = (unsigned short*)(smem + XR_OFF) + w * 40 + ih;
#pragma unroll
    for (int i = 0; i < 16; i += 2) {
      float a0 = lb[(size_t)(ih + i) * HW + w], a1 = lb[(size_t)(ih + i + 1) * HW + w];
      *(unsigned int*)(xlrow + i) = pk2(a0, a1);
      float c0 = rb[(size_t)(ih + i) * HW + w], c1 = rb[(size_t)(ih + i + 1) * HW + w];
      *(unsigned int*)(xrrow + i) = pk2(c0, c1);
    }
    int o = t >> 3, i0 = (t & 7) * 4;
    {
      float4 v4 = *(const float4*)(qw + g * 1024 + t * 4);
      unsigned short* dst = (unsigned short*)(smem + WQ_OFF) + o * 40 + i0;
      *(unsigned int*)(dst) = pk2(v4.x, v4.y); *(unsigned int*)(dst + 2) = pk2(v4.z, v4.w);
    }
    {
      float4 v4 = *(const float4*)(kw + g * 1024 + t * 4);
      unsigned short* dst = (unsigned short*)(smem + WK_OFF) + o * 40 + i0;
      *(unsigned int*)(dst) = pk2(v4.x, v4.y); *(unsigned int*)(dst + 2) = pk2(v4.z, v4.w);
    }
    {
      float4 v4 = *(const float4*)(vw + g * 1024 + t * 4);
      unsigned short* dst = (unsigned short*)(smem + WV_OFF) + o * 40 + i0;
      *(unsigned int*)(dst) = pk2(v4.x, v4.y); *(unsigned int*)(dst + 2) = pk2(v4.z, v4.w);
    }
  }
  __syncthreads();  // B1

  const int lane = t & 63, wid = t >> 6;
  const int c = lane & 15, q4 = lane >> 4;
  const int wbase = wid * 32;
  const f32x4_t zero = {0.f, 0.f, 0.f, 0.f};

  bf16x8_t a_xl[2], a_xr[2];
#pragma unroll
  for (int sub = 0; sub < 2; ++sub) {
    a_xl[sub] = *(const bf16x8_t*)(smem + XL_OFF + (wbase + sub * 16 + c) * 80 + q4 * 16);
    a_xr[sub] = *(const bf16x8_t*)(smem + XR_OFF + (wbase + sub * 16 + c) * 80 + q4 * 16);
  }
  f32x4_t qacc[2][2], kacc[2][2];
#pragma unroll
  for (int ot = 0; ot < 2; ++ot) {
    bf16x8_t bq = *(const bf16x8_t*)(smem + WQ_OFF + (ot * 16 + c) * 80 + q4 * 16);
    bf16x8_t bk = *(const bf16x8_t*)(smem + WK_OFF + (ot * 16 + c) * 80 + q4 * 16);
#pragma unroll
    for (int sub = 0; sub < 2; ++sub) {
      qacc[sub][ot] = __builtin_amdgcn_mfma_f32_16x16x32_bf16(a_xl[sub], bq, zero, 0, 0, 0);
      kacc[sub][ot] = __builtin_amdgcn_mfma_f32_16x16x32_bf16(a_xr[sub], bk, zero, 0, 0, 0);
    }
  }
  {
    const float scale = 0.17677669529663687f;  // 1/sqrt(32)
    unsigned short* qsp = (unsigned short*)(smem + QS_OFF);
    unsigned short* ksp = (unsigned short*)(smem + KS_OFF);
#pragma unroll
    for (int sub = 0; sub < 2; ++sub)
#pragma unroll
      for (int r = 0; r < 4; ++r) {
        int w = wbase + sub * 16 + q4 * 4 + r;
        float2 sc = rope[w * 16 + c];
        float sn = sc.x, cs = sc.y;
        float q0 = qacc[sub][0][r], q1 = qacc[sub][1][r];
        qsp[w * 40 + c]      = f2bb((q0 * cs - q1 * sn) * scale);
        qsp[w * 40 + c + 16] = f2bb((q1 * cs + q0 * sn) * scale);
        float k0 = kacc[sub][0][r], k1 = kacc[sub][1][r];
        ksp[w * 40 + c]      = f2bb(k0 * cs - k1 * sn);
        ksp[w * 40 + c + 16] = f2bb(k1 * cs + k0 * sn);
      }
  }
  __syncthreads();  // B2

  // ---- V^T projection; permuted-k layout: elem (d, k=wp) at pos c*8 + wid*2 + sub
  {
    f32x4_t vacc[2][2];
#pragma unroll
    for (int dt = 0; dt < 2; ++dt) {
      bf16x8_t awv = *(const bf16x8_t*)(smem + WV_OFF + (dt * 16 + c) * 80 + q4 * 16);
#pragma unroll
      for (int sub = 0; sub < 2; ++sub)
        vacc[dt][sub] = __builtin_amdgcn_mfma_f32_16x16x32_bf16(awv, a_xr[sub], zero, 0, 0, 0);
    }
    unsigned short* vtp = (unsigned short*)(smem + VT_OFF);
#pragma unroll
    for (int dt = 0; dt < 2; ++dt)
#pragma unroll
      for (int r = 0; r < 4; ++r) {
        int d = dt * 16 + q4 * 4 + r;
        *(unsigned int*)(vtp + d * 136 + c * 8 + wid * 2) = pk2(vacc[dt][0][r], vacc[dt][1][r]);
      }
  }

  bf16x8_t aq0 = *(const bf16x8_t*)(smem + QS_OFF + (wbase + c) * 80 + q4 * 16);
  bf16x8_t aq1 = *(const bf16x8_t*)(smem + QS_OFF + (wbase + 16 + c) * 80 + q4 * 16);
  f32x4_t sac[2][8];
#pragma unroll
  for (int kt = 0; kt < 8; ++kt) {
    bf16x8_t bk = *(const bf16x8_t*)(smem + KS_OFF + (kt * 16 + c) * 80 + q4 * 16);
    sac[0][kt] = __builtin_amdgcn_mfma_f32_16x16x32_bf16(aq0, bk, zero, 0, 0, 0);
    sac[1][kt] = __builtin_amdgcn_mfma_f32_16x16x32_bf16(aq1, bk, zero, 0, 0, 0);
  }

  float dinv_[2][4];
#pragma unroll
  for (int sub = 0; sub < 2; ++sub)
#pragma unroll
    for (int r = 0; r < 4; ++r) {
      float m = sac[sub][0][r];
#pragma unroll
      for (int kt = 1; kt < 8; ++kt) m = fmaxf(m, sac[sub][kt][r]);
      m = fmaxf(m, __shfl_xor(m, 1));
      m = fmaxf(m, __shfl_xor(m, 2));
      m = fmaxf(m, __shfl_xor(m, 4));
      m = fmaxf(m, __shfl_xor(m, 8));
      float em = __expf(-m);
      float ss = 0.f;
#pragma unroll
      for (int kt = 0; kt < 8; ++kt) {
        float e = __expf(sac[sub][kt][r] - m) - em;
        sac[sub][kt][r] = fmaxf(e, 0.f);
        ss += fabsf(e);
      }
      ss += __shfl_xor(ss, 1);
      ss += __shfl_xor(ss, 2);
      ss += __shfl_xor(ss, 4);
      ss += __shfl_xor(ss, 8);
      dinv_[sub][r] = 1.0f / (ss + 1e-6f);
    }
  __syncthreads();  // B3

  // ---- write P in permuted-k layout ----
  {
    unsigned short* pp = (unsigned short*)(smem + P_OFF);
#pragma unroll
    for (int sub = 0; sub < 2; ++sub)
#pragma unroll
      for (int r = 0; r < 4; ++r) {
        int w = wbase + sub * 16 + q4 * 4 + r;
        float dv = dinv_[sub][r];
        uint4 u;
        u.x = pk2(sac[sub][0][r] * dv, sac[sub][1][r] * dv);
        u.y = pk2(sac[sub][2][r] * dv, sac[sub][3][r] * dv);
        u.z = pk2(sac[sub][4][r] * dv, sac[sub][5][r] * dv);
        u.w = pk2(sac[sub][6][r] * dv, sac[sub][7][r] * dv);
        *(uint4*)(pp + w * 136 + c * 8) = u;
      }
  }
  f32x4_t oacc[2][2] = {{zero, zero}, {zero, zero}};
#pragma unroll
  for (int ks = 0; ks < 4; ++ks) {
    bf16x8_t ap0 = *(const bf16x8_t*)(smem + P_OFF + (wbase + c) * 272 + ks * 64 + q4 * 16);
    bf16x8_t ap1 = *(const bf16x8_t*)(smem + P_OFF + (wbase + 16 + c) * 272 + ks * 64 + q4 * 16);
    bf16x8_t bv0 = *(const bf16x8_t*)(smem + VT_OFF + (c) * 272 + ks * 64 + q4 * 16);
    bf16x8_t bv1 = *(const bf16x8_t*)(smem + VT_OFF + (16 + c) * 272 + ks * 64 + q4 * 16);
    oacc[0][0] = __builtin_amdgcn_mfma_f32_16x16x32_bf16(ap0, bv0, oacc[0][0], 0, 0, 0);
    oacc[0][1] = __builtin_amdgcn_mfma_f32_16x16x32_bf16(ap0, bv1, oacc[0][1], 0, 0, 0);
    oacc[1][0] = __builtin_amdgcn_mfma_f32_16x16x32_bf16(ap1, bv0, oacc[1][0], 0, 0, 0);
    oacc[1][1] = __builtin_amdgcn_mfma_f32_16x16x32_bf16(ap1, bv1, oacc[1][1], 0, 0, 0);
  }
  {
    __hip_bfloat16* ob = att_out + ((size_t)(b * cH + h) * cW) * cC + g * cHS;
#pragma unroll
    for (int sub = 0; sub < 2; ++sub)
#pragma unroll
      for (int dt = 0; dt < 2; ++dt)
#pragma unroll
        for (int r = 0; r < 4; ++r) {
          int w = wbase + sub * 16 + q4 * 4 + r;
          ob[(size_t)w * cC + dt * 16 + c] = __float2bfloat16(oacc[sub][dt][r]);
        }
  }
}

// ---------------- ffn1 GEMM: hidden(fp8,x64) = gelu(x1 @ w1T^T + b1) ----------------
// 128x128 tile, XCD-swizzled 1D grid, 3-buffer 2-deep prefetch, counted vmcnt, swizzled tiles.
// Epilogue packs 4 fp8/uint (k-permuted within 64-col groups; w2T shares the permutation).
__global__ __launch_bounds__(256) void ffn1_gemm(
    const __hip_bfloat16* __restrict__ A, const __hip_bfloat16* __restrict__ Bt,
    const float* __restrict__ bias, unsigned char* __restrict__ outb)
{
  constexpr int K = 256, N = 1024;
  __shared__ __align__(16) char smem[49152];  // 3 x (As 8KB + Bs 8KB)
  const int t = threadIdx.x;
  const int id = blockIdx.x;
  const int slot = id >> 3;
  const int by = (id & 7) * 128 + (slot >> 3);
  const int bx = slot & 7;
  const int m0 = by * 128, n0 = bx * 128;
  const int lane = t & 63, wid = t >> 6;
  const int r16 = lane & 15, kq = lane >> 4;
  const int wr = (wid >> 1) * 64, wc = (wid & 1) * 64;

  f32x4_t acc[4][4];
#pragma unroll
  for (int fi = 0; fi < 4; ++fi)
#pragma unroll
    for (int fj = 0; fj < 4; ++fj) acc[fi][fj] = {0.f, 0.f, 0.f, 0.f};

  auto stage = [&](int buf, int k0) {
    char* As = smem + buf * 16384;
    char* Bs = As + 8192;
#pragma unroll
    for (int i = 0; i < 2; ++i) {
      int chunk = i * 4 + wid;
      int row = chunk * 16 + (lane >> 2);
      int sw = (((lane & 3) ^ ((row >> 1) & 3))) * 8;  // swizzled 16B slot (elems)
      GLOAD_LDS16(A  + (size_t)(m0 + row) * K + k0 + sw, As + chunk * 1024);
      GLOAD_LDS16(Bt + (size_t)(n0 + row) * K + k0 + sw, Bs + chunk * 1024);
    }
  };

  constexpr int NK = K >> 5;  // 8
  stage(0, 0);
  stage(1, 32);
  for (int tt = 0; tt < NK; ++tt) {
    if (tt + 2 < NK) {
      stage((tt + 2) % 3, (tt + 2) << 5);
      asm volatile("s_waitcnt vmcnt(8)" ::: "memory");
    } else if (tt + 1 < NK) {
      asm volatile("s_waitcnt vmcnt(4)" ::: "memory");
    } else {
      asm volatile("s_waitcnt vmcnt(0)" ::: "memory");
    }
    __builtin_amdgcn_s_barrier();
    __builtin_amdgcn_sched_barrier(0);  // pin ds_reads after the rendezvous (rule #18)
    char* As = smem + (tt % 3) * 16384;
    char* Bs = As + 8192;
    bf16x8_t af[4], bf[4];
#pragma unroll
    for (int fi = 0; fi < 4; ++fi) {
      int rr = wr + fi * 16 + r16;
      af[fi] = *(const bf16x8_t*)(As + rr * 64 + ((kq ^ ((rr >> 1) & 3)) * 16));
    }
#pragma unroll
    for (int fj = 0; fj < 4; ++fj) {
      int rr = wc + fj * 16 + r16;
      bf[fj] = *(const bf16x8_t*)(Bs + rr * 64 + ((kq ^ ((rr >> 1) & 3)) * 16));
    }
#pragma unroll
    for (int fi = 0; fi < 4; ++fi)
#pragma unroll
      for (int fj = 0; fj < 4; ++fj)
        acc[fi][fj] = __builtin_amdgcn_mfma_f32_16x16x32_bf16(af[fi], bf[fj], acc[fi][fj], 0, 0, 0);
    __builtin_amdgcn_sched_barrier(0);
    __builtin_amdgcn_s_barrier();       // WAR
  }

  // ---- epilogue: bias + gelu, x64 scale, fp8 packed permuted stores (16 x uint per thread) ----
  float bv[4];
#pragma unroll
  for (int fj = 0; fj < 4; ++fj) bv[fj] = bias[n0 + wc + fj * 16 + r16];
  unsigned char* obase = outb + (size_t)(m0 + wr + kq * 4) * N + n0 + wc + r16 * 4;
#pragma unroll
  for (int fi = 0; fi < 4; ++fi)
#pragma unroll
    for (int r = 0; r < 4; ++r) {
      float v0 = gelu_fast(acc[fi][0][r] + bv[0]) * 64.0f;
      float v1 = gelu_fast(acc[fi][1][r] + bv[1]) * 64.0f;
      float v2 = gelu_fast(acc[fi][2][r] + bv[2]) * 64.0f;
      float v3 = gelu_fast(acc[fi][3][r] + bv[3]) * 64.0f;
      int u = __builtin_amdgcn_cvt_pk_fp8_f32(v0, v1, 0, false);
      u = __builtin_amdgcn_cvt_pk_fp8_f32(v2, v3, u, true);
      *(unsigned int*)(obase + (size_t)(fi * 16 + r) * N) = (unsigned)u;
    }
}

// ---------------- proj GEMM + left residual + LN1 -> bf16 x1 (bf16 operands) ----------------
__global__ __launch_bounds__(256, 2) void proj_gemm_ln(
    const __hip_bfloat16* __restrict__ A, const __hip_bfloat16* __restrict__ Bt,
    const float* __restrict__ bias, const float* __restrict__ leftres,
    const float* __restrict__ g, const float* __restrict__ be,
    __hip_bfloat16* __restrict__ outp)
{
  constexpr int KK = 256;
  __shared__ __align__(16) char smem[73728];  // 3 x (As 8KB + Bs 16KB)
  const int t = threadIdx.x, lane = t & 63, wid = t >> 6;
  const int c = lane & 15, q4 = lane >> 4;
  const int m0 = blockIdx.x * 128;
  const int wr = wid * 32;
  const f32x4_t zero = {0.f, 0.f, 0.f, 0.f};

  f32x4_t acc[2][16];
#pragma unroll
  for (int fi = 0; fi < 2; ++fi)
#pragma unroll
    for (int fj = 0; fj < 16; ++fj) acc[fi][fj] = zero;

  auto stage = [&](int buf, int k0) {
    char* As = smem + buf * 24576;
    char* Bs = As + 8192;
#pragma unroll
    for (int i = 0; i < 2; ++i) {
      int chunk = (wid * 2 + i);
      int row = chunk * 16 + (lane >> 2);
      int sw = (((lane & 3) ^ ((row >> 1) & 3))) * 8;
      GLOAD_LDS16(A + (size_t)(m0 + row) * KK + k0 + sw, As + chunk * 1024);
    }
#pragma unroll
    for (int i = 0; i < 4; ++i) {
      int chunk = (wid * 4 + i);
      int row = chunk * 16 + (lane >> 2);
      int sw = (((lane & 3) ^ ((row >> 1) & 3))) * 8;
      GLOAD_LDS16(Bt + (size_t)row * KK + k0 + sw, Bs + chunk * 1024);
    }
  };

  constexpr int NK = KK >> 5;
  stage(0, 0);
  stage(1, 32);
  for (int tt = 0; tt < NK; ++tt) {
    if (tt + 2 < NK) {
      stage((tt + 2) % 3, (tt + 2) << 5);
      asm volatile("s_waitcnt vmcnt(12)" ::: "memory");
    } else if (tt + 1 < NK) {
      asm volatile("s_waitcnt vmcnt(6)" ::: "memory");
    } else {
      asm volatile("s_waitcnt vmcnt(0)" ::: "memory");
    }
    __builtin_amdgcn_s_barrier();
    __builtin_amdgcn_sched_barrier(0);
    char* As = smem + (tt % 3) * 24576;
    char* Bs = As + 8192;
    int ra0 = wr + c, ra1 = wr + 16 + c;
    bf16x8_t af0 = *(const bf16x8_t*)(As + ra0 * 64 + ((q4 ^ ((ra0 >> 1) & 3)) * 16));
    bf16x8_t af1 = *(const bf16x8_t*)(As + ra1 * 64 + ((q4 ^ ((ra1 >> 1) & 3)) * 16));
#pragma unroll
    for (int fj = 0; fj < 16; ++fj) {
      int rb = fj * 16 + c;
      bf16x8_t bf = *(const bf16x8_t*)(Bs + rb * 64 + ((q4 ^ ((rb >> 1) & 3)) * 16));
      acc[0][fj] = __builtin_amdgcn_mfma_f32_16x16x32_bf16(af0, bf, acc[0][fj], 0, 0, 0);
      acc[1][fj] = __builtin_amdgcn_mfma_f32_16x16x32_bf16(af1, bf, acc[1][fj], 0, 0, 0);
    }
    __builtin_amdgcn_sched_barrier(0);
    __builtin_amdgcn_s_barrier();
  }

  // ---- epilogue: bias + left^T residual ----
  {
    const int b_ = m0 >> 15, h_ = (m0 >> 7) & 255;
#pragma unroll
    for (int fj = 0; fj < 16; ++fj) {
      int n = fj * 16 + c;
      float bv = bias[n];
#pragma unroll
      for (int fi = 0; fi < 2; ++fi) {
        int w0 = wr + fi * 16 + q4 * 4;
        float4 lr = *(const float4*)(leftres + (((size_t)b_ * 256 + n) * 256 + h_) * 128 + w0);
        float la[4] = {lr.x, lr.y, lr.z, lr.w};
#pragma unroll
        for (int r = 0; r < 4; ++r) acc[fi][fj][r] += bv + la[r];
      }
    }
  }

  // ---- LN1 in-register ----
  float mu[2][4], rs[2][4];
#pragma unroll
  for (int fi = 0; fi < 2; ++fi)
#pragma unroll
    for (int r = 0; r < 4; ++r) {
      float s = 0.f;
#pragma unroll
      for (int fj = 0; fj < 16; ++fj) s += acc[fi][fj][r];
      s += __shfl_xor(s, 1); s += __shfl_xor(s, 2); s += __shfl_xor(s, 4); s += __shfl_xor(s, 8);
      float m_ = s * (1.0f / 256.0f);
      float sq = 0.f;
#pragma unroll
      for (int fj = 0; fj < 16; ++fj) { float d = acc[fi][fj][r] - m_; sq += d * d; }
      sq += __shfl_xor(sq, 1); sq += __shfl_xor(sq, 2); sq += __shfl_xor(sq, 4); sq += __shfl_xor(sq, 8);
      mu[fi][r] = m_;
      rs[fi][r] = rsqrtf(sq * (1.0f / 256.0f) + 1e-5f);
    }
#pragma unroll
  for (int fj = 0; fj < 16; ++fj) {
    int n = fj * 16 + c;
    float gv = g[n], bev = be[n];
#pragma unroll
    for (int fi = 0; fi < 2; ++fi)
#pragma unroll
      for (int r = 0; r < 4; ++r) {
        int row = wr + fi * 16 + q4 * 4 + r;
        outp[(size_t)(m0 + row) * 256 + n] =
            __float2bfloat16((acc[fi][fj][r] - mu[fi][r]) * rs[fi][r] * gv + bev);
      }
  }
}

// ---------------- ffn2 (fp8 x fp8) + b2 + x1 residual + LN2 -> fp32 d_out ----------------
// A = hidden fp8 [M,1024] (x64, k-permuted); Bt = w2T fp8 [256][1024] (x64, same perm).
// K-step = 64 fp8 (64B rows — byte-identical staging to the bf16 version); 2 sub-k MFMAs/step.
__global__ __launch_bounds__(256, 2) void ffn2_ln(
    const unsigned char* __restrict__ A, const unsigned char* __restrict__ Bt,
    const float* __restrict__ bias, const __hip_bfloat16* __restrict__ resbf,
    const float* __restrict__ g, const float* __restrict__ be,
    float* __restrict__ outp)
{
  constexpr int KK = 1024;
  __shared__ __align__(16) char smem[73728];  // 3 x (As 8KB + Bs 16KB)
  const int t = threadIdx.x, lane = t & 63, wid = t >> 6;
  const int c = lane & 15, q4 = lane >> 4;
  const int m0 = blockIdx.x * 128;
  const int wr = wid * 32;
  const f32x4_t zero = {0.f, 0.f, 0.f, 0.f};

  f32x4_t acc[2][16];
#pragma unroll
  for (int fi = 0; fi < 2; ++fi)
#pragma unroll
    for (int fj = 0; fj < 16; ++fj) acc[fi][fj] = zero;

  auto stage = [&](int buf, int k0) {
    char* As = smem + buf * 24576;
    char* Bs = As + 8192;
#pragma unroll
    for (int i = 0; i < 2; ++i) {
      int chunk = (wid * 2 + i);
      int row = chunk * 16 + (lane >> 2);
      int sw = (((lane & 3) ^ ((row >> 1) & 3))) * 16;  // 16B slots, byte units
      GLOAD_LDS16(A + (size_t)(m0 + row) * KK + k0 + sw, As + chunk * 1024);
    }
#pragma unroll
    for (int i = 0; i < 4; ++i) {
      int chunk = (wid * 4 + i);
      int row = chunk * 16 + (lane >> 2);
      int sw = (((lane & 3) ^ ((row >> 1) & 3))) * 16;
      GLOAD_LDS16(Bt + (size_t)row * KK + k0 + sw, Bs + chunk * 1024);
    }
  };

  constexpr int NK = 16;  // K-steps of 64 fp8
  stage(0, 0);
  stage(1, 64);
  // per-lane fragment byte offsets within a 64B row: sub-k s, k = s*32 + q4*8..+8
  // slot16 = 2s + (q4>>1); all rows a lane touches share swizzle sl = (c>>1)&3
  const int sl = (c >> 1) & 3;
  const int koff0 = ((((q4 >> 1)) ^ sl) << 4) | ((q4 & 1) << 3);
  const int koff1 = (((2 | (q4 >> 1)) ^ sl) << 4) | ((q4 & 1) << 3);
  for (int tt = 0; tt < NK; ++tt) {
    if (tt + 2 < NK) {
      stage((tt + 2) % 3, (tt + 2) << 6);
      asm volatile("s_waitcnt vmcnt(12)" ::: "memory");
    } else if (tt + 1 < NK) {
      asm volatile("s_waitcnt vmcnt(6)" ::: "memory");
    } else {
      asm volatile("s_waitcnt vmcnt(0)" ::: "memory");
    }
    __builtin_amdgcn_s_barrier();
    __builtin_amdgcn_sched_barrier(0);
    char* As = smem + (tt % 3) * 24576;
    char* Bs = As + 8192;
    const char* arow0 = As + (wr + c) * 64;
    const char* arow1 = As + (wr + 16 + c) * 64;
    long a00 = *(const long*)(arow0 + koff0);
    long a01 = *(const long*)(arow0 + koff1);
    long a10 = *(const long*)(arow1 + koff0);
    long a11 = *(const long*)(arow1 + koff1);
#pragma unroll
    for (int fj = 0; fj < 16; ++fj) {
      const char* brow = Bs + (fj * 16 + c) * 64;
      long b0 = *(const long*)(brow + koff0);
      long b1 = *(const long*)(brow + koff1);
      acc[0][fj] = __builtin_amdgcn_mfma_f32_16x16x32_fp8_fp8(a00, b0, acc[0][fj], 0, 0, 0);
      acc[0][fj] = __builtin_amdgcn_mfma_f32_16x16x32_fp8_fp8(a01, b1, acc[0][fj], 0, 0, 0);
      acc[1][fj] = __builtin_amdgcn_mfma_f32_16x16x32_fp8_fp8(a10, b0, acc[1][fj], 0, 0, 0);
      acc[1][fj] = __builtin_amdgcn_mfma_f32_16x16x32_fp8_fp8(a11, b1, acc[1][fj], 0, 0, 0);
    }
    __builtin_amdgcn_sched_barrier(0);
    __builtin_amdgcn_s_barrier();
  }

  // ---- epilogue: unscale (2^-12) + b2 + x1 residual ----
#pragma unroll
  for (int fj = 0; fj < 16; ++fj) {
    int n = fj * 16 + c;
    float bv = bias[n];
#pragma unroll
    for (int fi = 0; fi < 2; ++fi)
#pragma unroll
      for (int r = 0; r < 4; ++r) {
        int row = wr + fi * 16 + q4 * 4 + r;
        acc[fi][fj][r] = acc[fi][fj][r] * 0.000244140625f + bv +
                         __bfloat162float(resbf[(size_t)(m0 + row) * 256 + n]);
      }
  }

  // ---- LN2 in-register ----
  float mu[2][4], rs[2][4];
#pragma unroll
  for (int fi = 0; fi < 2; ++fi)
#pragma unroll
    for (int r = 0; r < 4; ++r) {
      float s = 0.f;
#pragma unroll
      for (int fj = 0; fj < 16; ++fj) s += acc[fi][fj][r];
      s += __shfl_xor(s, 1); s += __shfl_xor(s, 2); s += __shfl_xor(s, 4); s += __shfl_xor(s, 8);
      float m_ = s * (1.0f / 256.0f);
      float sq = 0.f;
#pragma unroll
      for (int fj = 0; fj < 16; ++fj) { float d = acc[fi][fj][r] - m_; sq += d * d; }
      sq += __shfl_xor(sq, 1); sq += __shfl_xor(sq, 2); sq += __shfl_xor(sq, 4); sq += __shfl_xor(sq, 8);
      mu[fi][r] = m_;
      rs[fi][r] = rsqrtf(sq * (1.0f / 256.0f) + 1e-5f);
    }
#pragma unroll
  for (int fj = 0; fj < 16; ++fj) {
    int n = fj * 16 + c;
    float gv = g[n], bev = be[n];
#pragma unroll
    for (int fi = 0; fi < 2; ++fi)
#pragma unroll
      for (int r = 0; r < 4; ++r) {
        int row = wr + fi * 16 + q4 * 4 + r;
        outp[(size_t)(m0 + row) * 256 + n] =
            (acc[fi][fj][r] - mu[fi][r]) * rs[fi][r] * gv + bev;
      }
  }
}

extern "C" void kernel_launch(void* const* d_in, const int* in_sizes, int n_in,
                              void* d_out, int out_size, void* d_ws, size_t ws_size,
                              hipStream_t stream) {
  const float* left   = (const float*)d_in[0];
  const float* right  = (const float*)d_in[1];
  const float* qw     = (const float*)d_in[2];
  const float* kw     = (const float*)d_in[3];
  const float* vw     = (const float*)d_in[4];
  const float* proj_w = (const float*)d_in[5];
  const float* proj_b = (const float*)d_in[6];
  const float* ln1_g  = (const float*)d_in[7];
  const float* ln1_b  = (const float*)d_in[8];
  const float* ln2_g  = (const float*)d_in[9];
  const float* ln2_b  = (const float*)d_in[10];
  const float* w1     = (const float*)d_in[11];
  const float* b1     = (const float*)d_in[12];
  const float* w2     = (const float*)d_in[13];
  const float* b2     = (const float*)d_in[14];

  char* ws = (char*)d_ws;
  __hip_bfloat16* att_out = (__hip_bfloat16*)ws;                 // [M,256]  bf16 [0, 67MB)
  __hip_bfloat16* x1      = (__hip_bfloat16*)(ws + 67108864);    // [M,256]  bf16 [67,134MB)
  unsigned char*  hidden  = (unsigned char*)(ws + 134217728);    // [M,1024] fp8  [134,268MB)
  float2*         rope    = (float2*)(ws + 134217728);           // 16KB, lifetime disjoint from hidden
  __hip_bfloat16* pwT     = (__hip_bfloat16*)(ws + 402653184);   // [256][256] bf16
  __hip_bfloat16* w1T     = pwT + 65536;                         // [1024][256] bf16
  unsigned char*  w2T     = (unsigned char*)(w1T + 262144);      // [256][1024] fp8, k-permuted, x64

  transpose_bf16<<<256, 256, 0, stream>>>(proj_w, pwT, 256, 256);
  transpose_bf16<<<1024, 256, 0, stream>>>(w1, w1T, 256, 1024);
  transpose_perm_fp8<<<1024, 256, 0, stream>>>(w2, w2T, 1024, 256);
  rope_init<<<8, 256, 0, stream>>>(rope);

  attn_mfma<<<cB * cH * cHN, 256, 0, stream>>>(left, right, qw, kw, vw, rope, att_out);

  // x1 = LN1(att_out @ proj_w + proj_b + left^T)
  proj_gemm_ln<<<cM / 128, 256, 0, stream>>>(att_out, pwT, proj_b, left, ln1_g, ln1_b, x1);
  // hidden(fp8) = gelu(x1 @ w1 + b1) * 64
  ffn1_gemm<<<8192, 256, 0, stream>>>(x1, w1T, b1, hidden);
  // out = LN2(hidden @ w2 / 4096 + b2 + x1)
  ffn2_ln<<<cM / 128, 256, 0, stream>>>(hidden, w2T, b2, x1, ln2_g, ln2_b, (float*)d_out);
}

// Round 13
// 406.275 us; speedup vs baseline: 2.5231x; 1.0007x over previous
//
#include <hip/hip_runtime.h>
#include <hip/hip_bf16.h>

#define DEV __device__ __forceinline__

typedef __attribute__((ext_vector_type(8))) short bf16x8_t;
typedef __attribute__((ext_vector_type(4))) float f32x4_t;

constexpr int cB = 4, cC = 256, cH = 256, cW = 128, cHN = 8, cHS = 32;
constexpr int cM = cB * cH * cW;  // 131072 rows

DEV float bfu(unsigned int b16) { union { unsigned int u; float f; } v; v.u = b16 << 16; return v.f; }
DEV unsigned short f2bb(float f) { union { __hip_bfloat16 h; unsigned short u; } v; v.h = __float2bfloat16(f); return v.u; }
DEV unsigned int pk2(float a, float b) { return (unsigned)f2bb(a) | ((unsigned)f2bb(b) << 16); }

#define GLOAD_LDS16(g, l) \
  __builtin_amdgcn_global_load_lds((const __attribute__((address_space(1))) void*)(g), \
                                   (__attribute__((address_space(3))) void*)(l), 16, 0, 0)

// fast exact-GELU: A&S 7.1.26 erf approximation (max abs err 1.5e-7) — proven absmax 0.031
DEV float gelu_fast(float v) {
  float ax = fabsf(v) * 0.7071067811865475f;
  float t = __builtin_amdgcn_rcpf(1.0f + 0.3275911f * ax);
  float poly = ((((1.061405429f * t - 1.453152027f) * t + 1.421413741f) * t
                 - 0.284496736f) * t + 0.254829592f) * t;
  float e = __expf(-ax * ax);
  float erfv = 1.0f - poly * e;  // erf(|v|/sqrt2)
  float phi = 0.5f + 0.5f * copysignf(erfv, v);
  return v * phi;
}

// ---------------- weight transpose + fp32->bf16 ----------------
__global__ __launch_bounds__(256) void transpose_bf16(const float* __restrict__ src,
                                                      __hip_bfloat16* __restrict__ dst,
                                                      int R, int Ccol) {
  int idx = blockIdx.x * 256 + threadIdx.x;
  if (idx < R * Ccol) {
    int r = idx / Ccol, c = idx - r * Ccol;
    dst[c * R + r] = __float2bfloat16(src[idx]);
  }
}

// transpose for w2 -> fp8 e4m3, scaled x64, with k-permutation matching ffn1's packed stores:
// within each 64-k group, orig k -> pos ((k&15)<<2) | ((k>>4)&3)
__global__ __launch_bounds__(256) void transpose_perm_fp8(const float* __restrict__ src,
                                                          unsigned char* __restrict__ dst,
                                                          int R, int Ccol) {
  int idx = blockIdx.x * 256 + threadIdx.x;
  if (idx < R * Ccol) {
    int r = idx / Ccol, c = idx - r * Ccol;  // r = k, c = n
    int pk = (r & ~63) | ((r & 15) << 2) | ((r >> 4) & 3);
    int u = __builtin_amdgcn_cvt_pk_fp8_f32(src[idx] * 64.0f, 0.0f, 0, false);
    dst[(size_t)c * R + pk] = (unsigned char)(u & 0xff);
  }
}

// ---------------- RoPE sin/cos table: [w=128][c=16] -> (sin, cos) ----------------
__global__ __launch_bounds__(256) void rope_init(float2* __restrict__ tab) {
  int i = blockIdx.x * 256 + threadIdx.x;  // 2048 entries
  int w = i >> 4, c = i & 15;
  float inv = expf((float)c * -0.28782313662425572f);  // 100^(-c/16)
  float ang = (float)w * inv;
  tab[i] = make_float2(sinf(ang), cosf(ang));
}

// ---------------- MFMA attention: grouped proj + RoPE + softpick + PV ----------------
constexpr int XL_OFF = 0, XR_OFF = 10240, WQ_OFF = 20480, WK_OFF = 23040, WV_OFF = 25600;
constexpr int QS_OFF = 28160, KS_OFF = 38400, VT_OFF = 0, P_OFF = 10240;
constexpr int SMEM_BYTES = 48640;

__global__ __launch_bounds__(256) void attn_mfma(
    const float* __restrict__ left, const float* __restrict__ right,
    const float* __restrict__ qw, const float* __restrict__ kw, const float* __restrict__ vw,
    const float2* __restrict__ rope,
    __hip_bfloat16* __restrict__ att_out)
{
  __shared__ __align__(16) char smem[SMEM_BYTES];

  const int t = threadIdx.x;
  const int g = blockIdx.x & 7;
  const int h = (blockIdx.x >> 3) & 255;
  const int b = blockIdx.x >> 11;
  const size_t HW = (size_t)cH * cW;

  {
    const float* lb = left  + ((size_t)(b * cC + g * cHS) * cH + h) * cW;
    const float* rb = right + ((size_t)(b * cC + g * cHS) * cH + h) * cW;
    int w = t & 127, ih = (t >> 7) * 16;
    unsigned short* xlrow = (unsigned short*)(smem + XL_OFF) + w * 40 + ih;
    unsigned short* xrrow = (unsigned short*)(smem + XR_OFF) + w * 40 + ih;
#pragma unroll
    for (int i = 0; i < 16; i += 2) {
      float a0 = lb[(size_t)(ih + i) * HW + w], a1 = lb[(size_t)(ih + i + 1) * HW + w];
      *(unsigned int*)(xlrow + i) = pk2(a0, a1);
      float c0 = rb[(size_t)(ih + i) * HW + w], c1 = rb[(size_t)(ih + i + 1) * HW + w];
      *(unsigned int*)(xrrow + i) = pk2(c0, c1);
    }
    int o = t >> 3, i0 = (t & 7) * 4;
    {
      float4 v4 = *(const float4*)(qw + g * 1024 + t * 4);
      unsigned short* dst = (unsigned short*)(smem + WQ_OFF) + o * 40 + i0;
      *(unsigned int*)(dst) = pk2(v4.x, v4.y); *(unsigned int*)(dst + 2) = pk2(v4.z, v4.w);
    }
    {
      float4 v4 = *(const float4*)(kw + g * 1024 + t * 4);
      unsigned short* dst = (unsigned short*)(smem + WK_OFF) + o * 40 + i0;
      *(unsigned int*)(dst) = pk2(v4.x, v4.y); *(unsigned int*)(dst + 2) = pk2(v4.z, v4.w);
    }
    {
      float4 v4 = *(const float4*)(vw + g * 1024 + t * 4);
      unsigned short* dst = (unsigned short*)(smem + WV_OFF) + o * 40 + i0;
      *(unsigned int*)(dst) = pk2(v4.x, v4.y); *(unsigned int*)(dst + 2) = pk2(v4.z, v4.w);
    }
  }
  __syncthreads();  // B1

  const int lane = t & 63, wid = t >> 6;
  const int c = lane & 15, q4 = lane >> 4;
  const int wbase = wid * 32;
  const f32x4_t zero = {0.f, 0.f, 0.f, 0.f};

  bf16x8_t a_xl[2], a_xr[2];
#pragma unroll
  for (int sub = 0; sub < 2; ++sub) {
    a_xl[sub] = *(const bf16x8_t*)(smem + XL_OFF + (wbase + sub * 16 + c) * 80 + q4 * 16);
    a_xr[sub] = *(const bf16x8_t*)(smem + XR_OFF + (wbase + sub * 16 + c) * 80 + q4 * 16);
  }
  f32x4_t qacc[2][2], kacc[2][2];
#pragma unroll
  for (int ot = 0; ot < 2; ++ot) {
    bf16x8_t bq = *(const bf16x8_t*)(smem + WQ_OFF + (ot * 16 + c) * 80 + q4 * 16);
    bf16x8_t bk = *(const bf16x8_t*)(smem + WK_OFF + (ot * 16 + c) * 80 + q4 * 16);
#pragma unroll
    for (int sub = 0; sub < 2; ++sub) {
      qacc[sub][ot] = __builtin_amdgcn_mfma_f32_16x16x32_bf16(a_xl[sub], bq, zero, 0, 0, 0);
      kacc[sub][ot] = __builtin_amdgcn_mfma_f32_16x16x32_bf16(a_xr[sub], bk, zero, 0, 0, 0);
    }
  }
  {
    const float scale = 0.17677669529663687f;  // 1/sqrt(32)
    unsigned short* qsp = (unsigned short*)(smem + QS_OFF);
    unsigned short* ksp = (unsigned short*)(smem + KS_OFF);
#pragma unroll
    for (int sub = 0; sub < 2; ++sub)
#pragma unroll
      for (int r = 0; r < 4; ++r) {
        int w = wbase + sub * 16 + q4 * 4 + r;
        float2 sc = rope[w * 16 + c];
        float sn = sc.x, cs = sc.y;
        float q0 = qacc[sub][0][r], q1 = qacc[sub][1][r];
        qsp[w * 40 + c]      = f2bb((q0 * cs - q1 * sn) * scale);
        qsp[w * 40 + c + 16] = f2bb((q1 * cs + q0 * sn) * scale);
        float k0 = kacc[sub][0][r], k1 = kacc[sub][1][r];
        ksp[w * 40 + c]      = f2bb(k0 * cs - k1 * sn);
        ksp[w * 40 + c + 16] = f2bb(k1 * cs + k0 * sn);
      }
  }
  __syncthreads();  // B2

  // ---- V^T projection; permuted-k layout: elem (d, k=wp) at pos c*8 + wid*2 + sub
  {
    f32x4_t vacc[2][2];
#pragma unroll
    for (int dt = 0; dt < 2; ++dt) {
      bf16x8_t awv = *(const bf16x8_t*)(smem + WV_OFF + (dt * 16 + c) * 80 + q4 * 16);
#pragma unroll
      for (int sub = 0; sub < 2; ++sub)
        vacc[dt][sub] = __builtin_amdgcn_mfma_f32_16x16x32_bf16(awv, a_xr[sub], zero, 0, 0, 0);
    }
    unsigned short* vtp = (unsigned short*)(smem + VT_OFF);
#pragma unroll
    for (int dt = 0; dt < 2; ++dt)
#pragma unroll
      for (int r = 0; r < 4; ++r) {
        int d = dt * 16 + q4 * 4 + r;
        *(unsigned int*)(vtp + d * 136 + c * 8 + wid * 2) = pk2(vacc[dt][0][r], vacc[dt][1][r]);
      }
  }

  bf16x8_t aq0 = *(const bf16x8_t*)(smem + QS_OFF + (wbase + c) * 80 + q4 * 16);
  bf16x8_t aq1 = *(const bf16x8_t*)(smem + QS_OFF + (wbase + 16 + c) * 80 + q4 * 16);
  f32x4_t sac[2][8];
#pragma unroll
  for (int kt = 0; kt < 8; ++kt) {
    bf16x8_t bk = *(const bf16x8_t*)(smem + KS_OFF + (kt * 16 + c) * 80 + q4 * 16);
    sac[0][kt] = __builtin_amdgcn_mfma_f32_16x16x32_bf16(aq0, bk, zero, 0, 0, 0);
    sac[1][kt] = __builtin_amdgcn_mfma_f32_16x16x32_bf16(aq1, bk, zero, 0, 0, 0);
  }

  float dinv_[2][4];
#pragma unroll
  for (int sub = 0; sub < 2; ++sub)
#pragma unroll
    for (int r = 0; r < 4; ++r) {
      float m = sac[sub][0][r];
#pragma unroll
      for (int kt = 1; kt < 8; ++kt) m = fmaxf(m, sac[sub][kt][r]);
      m = fmaxf(m, __shfl_xor(m, 1));
      m = fmaxf(m, __shfl_xor(m, 2));
      m = fmaxf(m, __shfl_xor(m, 4));
      m = fmaxf(m, __shfl_xor(m, 8));
      float em = __expf(-m);
      float ss = 0.f;
#pragma unroll
      for (int kt = 0; kt < 8; ++kt) {
        float e = __expf(sac[sub][kt][r] - m) - em;
        sac[sub][kt][r] = fmaxf(e, 0.f);
        ss += fabsf(e);
      }
      ss += __shfl_xor(ss, 1);
      ss += __shfl_xor(ss, 2);
      ss += __shfl_xor(ss, 4);
      ss += __shfl_xor(ss, 8);
      dinv_[sub][r] = 1.0f / (ss + 1e-6f);
    }
  __syncthreads();  // B3

  // ---- write P in permuted-k layout ----
  {
    unsigned short* pp = (unsigned short*)(smem + P_OFF);
#pragma unroll
    for (int sub = 0; sub < 2; ++sub)
#pragma unroll
      for (int r = 0; r < 4; ++r) {
        int w = wbase + sub * 16 + q4 * 4 + r;
        float dv = dinv_[sub][r];
        uint4 u;
        u.x = pk2(sac[sub][0][r] * dv, sac[sub][1][r] * dv);
        u.y = pk2(sac[sub][2][r] * dv, sac[sub][3][r] * dv);
        u.z = pk2(sac[sub][4][r] * dv, sac[sub][5][r] * dv);
        u.w = pk2(sac[sub][6][r] * dv, sac[sub][7][r] * dv);
        *(uint4*)(pp + w * 136 + c * 8) = u;
      }
  }
  f32x4_t oacc[2][2] = {{zero, zero}, {zero, zero}};
#pragma unroll
  for (int ks = 0; ks < 4; ++ks) {
    bf16x8_t ap0 = *(const bf16x8_t*)(smem + P_OFF + (wbase + c) * 272 + ks * 64 + q4 * 16);
    bf16x8_t ap1 = *(const bf16x8_t*)(smem + P_OFF + (wbase + 16 + c) * 272 + ks * 64 + q4 * 16);
    bf16x8_t bv0 = *(const bf16x8_t*)(smem + VT_OFF + (c) * 272 + ks * 64 + q4 * 16);
    bf16x8_t bv1 = *(const bf16x8_t*)(smem + VT_OFF + (16 + c) * 272 + ks * 64 + q4 * 16);
    oacc[0][0] = __builtin_amdgcn_mfma_f32_16x16x32_bf16(ap0, bv0, oacc[0][0], 0, 0, 0);
    oacc[0][1] = __builtin_amdgcn_mfma_f32_16x16x32_bf16(ap0, bv1, oacc[0][1], 0, 0, 0);
    oacc[1][0] = __builtin_amdgcn_mfma_f32_16x16x32_bf16(ap1, bv0, oacc[1][0], 0, 0, 0);
    oacc[1][1] = __builtin_amdgcn_mfma_f32_16x16x32_bf16(ap1, bv1, oacc[1][1], 0, 0, 0);
  }
  {
    __hip_bfloat16* ob = att_out + ((size_t)(b * cH + h) * cW) * cC + g * cHS;
#pragma unroll
    for (int sub = 0; sub < 2; ++sub)
#pragma unroll
      for (int dt = 0; dt < 2; ++dt)
#pragma unroll
        for (int r = 0; r < 4; ++r) {
          int w = wbase + sub * 16 + q4 * 4 + r;
          ob[(size_t)w * cC + dt * 16 + c] = __float2bfloat16(oacc[sub][dt][r]);
        }
  }
}

// ---------------- ffn1 GEMM: hidden(fp8,x64) = gelu(x1 @ w1T^T + b1) ----------------
// 128x128 tile, XCD-swizzled 1D grid, 3-buffer 2-deep prefetch, counted vmcnt, swizzled tiles.
// Epilogue packs 4 fp8/uint (k-permuted within 64-col groups; w2T shares the permutation).
__global__ __launch_bounds__(256) void ffn1_gemm(
    const __hip_bfloat16* __restrict__ A, const __hip_bfloat16* __restrict__ Bt,
    const float* __restrict__ bias, unsigned char* __restrict__ outb)
{
  constexpr int K = 256, N = 1024;
  __shared__ __align__(16) char smem[49152];  // 3 x (As 8KB + Bs 8KB)
  const int t = threadIdx.x;
  const int id = blockIdx.x;
  const int slot = id >> 3;
  const int by = (id & 7) * 128 + (slot >> 3);
  const int bx = slot & 7;
  const int m0 = by * 128, n0 = bx * 128;
  const int lane = t & 63, wid = t >> 6;
  const int r16 = lane & 15, kq = lane >> 4;
  const int wr = (wid >> 1) * 64, wc = (wid & 1) * 64;

  f32x4_t acc[4][4];
#pragma unroll
  for (int fi = 0; fi < 4; ++fi)
#pragma unroll
    for (int fj = 0; fj < 4; ++fj) acc[fi][fj] = {0.f, 0.f, 0.f, 0.f};

  auto stage = [&](int buf, int k0) {
    char* As = smem + buf * 16384;
    char* Bs = As + 8192;
#pragma unroll
    for (int i = 0; i < 2; ++i) {
      int chunk = i * 4 + wid;
      int row = chunk * 16 + (lane >> 2);
      int sw = (((lane & 3) ^ ((row >> 1) & 3))) * 8;  // swizzled 16B slot (elems)
      GLOAD_LDS16(A  + (size_t)(m0 + row) * K + k0 + sw, As + chunk * 1024);
      GLOAD_LDS16(Bt + (size_t)(n0 + row) * K + k0 + sw, Bs + chunk * 1024);
    }
  };

  constexpr int NK = K >> 5;  // 8
  stage(0, 0);
  stage(1, 32);
  for (int tt = 0; tt < NK; ++tt) {
    if (tt + 2 < NK) {
      stage((tt + 2) % 3, (tt + 2) << 5);
      asm volatile("s_waitcnt vmcnt(8)" ::: "memory");
    } else if (tt + 1 < NK) {
      asm volatile("s_waitcnt vmcnt(4)" ::: "memory");
    } else {
      asm volatile("s_waitcnt vmcnt(0)" ::: "memory");
    }
    __builtin_amdgcn_s_barrier();
    __builtin_amdgcn_sched_barrier(0);  // pin ds_reads after the rendezvous (rule #18)
    char* As = smem + (tt % 3) * 16384;
    char* Bs = As + 8192;
    bf16x8_t af[4], bf[4];
#pragma unroll
    for (int fi = 0; fi < 4; ++fi) {
      int rr = wr + fi * 16 + r16;
      af[fi] = *(const bf16x8_t*)(As + rr * 64 + ((kq ^ ((rr >> 1) & 3)) * 16));
    }
#pragma unroll
    for (int fj = 0; fj < 4; ++fj) {
      int rr = wc + fj * 16 + r16;
      bf[fj] = *(const bf16x8_t*)(Bs + rr * 64 + ((kq ^ ((rr >> 1) & 3)) * 16));
    }
#pragma unroll
    for (int fi = 0; fi < 4; ++fi)
#pragma unroll
      for (int fj = 0; fj < 4; ++fj)
        acc[fi][fj] = __builtin_amdgcn_mfma_f32_16x16x32_bf16(af[fi], bf[fj], acc[fi][fj], 0, 0, 0);
    __builtin_amdgcn_sched_barrier(0);
    __builtin_amdgcn_s_barrier();       // WAR
  }

  // ---- epilogue: bias + gelu, x64 scale, fp8 packed permuted stores (16 x uint per thread) ----
  float bv[4];
#pragma unroll
  for (int fj = 0; fj < 4; ++fj) bv[fj] = bias[n0 + wc + fj * 16 + r16];
  unsigned char* obase = outb + (size_t)(m0 + wr + kq * 4) * N + n0 + wc + r16 * 4;
#pragma unroll
  for (int fi = 0; fi < 4; ++fi)
#pragma unroll
    for (int r = 0; r < 4; ++r) {
      float v0 = gelu_fast(acc[fi][0][r] + bv[0]) * 64.0f;
      float v1 = gelu_fast(acc[fi][1][r] + bv[1]) * 64.0f;
      float v2 = gelu_fast(acc[fi][2][r] + bv[2]) * 64.0f;
      float v3 = gelu_fast(acc[fi][3][r] + bv[3]) * 64.0f;
      int u = __builtin_amdgcn_cvt_pk_fp8_f32(v0, v1, 0, false);
      u = __builtin_amdgcn_cvt_pk_fp8_f32(v2, v3, u, true);
      *(unsigned int*)(obase + (size_t)(fi * 16 + r) * N) = (unsigned)u;
    }
}

// ---------------- proj GEMM + left residual + LN1 -> bf16 x1 (bf16 operands) ----------------
__global__ __launch_bounds__(256, 2) void proj_gemm_ln(
    const __hip_bfloat16* __restrict__ A, const __hip_bfloat16* __restrict__ Bt,
    const float* __restrict__ bias, const float* __restrict__ leftres,
    const float* __restrict__ g, const float* __restrict__ be,
    __hip_bfloat16* __restrict__ outp)
{
  constexpr int KK = 256;
  __shared__ __align__(16) char smem[73728];  // 3 x (As 8KB + Bs 16KB)
  const int t = threadIdx.x, lane = t & 63, wid = t >> 6;
  const int c = lane & 15, q4 = lane >> 4;
  const int m0 = blockIdx.x * 128;
  const int wr = wid * 32;
  const f32x4_t zero = {0.f, 0.f, 0.f, 0.f};

  f32x4_t acc[2][16];
#pragma unroll
  for (int fi = 0; fi < 2; ++fi)
#pragma unroll
    for (int fj = 0; fj < 16; ++fj) acc[fi][fj] = zero;

  auto stage = [&](int buf, int k0) {
    char* As = smem + buf * 24576;
    char* Bs = As + 8192;
#pragma unroll
    for (int i = 0; i < 2; ++i) {
      int chunk = (wid * 2 + i);
      int row = chunk * 16 + (lane >> 2);
      int sw = (((lane & 3) ^ ((row >> 1) & 3))) * 8;
      GLOAD_LDS16(A + (size_t)(m0 + row) * KK + k0 + sw, As + chunk * 1024);
    }
#pragma unroll
    for (int i = 0; i < 4; ++i) {
      int chunk = (wid * 4 + i);
      int row = chunk * 16 + (lane >> 2);
      int sw = (((lane & 3) ^ ((row >> 1) & 3))) * 8;
      GLOAD_LDS16(Bt + (size_t)row * KK + k0 + sw, Bs + chunk * 1024);
    }
  };

  constexpr int NK = KK >> 5;
  stage(0, 0);
  stage(1, 32);
  for (int tt = 0; tt < NK; ++tt) {
    if (tt + 2 < NK) {
      stage((tt + 2) % 3, (tt + 2) << 5);
      asm volatile("s_waitcnt vmcnt(12)" ::: "memory");
    } else if (tt + 1 < NK) {
      asm volatile("s_waitcnt vmcnt(6)" ::: "memory");
    } else {
      asm volatile("s_waitcnt vmcnt(0)" ::: "memory");
    }
    __builtin_amdgcn_s_barrier();
    __builtin_amdgcn_sched_barrier(0);
    char* As = smem + (tt % 3) * 24576;
    char* Bs = As + 8192;
    int ra0 = wr + c, ra1 = wr + 16 + c;
    bf16x8_t af0 = *(const bf16x8_t*)(As + ra0 * 64 + ((q4 ^ ((ra0 >> 1) & 3)) * 16));
    bf16x8_t af1 = *(const bf16x8_t*)(As + ra1 * 64 + ((q4 ^ ((ra1 >> 1) & 3)) * 16));
#pragma unroll
    for (int fj = 0; fj < 16; ++fj) {
      int rb = fj * 16 + c;
      bf16x8_t bf = *(const bf16x8_t*)(Bs + rb * 64 + ((q4 ^ ((rb >> 1) & 3)) * 16));
      acc[0][fj] = __builtin_amdgcn_mfma_f32_16x16x32_bf16(af0, bf, acc[0][fj], 0, 0, 0);
      acc[1][fj] = __builtin_amdgcn_mfma_f32_16x16x32_bf16(af1, bf, acc[1][fj], 0, 0, 0);
    }
    __builtin_amdgcn_sched_barrier(0);
    __builtin_amdgcn_s_barrier();
  }

  // ---- epilogue: bias + left^T residual ----
  {
    const int b_ = m0 >> 15, h_ = (m0 >> 7) & 255;
#pragma unroll
    for (int fj = 0; fj < 16; ++fj) {
      int n = fj * 16 + c;
      float bv = bias[n];
#pragma unroll
      for (int fi = 0; fi < 2; ++fi) {
        int w0 = wr + fi * 16 + q4 * 4;
        float4 lr = *(const float4*)(leftres + (((size_t)b_ * 256 + n) * 256 + h_) * 128 + w0);
        float la[4] = {lr.x, lr.y, lr.z, lr.w};
#pragma unroll
        for (int r = 0; r < 4; ++r) acc[fi][fj][r] += bv + la[r];
      }
    }
  }

  // ---- LN1 in-register ----
  float mu[2][4], rs[2][4];
#pragma unroll
  for (int fi = 0; fi < 2; ++fi)
#pragma unroll
    for (int r = 0; r < 4; ++r) {
      float s = 0.f;
#pragma unroll
      for (int fj = 0; fj < 16; ++fj) s += acc[fi][fj][r];
      s += __shfl_xor(s, 1); s += __shfl_xor(s, 2); s += __shfl_xor(s, 4); s += __shfl_xor(s, 8);
      float m_ = s * (1.0f / 256.0f);
      float sq = 0.f;
#pragma unroll
      for (int fj = 0; fj < 16; ++fj) { float d = acc[fi][fj][r] - m_; sq += d * d; }
      sq += __shfl_xor(sq, 1); sq += __shfl_xor(sq, 2); sq += __shfl_xor(sq, 4); sq += __shfl_xor(sq, 8);
      mu[fi][r] = m_;
      rs[fi][r] = rsqrtf(sq * (1.0f / 256.0f) + 1e-5f);
    }
#pragma unroll
  for (int fj = 0; fj < 16; ++fj) {
    int n = fj * 16 + c;
    float gv = g[n], bev = be[n];
#pragma unroll
    for (int fi = 0; fi < 2; ++fi)
#pragma unroll
      for (int r = 0; r < 4; ++r) {
        int row = wr + fi * 16 + q4 * 4 + r;
        outp[(size_t)(m0 + row) * 256 + n] =
            __float2bfloat16((acc[fi][fj][r] - mu[fi][r]) * rs[fi][r] * gv + bev);
      }
  }
}

// ---------------- ffn2 (fp8 x fp8) + b2 + x1 residual + LN2 -> fp32 d_out ----------------
// A = hidden fp8 [M,1024] (x64, k-permuted); Bt = w2T fp8 [256][1024] (x64, same perm).
// K-step = 64 fp8 (64B rows — byte-identical staging to the bf16 version); 2 sub-k MFMAs/step.
__global__ __launch_bounds__(256, 2) void ffn2_ln(
    const unsigned char* __restrict__ A, const unsigned char* __restrict__ Bt,
    const float* __restrict__ bias, const __hip_bfloat16* __restrict__ resbf,
    const float* __restrict__ g, const float* __restrict__ be,
    float* __restrict__ outp)
{
  constexpr int KK = 1024;
  __shared__ __align__(16) char smem[73728];  // 3 x (As 8KB + Bs 16KB)
  const int t = threadIdx.x, lane = t & 63, wid = t >> 6;
  const int c = lane & 15, q4 = lane >> 4;
  const int m0 = blockIdx.x * 128;
  const int wr = wid * 32;
  const f32x4_t zero = {0.f, 0.f, 0.f, 0.f};

  f32x4_t acc[2][16];
#pragma unroll
  for (int fi = 0; fi < 2; ++fi)
#pragma unroll
    for (int fj = 0; fj < 16; ++fj) acc[fi][fj] = zero;

  auto stage = [&](int buf, int k0) {
    char* As = smem + buf * 24576;
    char* Bs = As + 8192;
#pragma unroll
    for (int i = 0; i < 2; ++i) {
      int chunk = (wid * 2 + i);
      int row = chunk * 16 + (lane >> 2);
      int sw = (((lane & 3) ^ ((row >> 1) & 3))) * 16;  // 16B slots, byte units
      GLOAD_LDS16(A + (size_t)(m0 + row) * KK + k0 + sw, As + chunk * 1024);
    }
#pragma unroll
    for (int i = 0; i < 4; ++i) {
      int chunk = (wid * 4 + i);
      int row = chunk * 16 + (lane >> 2);
      int sw = (((lane & 3) ^ ((row >> 1) & 3))) * 16;
      GLOAD_LDS16(Bt + (size_t)row * KK + k0 + sw, Bs + chunk * 1024);
    }
  };

  constexpr int NK = 16;  // K-steps of 64 fp8
  stage(0, 0);
  stage(1, 64);
  // per-lane fragment byte offsets within a 64B row: sub-k s, k = s*32 + q4*8..+8
  // slot16 = 2s + (q4>>1); all rows a lane touches share swizzle sl = (c>>1)&3
  const int sl = (c >> 1) & 3;
  const int koff0 = ((((q4 >> 1)) ^ sl) << 4) | ((q4 & 1) << 3);
  const int koff1 = (((2 | (q4 >> 1)) ^ sl) << 4) | ((q4 & 1) << 3);
  for (int tt = 0; tt < NK; ++tt) {
    if (tt + 2 < NK) {
      stage((tt + 2) % 3, (tt + 2) << 6);
      asm volatile("s_waitcnt vmcnt(12)" ::: "memory");
    } else if (tt + 1 < NK) {
      asm volatile("s_waitcnt vmcnt(6)" ::: "memory");
    } else {
      asm volatile("s_waitcnt vmcnt(0)" ::: "memory");
    }
    __builtin_amdgcn_s_barrier();
    __builtin_amdgcn_sched_barrier(0);
    char* As = smem + (tt % 3) * 24576;
    char* Bs = As + 8192;
    const char* arow0 = As + (wr + c) * 64;
    const char* arow1 = As + (wr + 16 + c) * 64;
    long a00 = *(const long*)(arow0 + koff0);
    long a01 = *(const long*)(arow0 + koff1);
    long a10 = *(const long*)(arow1 + koff0);
    long a11 = *(const long*)(arow1 + koff1);
#pragma unroll
    for (int fj = 0; fj < 16; ++fj) {
      const char* brow = Bs + (fj * 16 + c) * 64;
      long b0 = *(const long*)(brow + koff0);
      long b1 = *(const long*)(brow + koff1);
      acc[0][fj] = __builtin_amdgcn_mfma_f32_16x16x32_fp8_fp8(a00, b0, acc[0][fj], 0, 0, 0);
      acc[0][fj] = __builtin_amdgcn_mfma_f32_16x16x32_fp8_fp8(a01, b1, acc[0][fj], 0, 0, 0);
      acc[1][fj] = __builtin_amdgcn_mfma_f32_16x16x32_fp8_fp8(a10, b0, acc[1][fj], 0, 0, 0);
      acc[1][fj] = __builtin_amdgcn_mfma_f32_16x16x32_fp8_fp8(a11, b1, acc[1][fj], 0, 0, 0);
    }
    __builtin_amdgcn_sched_barrier(0);
    __builtin_amdgcn_s_barrier();
  }

  // ---- epilogue: unscale (2^-12) + b2 + x1 residual ----
#pragma unroll
  for (int fj = 0; fj < 16; ++fj) {
    int n = fj * 16 + c;
    float bv = bias[n];
#pragma unroll
    for (int fi = 0; fi < 2; ++fi)
#pragma unroll
      for (int r = 0; r < 4; ++r) {
        int row = wr + fi * 16 + q4 * 4 + r;
        acc[fi][fj][r] = acc[fi][fj][r] * 0.000244140625f + bv +
                         __bfloat162float(resbf[(size_t)(m0 + row) * 256 + n]);
      }
  }

  // ---- LN2 in-register ----
  float mu[2][4], rs[2][4];
#pragma unroll
  for (int fi = 0; fi < 2; ++fi)
#pragma unroll
    for (int r = 0; r < 4; ++r) {
      float s = 0.f;
#pragma unroll
      for (int fj = 0; fj < 16; ++fj) s += acc[fi][fj][r];
      s += __shfl_xor(s, 1); s += __shfl_xor(s, 2); s += __shfl_xor(s, 4); s += __shfl_xor(s, 8);
      float m_ = s * (1.0f / 256.0f);
      float sq = 0.f;
#pragma unroll
      for (int fj = 0; fj < 16; ++fj) { float d = acc[fi][fj][r] - m_; sq += d * d; }
      sq += __shfl_xor(sq, 1); sq += __shfl_xor(sq, 2); sq += __shfl_xor(sq, 4); sq += __shfl_xor(sq, 8);
      mu[fi][r] = m_;
      rs[fi][r] = rsqrtf(sq * (1.0f / 256.0f) + 1e-5f);
    }
#pragma unroll
  for (int fj = 0; fj < 16; ++fj) {
    int n = fj * 16 + c;
    float gv = g[n], bev = be[n];
#pragma unroll
    for (int fi = 0; fi < 2; ++fi)
#pragma unroll
      for (int r = 0; r < 4; ++r) {
        int row = wr + fi * 16 + q4 * 4 + r;
        outp[(size_t)(m0 + row) * 256 + n] =
            (acc[fi][fj][r] - mu[fi][r]) * rs[fi][r] * gv + bev;
      }
  }
}

extern "C" void kernel_launch(void* const* d_in, const int* in_sizes, int n_in,
                              void* d_out, int out_size, void* d_ws, size_t ws_size,
                              hipStream_t stream) {
  const float* left   = (const float*)d_in[0];
  const float* right  = (const float*)d_in[1];
  const float* qw     = (const float*)d_in[2];
  const float* kw     = (const float*)d_in[3];
  const float* vw     = (const float*)d_in[4];
  const float* proj_w = (const float*)d_in[5];
  const float* proj_b = (const float*)d_in[6];
  const float* ln1_g  = (const float*)d_in[7];
  const float* ln1_b  = (const float*)d_in[8];
  const float* ln2_g  = (const float*)d_in[9];
  const float* ln2_b  = (const float*)d_in[10];
  const float* w1     = (const float*)d_in[11];
  const float* b1     = (const float*)d_in[12];
  const float* w2     = (const float*)d_in[13];
  const float* b2     = (const float*)d_in[14];

  char* ws = (char*)d_ws;
  __hip_bfloat16* att_out = (__hip_bfloat16*)ws;                 // [M,256]  bf16 [0, 67MB)
  __hip_bfloat16* x1      = (__hip_bfloat16*)(ws + 67108864);    // [M,256]  bf16 [67,134MB)
  unsigned char*  hidden  = (unsigned char*)(ws + 134217728);    // [M,1024] fp8  [134,268MB)
  float2*         rope    = (float2*)(ws + 134217728);           // 16KB, lifetime disjoint from hidden
  __hip_bfloat16* pwT     = (__hip_bfloat16*)(ws + 402653184);   // [256][256] bf16
  __hip_bfloat16* w1T     = pwT + 65536;                         // [1024][256] bf16
  unsigned char*  w2T     = (unsigned char*)(w1T + 262144);      // [256][1024] fp8, k-permuted, x64

  transpose_bf16<<<256, 256, 0, stream>>>(proj_w, pwT, 256, 256);
  transpose_bf16<<<1024, 256, 0, stream>>>(w1, w1T, 256, 1024);
  transpose_perm_fp8<<<1024, 256, 0, stream>>>(w2, w2T, 1024, 256);
  rope_init<<<8, 256, 0, stream>>>(rope);

  attn_mfma<<<cB * cH * cHN, 256, 0, stream>>>(left, right, qw, kw, vw, rope, att_out);

  // x1 = LN1(att_out @ proj_w + proj_b + left^T)
  proj_gemm_ln<<<cM / 128, 256, 0, stream>>>(att_out, pwT, proj_b, left, ln1_g, ln1_b, x1);
  // hidden(fp8) = gelu(x1 @ w1 + b1) * 64
  ffn1_gemm<<<8192, 256, 0, stream>>>(x1, w1T, b1, hidden);
  // out = LN2(hidden @ w2 / 4096 + b2 + x1)
  ffn2_ln<<<cM / 128, 256, 0, stream>>>(hidden, w2T, b2, x1, ln2_g, ln2_b, (float*)d_out);
}